// Round 1
// baseline (3903.449 us; speedup 1.0000x reference)
//
#include <hip/hip_runtime.h>
#include <math.h>

#define B_   2
#define T_   1024
#define C_   768
#define DH_  64
#define NH_  12
#define HT_  48

__device__ __forceinline__ float wave_sum(float v) {
#pragma unroll
    for (int off = 32; off; off >>= 1) v += __shfl_xor(v, off, 64);
    return v;
}
__device__ __forceinline__ float wave_max(float v) {
#pragma unroll
    for (int off = 32; off; off >>= 1) v = fmaxf(v, __shfl_xor(v, off, 64));
    return v;
}

// ---------------------------------------------------------------- prep
// S[h][d][e] = wedge_A[d][e] - wedge_A[e][d] + (d==e)*wedge_bias[h][d]
// rope tables cos/sin (T x 32), wob[d] = sum_n WO_b[n][d]
__global__ void prep_kernel(const float* __restrict__ wA, const float* __restrict__ wb,
                            const float* __restrict__ WOb,
                            float* __restrict__ S, float* __restrict__ rc,
                            float* __restrict__ rs, float* __restrict__ wob) {
    int i = blockIdx.x * 256 + threadIdx.x;
    if (i < HT_ * 64 * 64) {
        int e = i & 63, d = (i >> 6) & 63, h = i >> 12;
        float v = wA[d * 64 + e] - wA[e * 64 + d];
        if (d == e) v += wb[h * 64 + d];
        S[i] = v;
    } else if (i < HT_ * 64 * 64 + T_ * 32) {
        int j = i - HT_ * 64 * 64;
        int t = j >> 5, f = j & 31;
        float invf = (float)(1.0 / pow(10000.0, (double)f / 32.0));
        float fr = (float)t * invf;
        rc[j] = cosf(fr);
        rs[j] = sinf(fr);
    } else if (i < HT_ * 64 * 64 + T_ * 32 + C_) {
        int d = i - (HT_ * 64 * 64 + T_ * 32);
        wob[d] = WOb[d] + WOb[C_ + d] + WOb[2 * C_ + d] + WOb[3 * C_ + d];
    }
}

// ---------------------------------------------------------------- GEMM, W as (N,K):  C = A @ W^T + bias
__global__ __launch_bounds__(256) void gemm_wt(const float* __restrict__ A, const float* __restrict__ W,
                                               const float* __restrict__ bias, float* __restrict__ C,
                                               int M, int N, int K) {
    __shared__ float As[16][68];
    __shared__ float Ws[16][68];
    const int bm = blockIdx.y * 64, bn = blockIdx.x * 64;
    const int tid = threadIdx.x;
    const int tx = tid & 15, ty = tid >> 4;
    float acc[4][4] = {};
    const int mm = tid >> 2;
    const int kk4 = (tid & 3) * 4;
    for (int k0 = 0; k0 < K; k0 += 16) {
        float4 av = *reinterpret_cast<const float4*>(&A[(size_t)(bm + mm) * K + k0 + kk4]);
        As[kk4 + 0][mm] = av.x; As[kk4 + 1][mm] = av.y; As[kk4 + 2][mm] = av.z; As[kk4 + 3][mm] = av.w;
        float4 wv = *reinterpret_cast<const float4*>(&W[(size_t)(bn + mm) * K + k0 + kk4]);
        Ws[kk4 + 0][mm] = wv.x; Ws[kk4 + 1][mm] = wv.y; Ws[kk4 + 2][mm] = wv.z; Ws[kk4 + 3][mm] = wv.w;
        __syncthreads();
#pragma unroll
        for (int kk = 0; kk < 16; kk++) {
            float a0 = As[kk][ty * 4 + 0], a1 = As[kk][ty * 4 + 1], a2 = As[kk][ty * 4 + 2], a3 = As[kk][ty * 4 + 3];
            float b0 = Ws[kk][tx * 4 + 0], b1 = Ws[kk][tx * 4 + 1], b2 = Ws[kk][tx * 4 + 2], b3 = Ws[kk][tx * 4 + 3];
            acc[0][0] += a0 * b0; acc[0][1] += a0 * b1; acc[0][2] += a0 * b2; acc[0][3] += a0 * b3;
            acc[1][0] += a1 * b0; acc[1][1] += a1 * b1; acc[1][2] += a1 * b2; acc[1][3] += a1 * b3;
            acc[2][0] += a2 * b0; acc[2][1] += a2 * b1; acc[2][2] += a2 * b2; acc[2][3] += a2 * b3;
            acc[3][0] += a3 * b0; acc[3][1] += a3 * b1; acc[3][2] += a3 * b2; acc[3][3] += a3 * b3;
        }
        __syncthreads();
    }
#pragma unroll
    for (int i = 0; i < 4; i++) {
        float4 o;
        o.x = acc[i][0] + bias[bn + tx * 4 + 0];
        o.y = acc[i][1] + bias[bn + tx * 4 + 1];
        o.z = acc[i][2] + bias[bn + tx * 4 + 2];
        o.w = acc[i][3] + bias[bn + tx * 4 + 3];
        *reinterpret_cast<float4*>(&C[(size_t)(bm + ty * 4 + i) * N + bn + tx * 4]) = o;
    }
}

// ---------------------------------------------------------------- GEMM, W as (K,N):  C = (A @ W + bias) * scl
__global__ __launch_bounds__(256) void gemm_kn(const float* __restrict__ A, const float* __restrict__ W,
                                               const float* __restrict__ bias, float* __restrict__ C,
                                               int M, int N, int K, float scl) {
    __shared__ float As[16][68];
    __shared__ float Ws[16][68];
    const int bm = blockIdx.y * 64, bn = blockIdx.x * 64;
    const int tid = threadIdx.x;
    const int tx = tid & 15, ty = tid >> 4;
    float acc[4][4] = {};
    const int mm = tid >> 2;
    const int kk4 = (tid & 3) * 4;
    const int wkk = tid >> 4;          // 0..15
    const int wnn = (tid & 15) * 4;    // 0..60
    for (int k0 = 0; k0 < K; k0 += 16) {
        float4 av = *reinterpret_cast<const float4*>(&A[(size_t)(bm + mm) * K + k0 + kk4]);
        As[kk4 + 0][mm] = av.x; As[kk4 + 1][mm] = av.y; As[kk4 + 2][mm] = av.z; As[kk4 + 3][mm] = av.w;
        float4 wv = *reinterpret_cast<const float4*>(&W[(size_t)(k0 + wkk) * N + bn + wnn]);
        Ws[wkk][wnn + 0] = wv.x; Ws[wkk][wnn + 1] = wv.y; Ws[wkk][wnn + 2] = wv.z; Ws[wkk][wnn + 3] = wv.w;
        __syncthreads();
#pragma unroll
        for (int kk = 0; kk < 16; kk++) {
            float a0 = As[kk][ty * 4 + 0], a1 = As[kk][ty * 4 + 1], a2 = As[kk][ty * 4 + 2], a3 = As[kk][ty * 4 + 3];
            float b0 = Ws[kk][tx * 4 + 0], b1 = Ws[kk][tx * 4 + 1], b2 = Ws[kk][tx * 4 + 2], b3 = Ws[kk][tx * 4 + 3];
            acc[0][0] += a0 * b0; acc[0][1] += a0 * b1; acc[0][2] += a0 * b2; acc[0][3] += a0 * b3;
            acc[1][0] += a1 * b0; acc[1][1] += a1 * b1; acc[1][2] += a1 * b2; acc[1][3] += a1 * b3;
            acc[2][0] += a2 * b0; acc[2][1] += a2 * b1; acc[2][2] += a2 * b2; acc[2][3] += a2 * b3;
            acc[3][0] += a3 * b0; acc[3][1] += a3 * b1; acc[3][2] += a3 * b2; acc[3][3] += a3 * b3;
        }
        __syncthreads();
    }
#pragma unroll
    for (int i = 0; i < 4; i++) {
        float4 o;
        o.x = (acc[i][0] + bias[bn + tx * 4 + 0]) * scl;
        o.y = (acc[i][1] + bias[bn + tx * 4 + 1]) * scl;
        o.z = (acc[i][2] + bias[bn + tx * 4 + 2]) * scl;
        o.w = (acc[i][3] + bias[bn + tx * 4 + 3]) * scl;
        *reinterpret_cast<float4*>(&C[(size_t)(bm + ty * 4 + i) * N + bn + tx * 4]) = o;
    }
}

// ---------------------------------------------------------------- q transform (in place): rmsnorm -> wedge -> rope
// q layout (B,T,48,64); row = (b*T+t)*48 + h
__global__ __launch_bounds__(256) void q_transform(float* __restrict__ q, const float* __restrict__ S,
                                                   const float* __restrict__ rc, const float* __restrict__ rs) {
    const int tid = threadIdx.x, wv = tid >> 6, lane = tid & 63;
    const int row = blockIdx.x * 4 + wv;
    const int h = row % 48;
    const int t = (row / 48) & (T_ - 1);
    float* rowp = q + ((size_t)row << 6);
    __shared__ float sh[4][64];
    float v = rowp[lane];
    float ss = wave_sum(v * v);
    v *= 1.f / sqrtf(ss * (1.f / 64.f) + 1.1920928955078125e-07f);
    sh[wv][lane] = v;
    __syncthreads();
    const float* Sh = S + h * 4096;
    float acc = v;
#pragma unroll 8
    for (int d = 0; d < 64; d++) acc += sh[wv][d] * Sh[d * 64 + lane];
    __syncthreads();
    sh[wv][lane] = acc;
    __syncthreads();
    int j = lane & 31;
    float x1 = sh[wv][2 * j], x2 = sh[wv][2 * j + 1];
    float cth = rc[t * 32 + j], sth = rs[t * 32 + j];
    rowp[lane] = (lane < 32) ? (x1 * cth - x2 * sth) : (x1 * sth + x2 * cth);
}

// ---------------------------------------------------------------- k transform: wedge -> rope, expand 12->48 heads
// kb (B,T,12,64) -> kf (B,48,T,64); row = (b*48+h)*T + t
__global__ __launch_bounds__(256) void k_transform(const float* __restrict__ kb, float* __restrict__ kf,
                                                   const float* __restrict__ S,
                                                   const float* __restrict__ rc, const float* __restrict__ rs) {
    const int tid = threadIdx.x, wv = tid >> 6, lane = tid & 63;
    const int row = blockIdx.x * 4 + wv;
    const int t = row & (T_ - 1);
    const int bh = row >> 10;
    const int h = bh % 48;
    const int b = bh / 48;
    const int hk = h % 12;
    __shared__ float sh[4][64];
    float v = kb[(((size_t)(b * T_ + t) * 12 + hk) << 6) + lane];
    sh[wv][lane] = v;
    __syncthreads();
    const float* Sh = S + h * 4096;
    float acc = v;
#pragma unroll 8
    for (int d = 0; d < 64; d++) acc += sh[wv][d] * Sh[d * 64 + lane];
    __syncthreads();
    sh[wv][lane] = acc;
    __syncthreads();
    int j = lane & 31;
    float x1 = sh[wv][2 * j], x2 = sh[wv][2 * j + 1];
    float cth = rc[t * 32 + j], sth = rs[t * 32 + j];
    kf[((size_t)row << 6) + lane] = (lane < 32) ? (x1 * cth - x2 * sth) : (x1 * sth + x2 * cth);
}

// ---------------------------------------------------------------- fused attention + topk + MLP
// one wave per (b,h,t); block = 4 consecutive t of same (b,h)
__global__ __launch_bounds__(256) void attn_kernel(
    const float* __restrict__ q,      // (B,T,48,64) transformed
    const float* __restrict__ kf,     // (B,48,T,64) transformed
    const float* __restrict__ kb,     // (B,T,12,64) vanilla
    const float* __restrict__ sink_s, // (48)
    const float* __restrict__ v_nulls,// (48*64)
    const float* __restrict__ fc_w,   // (256,64)
    const float* __restrict__ fc_b,   // (256)
    const float* __restrict__ proj_w, // (64,256)
    const float* __restrict__ proj_b, // (64)
    float* __restrict__ ctx)          // (B,T,48,64)
{
    const int tid = threadIdx.x, wv = tid >> 6, lane = tid & 63;
    const int bid = blockIdx.x;
    const int tgrp = bid & 255;
    const int h = (bid >> 8) % 48;
    const int b = bid / (48 * 256);
    const int t = tgrp * 4 + wv;
    const int hk = h % 12;

    __shared__ float mksh[4][64];
    __shared__ float hsh[4][256];

    // q row in registers
    const float* qrow = q + (((size_t)(b * T_ + t) * 48 + h) << 6);
    float4 qv[16];
#pragma unroll
    for (int i = 0; i < 16; i++) qv[i] = reinterpret_cast<const float4*>(qrow)[i];

    const float* kbase = kf + (((size_t)(b * 48 + h) * T_) << 6);
    const int nch = (t >> 6) + 1;
    float sc[16];
#pragma unroll
    for (int c = 0; c < 16; c++) {
        float v = -1e30f;
        if (c < nch) {  // wave-uniform
            int s = (c << 6) + lane;
            const float4* krow = reinterpret_cast<const float4*>(kbase + ((size_t)s << 6));
            float acc = 0.f;
#pragma unroll
            for (int i = 0; i < 16; i++) {
                float4 kv = krow[i];
                acc += qv[i].x * kv.x + qv[i].y * kv.y + qv[i].z * kv.z + qv[i].w * kv.w;
            }
            v = (s <= t) ? acc * 0.125f : -1e30f;
        }
        sc[c] = v;
    }

    // softmax stats (max includes sink)
    float M = -1e30f;
#pragma unroll
    for (int c = 0; c < 16; c++) M = fmaxf(M, sc[c]);
    M = wave_max(M);
    const float sink = sink_s[h];
    M = fmaxf(M, sink);
    float Zl = 0.f;
#pragma unroll
    for (int c = 0; c < 16; c++) Zl += expf(sc[c] - M);
    float Z = wave_sum(Zl) + expf(sink - M);
    const float invZ = 1.f / Z;

    // per-lane top-12 (sorted desc, static indices only)
    float lv[12]; int ls[12];
#pragma unroll
    for (int i = 0; i < 12; i++) { lv[i] = -1e30f; ls[i] = 0; }
#pragma unroll
    for (int c = 0; c < 16; c++) {
        float cv = sc[c]; int cs = (c << 6) + lane;
        if (cv > lv[11]) {
#pragma unroll
            for (int j = 0; j < 12; j++) {
                if (cv > lv[j]) {
                    float tv = lv[j]; int ts = ls[j];
                    lv[j] = cv; ls[j] = cs;
                    cv = tv; cs = ts;
                }
            }
        }
    }

    // wave merge of per-lane lists, 12 rounds; accumulate marker
    const float* kvan = kb + (((size_t)b * T_ * 12 + hk) << 6);  // + s*768 + lane
    float mk = 0.f;
    for (int r = 0; r < 12; r++) {
        float v = lv[0]; int s2 = ls[0];
#pragma unroll
        for (int off = 1; off < 64; off <<= 1) {
            float ov = __shfl_xor(v, off, 64);
            int os = __shfl_xor(s2, off, 64);
            if (ov > v || (ov == v && os < s2)) { v = ov; s2 = os; }
        }
        if (v > -1e29f) {  // wave-uniform: real candidate
            float w = expf(v - M) * invZ;
            mk += w * kvan[(size_t)s2 * 768 + lane];
        }
        if (ls[0] == s2 && lv[0] == v) {  // pop winner (owner lane)
#pragma unroll
            for (int j = 0; j < 11; j++) { lv[j] = lv[j + 1]; ls[j] = ls[j + 1]; }
            lv[11] = -1e30f; ls[11] = 0;
        }
    }
    mk = (mk + kvan[(size_t)t * 768 + lane]) * (1.f / 13.f);

    // MLP: fc (64 -> 256)
    mksh[wv][lane] = mk;
    __syncthreads();
    float hh[4];
#pragma unroll
    for (int rr = 0; rr < 4; rr++) {
        int o = rr * 64 + lane;
        const float4* wrow = reinterpret_cast<const float4*>(fc_w + (size_t)o * 64);
        float acc = fc_b[o];
#pragma unroll
        for (int d4 = 0; d4 < 16; d4++) {
            float4 w4 = wrow[d4];
            float4 m4 = reinterpret_cast<const float4*>(mksh[wv])[d4];
            acc += w4.x * m4.x + w4.y * m4.y + w4.z * m4.z + w4.w * m4.w;
        }
        hh[rr] = acc;
    }
    // activation + rmsnorm(256) + gated sigmoid
    float ss = 0.f;
#pragma unroll
    for (int rr = 0; rr < 4; rr++) {
        float x = hh[rr];
        float x2 = x * x;
        float y = x2 + 0.75f * x2 * x;
        hh[rr] = y;
        ss += y * y;
    }
    ss = wave_sum(ss);
    float rinv = 1.f / sqrtf(ss * (1.f / 256.f) + 1.1920928955078125e-07f);
#pragma unroll
    for (int rr = 0; rr < 4; rr++) {
        float y = hh[rr] * rinv;
        hh[rr] = y / (1.f + expf(-1.8137993642342178f * y));
    }
    __syncthreads();
#pragma unroll
    for (int rr = 0; rr < 4; rr++) hsh[wv][rr * 64 + lane] = hh[rr];
    __syncthreads();
    // proj (256 -> 64)
    const float4* prow = reinterpret_cast<const float4*>(proj_w + (size_t)lane * 256);
    float acc = proj_b[lane];
#pragma unroll
    for (int o4 = 0; o4 < 64; o4++) {
        float4 w4 = prow[o4];
        float4 h4 = reinterpret_cast<const float4*>(hsh[wv])[o4];
        acc += w4.x * h4.x + w4.y * h4.y + w4.z * h4.z + w4.w * h4.w;
    }
    float psink = expf(sink - M) * invZ;
    acc += psink * v_nulls[h * 64 + lane];
    ctx[(((size_t)(b * T_ + t) * 48 + h) << 6) + lane] = acc;
}

// ---------------------------------------------------------------- launch
extern "C" void kernel_launch(void* const* d_in, const int* in_sizes, int n_in,
                              void* d_out, int out_size, void* d_ws, size_t ws_size,
                              hipStream_t stream) {
    (void)in_sizes; (void)n_in; (void)out_size; (void)ws_size;
    const float* A       = (const float*)d_in[0];
    const float* X       = (const float*)d_in[1];
    const float* Wq_w    = (const float*)d_in[2];
    const float* Wq_b    = (const float*)d_in[3];
    const float* Wk_w    = (const float*)d_in[4];
    const float* Wk_b    = (const float*)d_in[5];
    const float* wedge_A = (const float*)d_in[6];
    const float* wedge_b = (const float*)d_in[7];
    const float* sink    = (const float*)d_in[8];
    const float* v_nulls = (const float*)d_in[9];
    const float* fc_w    = (const float*)d_in[10];
    const float* fc_b    = (const float*)d_in[11];
    const float* proj_w  = (const float*)d_in[12];
    const float* proj_b  = (const float*)d_in[13];
    const float* WO      = (const float*)d_in[14];
    const float* WO_b    = (const float*)d_in[15];
    float* out = (float*)d_out;
    float* ws  = (float*)d_ws;

    float* qbuf  = ws;                      // 2048*3072 (in-place transformed)
    float* kbbuf = qbuf + 2048 * 3072;      // 2048*768
    float* kfbuf = kbbuf + 2048 * 768;      // 2*48*1024*64
    float* ctx   = kfbuf + 6291456;         // 2048*3072
    float* Sbuf  = ctx + 6291456;           // 48*64*64
    float* rcbuf = Sbuf + 196608;           // 1024*32
    float* rsbuf = rcbuf + 32768;           // 1024*32
    float* wob   = rsbuf + 32768;           // 768

    prep_kernel<<<(48 * 64 * 64 + 1024 * 32 + 768 + 255) / 256, 256, 0, stream>>>(
        wedge_A, wedge_b, WO_b, Sbuf, rcbuf, rsbuf, wob);
    gemm_wt<<<dim3(48, 32), 256, 0, stream>>>(A, Wq_w, Wq_b, qbuf, 2048, 3072, 768);
    gemm_wt<<<dim3(12, 32), 256, 0, stream>>>(X, Wk_w, Wk_b, kbbuf, 2048, 768, 768);
    q_transform<<<24576, 256, 0, stream>>>(qbuf, Sbuf, rcbuf, rsbuf);
    k_transform<<<24576, 256, 0, stream>>>(kbbuf, kfbuf, Sbuf, rcbuf, rsbuf);
    attn_kernel<<<24576, 256, 0, stream>>>(qbuf, kfbuf, kbbuf, sink, v_nulls,
                                           fc_w, fc_b, proj_w, proj_b, ctx);
    gemm_kn<<<dim3(12, 32), 256, 0, stream>>>(ctx, WO, wob, out, 2048, 768, 3072, 0.25f);
}

// Round 2
// 1848.657 us; speedup vs baseline: 2.1115x; 2.1115x over previous
//
#include <hip/hip_runtime.h>
#include <math.h>

#define B_   2
#define T_   1024
#define C_   768
#define DH_  64
#define NH_  12
#define HT_  48

__device__ __forceinline__ float wave_sum(float v) {
#pragma unroll
    for (int off = 32; off; off >>= 1) v += __shfl_xor(v, off, 64);
    return v;
}
__device__ __forceinline__ float wave_max(float v) {
#pragma unroll
    for (int off = 32; off; off >>= 1) v = fmaxf(v, __shfl_xor(v, off, 64));
    return v;
}

// ---------------------------------------------------------------- prep
__global__ void prep_kernel(const float* __restrict__ wA, const float* __restrict__ wb,
                            const float* __restrict__ WOb,
                            float* __restrict__ S, float* __restrict__ rc,
                            float* __restrict__ rs, float* __restrict__ wob) {
    int i = blockIdx.x * 256 + threadIdx.x;
    if (i < HT_ * 64 * 64) {
        int e = i & 63, d = (i >> 6) & 63, h = i >> 12;
        float v = wA[d * 64 + e] - wA[e * 64 + d];
        if (d == e) v += wb[h * 64 + d];
        S[i] = v;
    } else if (i < HT_ * 64 * 64 + T_ * 32) {
        int j = i - HT_ * 64 * 64;
        int t = j >> 5, f = j & 31;
        float invf = (float)(1.0 / pow(10000.0, (double)f / 32.0));
        float fr = (float)t * invf;
        rc[j] = cosf(fr);
        rs[j] = sinf(fr);
    } else if (i < HT_ * 64 * 64 + T_ * 32 + C_) {
        int d = i - (HT_ * 64 * 64 + T_ * 32);
        wob[d] = WOb[d] + WOb[C_ + d] + WOb[2 * C_ + d] + WOb[3 * C_ + d];
    }
}

// ---------------------------------------------------------------- GEMM, W as (N,K):  C = A @ W^T + bias
__global__ __launch_bounds__(256) void gemm_wt(const float* __restrict__ A, const float* __restrict__ W,
                                               const float* __restrict__ bias, float* __restrict__ C,
                                               int M, int N, int K) {
    __shared__ float As[16][68];
    __shared__ float Ws[16][68];
    const int bm = blockIdx.y * 64, bn = blockIdx.x * 64;
    const int tid = threadIdx.x;
    const int tx = tid & 15, ty = tid >> 4;
    float acc[4][4] = {};
    const int mm = tid >> 2;
    const int kk4 = (tid & 3) * 4;
    for (int k0 = 0; k0 < K; k0 += 16) {
        float4 av = *reinterpret_cast<const float4*>(&A[(size_t)(bm + mm) * K + k0 + kk4]);
        As[kk4 + 0][mm] = av.x; As[kk4 + 1][mm] = av.y; As[kk4 + 2][mm] = av.z; As[kk4 + 3][mm] = av.w;
        float4 wv = *reinterpret_cast<const float4*>(&W[(size_t)(bn + mm) * K + k0 + kk4]);
        Ws[kk4 + 0][mm] = wv.x; Ws[kk4 + 1][mm] = wv.y; Ws[kk4 + 2][mm] = wv.z; Ws[kk4 + 3][mm] = wv.w;
        __syncthreads();
#pragma unroll
        for (int kk = 0; kk < 16; kk++) {
            float a0 = As[kk][ty * 4 + 0], a1 = As[kk][ty * 4 + 1], a2 = As[kk][ty * 4 + 2], a3 = As[kk][ty * 4 + 3];
            float b0 = Ws[kk][tx * 4 + 0], b1 = Ws[kk][tx * 4 + 1], b2 = Ws[kk][tx * 4 + 2], b3 = Ws[kk][tx * 4 + 3];
            acc[0][0] += a0 * b0; acc[0][1] += a0 * b1; acc[0][2] += a0 * b2; acc[0][3] += a0 * b3;
            acc[1][0] += a1 * b0; acc[1][1] += a1 * b1; acc[1][2] += a1 * b2; acc[1][3] += a1 * b3;
            acc[2][0] += a2 * b0; acc[2][1] += a2 * b1; acc[2][2] += a2 * b2; acc[2][3] += a2 * b3;
            acc[3][0] += a3 * b0; acc[3][1] += a3 * b1; acc[3][2] += a3 * b2; acc[3][3] += a3 * b3;
        }
        __syncthreads();
    }
#pragma unroll
    for (int i = 0; i < 4; i++) {
        float4 o;
        o.x = acc[i][0] + bias[bn + tx * 4 + 0];
        o.y = acc[i][1] + bias[bn + tx * 4 + 1];
        o.z = acc[i][2] + bias[bn + tx * 4 + 2];
        o.w = acc[i][3] + bias[bn + tx * 4 + 3];
        *reinterpret_cast<float4*>(&C[(size_t)(bm + ty * 4 + i) * N + bn + tx * 4]) = o;
    }
}

// ---------------------------------------------------------------- GEMM, W as (K,N):  C = (A @ W + bias) * scl
__global__ __launch_bounds__(256) void gemm_kn(const float* __restrict__ A, const float* __restrict__ W,
                                               const float* __restrict__ bias, float* __restrict__ C,
                                               int M, int N, int K, float scl) {
    __shared__ float As[16][68];
    __shared__ float Ws[16][68];
    const int bm = blockIdx.y * 64, bn = blockIdx.x * 64;
    const int tid = threadIdx.x;
    const int tx = tid & 15, ty = tid >> 4;
    float acc[4][4] = {};
    const int mm = tid >> 2;
    const int kk4 = (tid & 3) * 4;
    const int wkk = tid >> 4;
    const int wnn = (tid & 15) * 4;
    for (int k0 = 0; k0 < K; k0 += 16) {
        float4 av = *reinterpret_cast<const float4*>(&A[(size_t)(bm + mm) * K + k0 + kk4]);
        As[kk4 + 0][mm] = av.x; As[kk4 + 1][mm] = av.y; As[kk4 + 2][mm] = av.z; As[kk4 + 3][mm] = av.w;
        float4 wv = *reinterpret_cast<const float4*>(&W[(size_t)(k0 + wkk) * N + bn + wnn]);
        Ws[wkk][wnn + 0] = wv.x; Ws[wkk][wnn + 1] = wv.y; Ws[wkk][wnn + 2] = wv.z; Ws[wkk][wnn + 3] = wv.w;
        __syncthreads();
#pragma unroll
        for (int kk = 0; kk < 16; kk++) {
            float a0 = As[kk][ty * 4 + 0], a1 = As[kk][ty * 4 + 1], a2 = As[kk][ty * 4 + 2], a3 = As[kk][ty * 4 + 3];
            float b0 = Ws[kk][tx * 4 + 0], b1 = Ws[kk][tx * 4 + 1], b2 = Ws[kk][tx * 4 + 2], b3 = Ws[kk][tx * 4 + 3];
            acc[0][0] += a0 * b0; acc[0][1] += a0 * b1; acc[0][2] += a0 * b2; acc[0][3] += a0 * b3;
            acc[1][0] += a1 * b0; acc[1][1] += a1 * b1; acc[1][2] += a1 * b2; acc[1][3] += a1 * b3;
            acc[2][0] += a2 * b0; acc[2][1] += a2 * b1; acc[2][2] += a2 * b2; acc[2][3] += a2 * b3;
            acc[3][0] += a3 * b0; acc[3][1] += a3 * b1; acc[3][2] += a3 * b2; acc[3][3] += a3 * b3;
        }
        __syncthreads();
    }
#pragma unroll
    for (int i = 0; i < 4; i++) {
        float4 o;
        o.x = (acc[i][0] + bias[bn + tx * 4 + 0]) * scl;
        o.y = (acc[i][1] + bias[bn + tx * 4 + 1]) * scl;
        o.z = (acc[i][2] + bias[bn + tx * 4 + 2]) * scl;
        o.w = (acc[i][3] + bias[bn + tx * 4 + 3]) * scl;
        *reinterpret_cast<float4*>(&C[(size_t)(bm + ty * 4 + i) * N + bn + tx * 4]) = o;
    }
}

// ---------------------------------------------------------------- q transform (in place): rmsnorm -> wedge -> rope
__global__ __launch_bounds__(256) void q_transform(float* __restrict__ q, const float* __restrict__ S,
                                                   const float* __restrict__ rc, const float* __restrict__ rs) {
    const int tid = threadIdx.x, wv = tid >> 6, lane = tid & 63;
    const int row = blockIdx.x * 4 + wv;
    const int h = row % 48;
    const int t = (row / 48) & (T_ - 1);
    float* rowp = q + ((size_t)row << 6);
    __shared__ float sh[4][64];
    float v = rowp[lane];
    float ss = wave_sum(v * v);
    v *= 1.f / sqrtf(ss * (1.f / 64.f) + 1.1920928955078125e-07f);
    sh[wv][lane] = v;
    __syncthreads();
    const float* Sh = S + h * 4096;
    float acc = v;
#pragma unroll 8
    for (int d = 0; d < 64; d++) acc += sh[wv][d] * Sh[d * 64 + lane];
    __syncthreads();
    sh[wv][lane] = acc;
    __syncthreads();
    int j = lane & 31;
    float x1 = sh[wv][2 * j], x2 = sh[wv][2 * j + 1];
    float cth = rc[t * 32 + j], sth = rs[t * 32 + j];
    rowp[lane] = (lane < 32) ? (x1 * cth - x2 * sth) : (x1 * sth + x2 * cth);
}

// ---------------------------------------------------------------- k transform
__global__ __launch_bounds__(256) void k_transform(const float* __restrict__ kb, float* __restrict__ kf,
                                                   const float* __restrict__ S,
                                                   const float* __restrict__ rc, const float* __restrict__ rs) {
    const int tid = threadIdx.x, wv = tid >> 6, lane = tid & 63;
    const int row = blockIdx.x * 4 + wv;
    const int t = row & (T_ - 1);
    const int bh = row >> 10;
    const int h = bh % 48;
    const int b = bh / 48;
    const int hk = h % 12;
    __shared__ float sh[4][64];
    float v = kb[(((size_t)(b * T_ + t) * 12 + hk) << 6) + lane];
    sh[wv][lane] = v;
    __syncthreads();
    const float* Sh = S + h * 4096;
    float acc = v;
#pragma unroll 8
    for (int d = 0; d < 64; d++) acc += sh[wv][d] * Sh[d * 64 + lane];
    __syncthreads();
    sh[wv][lane] = acc;
    __syncthreads();
    int j = lane & 31;
    float x1 = sh[wv][2 * j], x2 = sh[wv][2 * j + 1];
    float cth = rc[t * 32 + j], sth = rs[t * 32 + j];
    kf[((size_t)row << 6) + lane] = (lane < 32) ? (x1 * cth - x2 * sth) : (x1 * sth + x2 * cth);
}

// ---------------------------------------------------------------- fused attention + topk + MLP (LDS-staged)
// one wave per (b,h,t); block = 4 consecutive t of same (b,h)
// All k-chunk and weight reads go through a 16KB swizzled LDS tile:
//   tile[row][slot^(row&7)] — bank-balanced for both cooperative coalesced
//   writes (16 lanes per 256B row) and per-lane row reads (ds_read_b128).
__global__ __launch_bounds__(256) void attn_kernel(
    const float* __restrict__ q,      // (B,T,48,64) transformed
    const float* __restrict__ kf,     // (B,48,T,64) transformed
    const float* __restrict__ kb,     // (B,T,12,64) vanilla
    const float* __restrict__ sink_s, // (48)
    const float* __restrict__ v_nulls,// (48*64)
    const float* __restrict__ fc_w,   // (256,64)
    const float* __restrict__ fc_b,   // (256)
    const float* __restrict__ proj_w, // (64,256)
    const float* __restrict__ proj_b, // (64)
    float* __restrict__ ctx)          // (B,T,48,64)
{
    const int tid = threadIdx.x, wv = tid >> 6, lane = tid & 63;
    const int bid = blockIdx.x;
    const int tgrp = bid & 255;
    const int h = (bid >> 8) % 48;
    const int b = bid / (48 * 256);
    const int t = tgrp * 4 + wv;
    const int hk = h % 12;

    __shared__ float4 ksh[64 * 16];   // 16KB swizzled staging tile
    __shared__ float mksh[4][64];
    __shared__ float hsh[4][256];

    // q row in registers
    const float* qrow = q + (((size_t)(b * T_ + t) * 48 + h) << 6);
    float4 qv[16];
#pragma unroll
    for (int i = 0; i < 16; i++) qv[i] = reinterpret_cast<const float4*>(qrow)[i];

    const float* kbase = kf + (((size_t)(b * 48 + h) * T_) << 6);
    // t>>6 is identical for all 4 waves of a block (t-groups don't straddle 64)
    const int nch = (tgrp >> 4) + 1;
    float sc[16];
#pragma unroll
    for (int c = 0; c < 16; c++) sc[c] = -1e30f;

#pragma unroll
    for (int c = 0; c < 16; c++) {
        if (c < nch) {  // block-uniform
            // cooperative coalesced stage of k chunk c (64 rows x 256B)
#pragma unroll
            for (int i = 0; i < 4; i++) {
                int idx = tid + 256 * i;
                int row = idx >> 4, slot = idx & 15;
                float4 v = *reinterpret_cast<const float4*>(
                    kbase + (((size_t)(c * 64 + row)) << 6) + slot * 4);
                ksh[row * 16 + (slot ^ (row & 7))] = v;
            }
            __syncthreads();
            float acc = 0.f;
#pragma unroll
            for (int j = 0; j < 16; j++) {
                float4 kv = ksh[lane * 16 + (j ^ (lane & 7))];
                acc += qv[j].x * kv.x + qv[j].y * kv.y + qv[j].z * kv.z + qv[j].w * kv.w;
            }
            int s = (c << 6) + lane;
            sc[c] = (s <= t) ? acc * 0.125f : -1e30f;
            __syncthreads();
        }
    }

    // softmax stats (max includes sink)
    float M = -1e30f;
#pragma unroll
    for (int c = 0; c < 16; c++) M = fmaxf(M, sc[c]);
    M = wave_max(M);
    const float sink = sink_s[h];
    M = fmaxf(M, sink);
    float Zl = 0.f;
#pragma unroll
    for (int c = 0; c < 16; c++) Zl += expf(sc[c] - M);
    float Z = wave_sum(Zl) + expf(sink - M);
    const float invZ = 1.f / Z;

    // per-lane top-12 (sorted desc, static indices only)
    float lv[12]; int ls[12];
#pragma unroll
    for (int i = 0; i < 12; i++) { lv[i] = -1e30f; ls[i] = 0; }
#pragma unroll
    for (int c = 0; c < 16; c++) {
        float cv = sc[c]; int cs = (c << 6) + lane;
        if (cv > lv[11]) {
#pragma unroll
            for (int j = 0; j < 12; j++) {
                if (cv > lv[j]) {
                    float tv = lv[j]; int ts = ls[j];
                    lv[j] = cv; ls[j] = cs;
                    cv = tv; cs = ts;
                }
            }
        }
    }

    // wave merge of per-lane lists, 12 rounds; accumulate marker
    const float* kvan = kb + (((size_t)b * T_ * 12 + hk) << 6);  // + s*768 + lane
    float mk = 0.f;
    for (int r = 0; r < 12; r++) {
        float v = lv[0]; int s2 = ls[0];
#pragma unroll
        for (int off = 1; off < 64; off <<= 1) {
            float ov = __shfl_xor(v, off, 64);
            int os = __shfl_xor(s2, off, 64);
            if (ov > v || (ov == v && os < s2)) { v = ov; s2 = os; }
        }
        if (v > -1e29f) {  // wave-uniform: real candidate
            float w = expf(v - M) * invZ;
            mk += w * kvan[(size_t)s2 * 768 + lane];
        }
        if (ls[0] == s2 && lv[0] == v) {  // pop winner (owner lane)
#pragma unroll
            for (int j = 0; j < 11; j++) { lv[j] = lv[j + 1]; ls[j] = ls[j + 1]; }
            lv[11] = -1e30f; ls[11] = 0;
        }
    }
    mk = (mk + kvan[(size_t)t * 768 + lane]) * (1.f / 13.f);
    mksh[wv][lane] = mk;   // same-wave visibility only; no barrier needed

    // MLP fc (64 -> 256), weights staged through LDS per 64-output chunk
    float hh[4];
#pragma unroll
    for (int rr = 0; rr < 4; rr++) {
#pragma unroll
        for (int i = 0; i < 4; i++) {
            int idx = tid + 256 * i;
            int row = idx >> 4, slot = idx & 15;
            float4 v = *reinterpret_cast<const float4*>(fc_w + ((rr * 64 + row) << 6) + slot * 4);
            ksh[row * 16 + (slot ^ (row & 7))] = v;
        }
        __syncthreads();
        float acc = fc_b[rr * 64 + lane];
#pragma unroll
        for (int j = 0; j < 16; j++) {
            float4 w4 = ksh[lane * 16 + (j ^ (lane & 7))];
            float4 m4 = *reinterpret_cast<const float4*>(&mksh[wv][j * 4]);
            acc += w4.x * m4.x + w4.y * m4.y + w4.z * m4.z + w4.w * m4.w;
        }
        hh[rr] = acc;
        __syncthreads();
    }

    // activation + rmsnorm(256) + gated sigmoid
    float ss = 0.f;
#pragma unroll
    for (int rr = 0; rr < 4; rr++) {
        float x = hh[rr];
        float x2 = x * x;
        float y = x2 + 0.75f * x2 * x;
        hh[rr] = y;
        ss += y * y;
    }
    ss = wave_sum(ss);
    float rinv = 1.f / sqrtf(ss * (1.f / 256.f) + 1.1920928955078125e-07f);
#pragma unroll
    for (int rr = 0; rr < 4; rr++) {
        float y = hh[rr] * rinv;
        hh[rr] = y / (1.f + expf(-1.8137993642342178f * y));
        hsh[wv][rr * 64 + lane] = hh[rr];   // same-wave use only
    }

    // proj (256 -> 64), weights staged through LDS per 64-K chunk
    float pacc = proj_b[lane];
#pragma unroll
    for (int kk = 0; kk < 4; kk++) {
#pragma unroll
        for (int i = 0; i < 4; i++) {
            int idx = tid + 256 * i;
            int row = idx >> 4, slot = idx & 15;   // row = output index o
            float4 v = *reinterpret_cast<const float4*>(proj_w + row * 256 + kk * 64 + slot * 4);
            ksh[row * 16 + (slot ^ (row & 7))] = v;
        }
        __syncthreads();
#pragma unroll
        for (int j = 0; j < 16; j++) {
            float4 w4 = ksh[lane * 16 + (j ^ (lane & 7))];
            float4 h4 = *reinterpret_cast<const float4*>(&hsh[wv][kk * 64 + j * 4]);
            pacc += w4.x * h4.x + w4.y * h4.y + w4.z * h4.z + w4.w * h4.w;
        }
        __syncthreads();
    }
    float psink = expf(sink - M) * invZ;
    pacc += psink * v_nulls[h * 64 + lane];
    ctx[(((size_t)(b * T_ + t) * 48 + h) << 6) + lane] = pacc;
}

// ---------------------------------------------------------------- launch
extern "C" void kernel_launch(void* const* d_in, const int* in_sizes, int n_in,
                              void* d_out, int out_size, void* d_ws, size_t ws_size,
                              hipStream_t stream) {
    (void)in_sizes; (void)n_in; (void)out_size; (void)ws_size;
    const float* A       = (const float*)d_in[0];
    const float* X       = (const float*)d_in[1];
    const float* Wq_w    = (const float*)d_in[2];
    const float* Wq_b    = (const float*)d_in[3];
    const float* Wk_w    = (const float*)d_in[4];
    const float* Wk_b    = (const float*)d_in[5];
    const float* wedge_A = (const float*)d_in[6];
    const float* wedge_b = (const float*)d_in[7];
    const float* sink    = (const float*)d_in[8];
    const float* v_nulls = (const float*)d_in[9];
    const float* fc_w    = (const float*)d_in[10];
    const float* fc_b    = (const float*)d_in[11];
    const float* proj_w  = (const float*)d_in[12];
    const float* proj_b  = (const float*)d_in[13];
    const float* WO      = (const float*)d_in[14];
    const float* WO_b    = (const float*)d_in[15];
    float* out = (float*)d_out;
    float* ws  = (float*)d_ws;

    float* qbuf  = ws;                      // 2048*3072 (in-place transformed)
    float* kbbuf = qbuf + 2048 * 3072;      // 2048*768
    float* kfbuf = kbbuf + 2048 * 768;      // 2*48*1024*64
    float* ctx   = kfbuf + 6291456;         // 2048*3072
    float* Sbuf  = ctx + 6291456;           // 48*64*64
    float* rcbuf = Sbuf + 196608;           // 1024*32
    float* rsbuf = rcbuf + 32768;           // 1024*32
    float* wob   = rsbuf + 32768;           // 768

    prep_kernel<<<(48 * 64 * 64 + 1024 * 32 + 768 + 255) / 256, 256, 0, stream>>>(
        wedge_A, wedge_b, WO_b, Sbuf, rcbuf, rsbuf, wob);
    gemm_wt<<<dim3(48, 32), 256, 0, stream>>>(A, Wq_w, Wq_b, qbuf, 2048, 3072, 768);
    gemm_wt<<<dim3(12, 32), 256, 0, stream>>>(X, Wk_w, Wk_b, kbbuf, 2048, 768, 768);
    q_transform<<<24576, 256, 0, stream>>>(qbuf, Sbuf, rcbuf, rsbuf);
    k_transform<<<24576, 256, 0, stream>>>(kbbuf, kfbuf, Sbuf, rcbuf, rsbuf);
    attn_kernel<<<24576, 256, 0, stream>>>(qbuf, kfbuf, kbbuf, sink, v_nulls,
                                           fc_w, fc_b, proj_w, proj_b, ctx);
    gemm_kn<<<dim3(12, 32), 256, 0, stream>>>(ctx, WO, wob, out, 2048, 768, 3072, 0.25f);
}

// Round 3
// 1640.597 us; speedup vs baseline: 2.3793x; 1.1268x over previous
//
#include <hip/hip_runtime.h>
#include <math.h>

#define B_   2
#define T_   1024
#define C_   768
#define DH_  64
#define NH_  12
#define HT_  48

__device__ __forceinline__ float wave_sum(float v) {
#pragma unroll
    for (int off = 32; off; off >>= 1) v += __shfl_xor(v, off, 64);
    return v;
}

// ---------------------------------------------------------------- prep
__global__ void prep_kernel(const float* __restrict__ wA, const float* __restrict__ wb,
                            const float* __restrict__ WOb,
                            float* __restrict__ S, float* __restrict__ rc,
                            float* __restrict__ rs, float* __restrict__ wob) {
    int i = blockIdx.x * 256 + threadIdx.x;
    if (i < HT_ * 64 * 64) {
        int e = i & 63, d = (i >> 6) & 63, h = i >> 12;
        float v = wA[d * 64 + e] - wA[e * 64 + d];
        if (d == e) v += wb[h * 64 + d];
        S[i] = v;
    } else if (i < HT_ * 64 * 64 + T_ * 32) {
        int j = i - HT_ * 64 * 64;
        int t = j >> 5, f = j & 31;
        float invf = (float)(1.0 / pow(10000.0, (double)f / 32.0));
        float fr = (float)t * invf;
        rc[j] = cosf(fr);
        rs[j] = sinf(fr);
    } else if (i < HT_ * 64 * 64 + T_ * 32 + C_) {
        int d = i - (HT_ * 64 * 64 + T_ * 32);
        wob[d] = WOb[d] + WOb[C_ + d] + WOb[2 * C_ + d] + WOb[3 * C_ + d];
    }
}

// ---------------------------------------------------------------- GEMM, W as (N,K):  C = A @ W^T + bias
__global__ __launch_bounds__(256) void gemm_wt(const float* __restrict__ A, const float* __restrict__ W,
                                               const float* __restrict__ bias, float* __restrict__ C,
                                               int M, int N, int K) {
    __shared__ float As[16][68];
    __shared__ float Ws[16][68];
    const int bm = blockIdx.y * 64, bn = blockIdx.x * 64;
    const int tid = threadIdx.x;
    const int tx = tid & 15, ty = tid >> 4;
    float acc[4][4] = {};
    const int mm = tid >> 2;
    const int kk4 = (tid & 3) * 4;
    for (int k0 = 0; k0 < K; k0 += 16) {
        float4 av = *reinterpret_cast<const float4*>(&A[(size_t)(bm + mm) * K + k0 + kk4]);
        As[kk4 + 0][mm] = av.x; As[kk4 + 1][mm] = av.y; As[kk4 + 2][mm] = av.z; As[kk4 + 3][mm] = av.w;
        float4 wv = *reinterpret_cast<const float4*>(&W[(size_t)(bn + mm) * K + k0 + kk4]);
        Ws[kk4 + 0][mm] = wv.x; Ws[kk4 + 1][mm] = wv.y; Ws[kk4 + 2][mm] = wv.z; Ws[kk4 + 3][mm] = wv.w;
        __syncthreads();
#pragma unroll
        for (int kk = 0; kk < 16; kk++) {
            float a0 = As[kk][ty * 4 + 0], a1 = As[kk][ty * 4 + 1], a2 = As[kk][ty * 4 + 2], a3 = As[kk][ty * 4 + 3];
            float b0 = Ws[kk][tx * 4 + 0], b1 = Ws[kk][tx * 4 + 1], b2 = Ws[kk][tx * 4 + 2], b3 = Ws[kk][tx * 4 + 3];
            acc[0][0] += a0 * b0; acc[0][1] += a0 * b1; acc[0][2] += a0 * b2; acc[0][3] += a0 * b3;
            acc[1][0] += a1 * b0; acc[1][1] += a1 * b1; acc[1][2] += a1 * b2; acc[1][3] += a1 * b3;
            acc[2][0] += a2 * b0; acc[2][1] += a2 * b1; acc[2][2] += a2 * b2; acc[2][3] += a2 * b3;
            acc[3][0] += a3 * b0; acc[3][1] += a3 * b1; acc[3][2] += a3 * b2; acc[3][3] += a3 * b3;
        }
        __syncthreads();
    }
#pragma unroll
    for (int i = 0; i < 4; i++) {
        float4 o;
        o.x = acc[i][0] + bias[bn + tx * 4 + 0];
        o.y = acc[i][1] + bias[bn + tx * 4 + 1];
        o.z = acc[i][2] + bias[bn + tx * 4 + 2];
        o.w = acc[i][3] + bias[bn + tx * 4 + 3];
        *reinterpret_cast<float4*>(&C[(size_t)(bm + ty * 4 + i) * N + bn + tx * 4]) = o;
    }
}

// ---------------------------------------------------------------- GEMM, W as (K,N):  C = (A @ W + bias) * scl
__global__ __launch_bounds__(256) void gemm_kn(const float* __restrict__ A, const float* __restrict__ W,
                                               const float* __restrict__ bias, float* __restrict__ C,
                                               int M, int N, int K, float scl) {
    __shared__ float As[16][68];
    __shared__ float Ws[16][68];
    const int bm = blockIdx.y * 64, bn = blockIdx.x * 64;
    const int tid = threadIdx.x;
    const int tx = tid & 15, ty = tid >> 4;
    float acc[4][4] = {};
    const int mm = tid >> 2;
    const int kk4 = (tid & 3) * 4;
    const int wkk = tid >> 4;
    const int wnn = (tid & 15) * 4;
    for (int k0 = 0; k0 < K; k0 += 16) {
        float4 av = *reinterpret_cast<const float4*>(&A[(size_t)(bm + mm) * K + k0 + kk4]);
        As[kk4 + 0][mm] = av.x; As[kk4 + 1][mm] = av.y; As[kk4 + 2][mm] = av.z; As[kk4 + 3][mm] = av.w;
        float4 wv = *reinterpret_cast<const float4*>(&W[(size_t)(k0 + wkk) * N + bn + wnn]);
        Ws[wkk][wnn + 0] = wv.x; Ws[wkk][wnn + 1] = wv.y; Ws[wkk][wnn + 2] = wv.z; Ws[wkk][wnn + 3] = wv.w;
        __syncthreads();
#pragma unroll
        for (int kk = 0; kk < 16; kk++) {
            float a0 = As[kk][ty * 4 + 0], a1 = As[kk][ty * 4 + 1], a2 = As[kk][ty * 4 + 2], a3 = As[kk][ty * 4 + 3];
            float b0 = Ws[kk][tx * 4 + 0], b1 = Ws[kk][tx * 4 + 1], b2 = Ws[kk][tx * 4 + 2], b3 = Ws[kk][tx * 4 + 3];
            acc[0][0] += a0 * b0; acc[0][1] += a0 * b1; acc[0][2] += a0 * b2; acc[0][3] += a0 * b3;
            acc[1][0] += a1 * b0; acc[1][1] += a1 * b1; acc[1][2] += a1 * b2; acc[1][3] += a1 * b3;
            acc[2][0] += a2 * b0; acc[2][1] += a2 * b1; acc[2][2] += a2 * b2; acc[2][3] += a2 * b3;
            acc[3][0] += a3 * b0; acc[3][1] += a3 * b1; acc[3][2] += a3 * b2; acc[3][3] += a3 * b3;
        }
        __syncthreads();
    }
#pragma unroll
    for (int i = 0; i < 4; i++) {
        float4 o;
        o.x = (acc[i][0] + bias[bn + tx * 4 + 0]) * scl;
        o.y = (acc[i][1] + bias[bn + tx * 4 + 1]) * scl;
        o.z = (acc[i][2] + bias[bn + tx * 4 + 2]) * scl;
        o.w = (acc[i][3] + bias[bn + tx * 4 + 3]) * scl;
        *reinterpret_cast<float4*>(&C[(size_t)(bm + ty * 4 + i) * N + bn + tx * 4]) = o;
    }
}

// ---------------------------------------------------------------- q transform (in place): rmsnorm -> wedge -> rope
__global__ __launch_bounds__(256) void q_transform(float* __restrict__ q, const float* __restrict__ S,
                                                   const float* __restrict__ rc, const float* __restrict__ rs) {
    const int tid = threadIdx.x, wv = tid >> 6, lane = tid & 63;
    const int row = blockIdx.x * 4 + wv;
    const int h = row % 48;
    const int t = (row / 48) & (T_ - 1);
    float* rowp = q + ((size_t)row << 6);
    __shared__ float sh[4][64];
    float v = rowp[lane];
    float ss = wave_sum(v * v);
    v *= 1.f / sqrtf(ss * (1.f / 64.f) + 1.1920928955078125e-07f);
    sh[wv][lane] = v;
    __syncthreads();
    const float* Sh = S + h * 4096;
    float acc = v;
#pragma unroll 8
    for (int d = 0; d < 64; d++) acc += sh[wv][d] * Sh[d * 64 + lane];
    __syncthreads();
    sh[wv][lane] = acc;
    __syncthreads();
    int j = lane & 31;
    float x1 = sh[wv][2 * j], x2 = sh[wv][2 * j + 1];
    float cth = rc[t * 32 + j], sth = rs[t * 32 + j];
    rowp[lane] = (lane < 32) ? (x1 * cth - x2 * sth) : (x1 * sth + x2 * cth);
}

// ---------------------------------------------------------------- k transform
__global__ __launch_bounds__(256) void k_transform(const float* __restrict__ kb, float* __restrict__ kf,
                                                   const float* __restrict__ S,
                                                   const float* __restrict__ rc, const float* __restrict__ rs) {
    const int tid = threadIdx.x, wv = tid >> 6, lane = tid & 63;
    const int row = blockIdx.x * 4 + wv;
    const int t = row & (T_ - 1);
    const int bh = row >> 10;
    const int h = bh % 48;
    const int b = bh / 48;
    const int hk = h % 12;
    __shared__ float sh[4][64];
    float v = kb[(((size_t)(b * T_ + t) * 12 + hk) << 6) + lane];
    sh[wv][lane] = v;
    __syncthreads();
    const float* Sh = S + h * 4096;
    float acc = v;
#pragma unroll 8
    for (int d = 0; d < 64; d++) acc += sh[wv][d] * Sh[d * 64 + lane];
    __syncthreads();
    sh[wv][lane] = acc;
    __syncthreads();
    int j = lane & 31;
    float x1 = sh[wv][2 * j], x2 = sh[wv][2 * j + 1];
    float cth = rc[t * 32 + j], sth = rs[t * 32 + j];
    kf[((size_t)row << 6) + lane] = (lane < 32) ? (x1 * cth - x2 * sth) : (x1 * sth + x2 * cth);
}

// ---------------------------------------------------------------- fused attention + topk + marker
// one wave (=one block, 64 threads) per 64 q-rows; lane = row.
// k-chunks staged once per wave into LDS, read broadcast (uniform addr).
__global__ __launch_bounds__(64, 1) void attn_kernel(
    const float* __restrict__ q,      // (B,T,48,64) transformed
    const float* __restrict__ kf,     // (B,48,T,64) transformed
    const float* __restrict__ kb,     // (B,T,12,64) vanilla
    const float* __restrict__ sink_s, // (48)
    float* __restrict__ mkbuf,        // (B*48*1024, 64) marker/13
    float* __restrict__ psbuf)        // (B*48*1024) sink prob
{
    const int lane = threadIdx.x;
    const int bid = blockIdx.x;
    const int tile = 15 - bid / 96;   // heavy tiles dispatched first
    const int bh = bid % 96;
    const int h = bh % 48;
    const int b = bh / 48;
    const int t = (tile << 6) + lane;
    const int nch = tile + 1;
    const int hk = h % 12;

    __shared__ float ksh[64 * 64];

    // q row in registers (lane-local)
    const float* qrow = q + (((size_t)((b << 10) + t) * 48 + h) << 6);
    float4 qv[16];
#pragma unroll
    for (int i = 0; i < 16; i++) qv[i] = reinterpret_cast<const float4*>(qrow)[i];

    const float4* ksrc = reinterpret_cast<const float4*>(kf + (((size_t)(b * 48 + h)) << 16));
    float4* kshv = reinterpret_cast<float4*>(ksh);

    float M = -1e30f, Z = 0.f;
    float lv[12]; int ls[12];
#pragma unroll
    for (int i = 0; i < 12; i++) { lv[i] = -1e30f; ls[i] = 0; }

    // prefetch chunk 0
    float4 pf[16];
#pragma unroll
    for (int i = 0; i < 16; i++) pf[i] = ksrc[(i << 6) + lane];

    for (int c = 0; c < nch; c++) {
#pragma unroll
        for (int i = 0; i < 16; i++) kshv[(i << 6) + lane] = pf[i];
        if (c + 1 < nch) {  // wave-uniform
            const float4* nsrc = ksrc + ((size_t)(c + 1) << 10);
#pragma unroll
            for (int i = 0; i < 16; i++) pf[i] = nsrc[(i << 6) + lane];
        }
        __syncthreads();
#pragma unroll 4
        for (int j = 0; j < 64; j++) {
            const float4* kj = reinterpret_cast<const float4*>(ksh + (j << 6));  // broadcast
            float ax = 0.f, ay = 0.f, az = 0.f, aw = 0.f;
#pragma unroll
            for (int i = 0; i < 16; i++) {
                float4 kv = kj[i];
                ax = fmaf(qv[i].x, kv.x, ax);
                ay = fmaf(qv[i].y, kv.y, ay);
                az = fmaf(qv[i].z, kv.z, az);
                aw = fmaf(qv[i].w, kv.w, aw);
            }
            int col = (c << 6) + j;
            float s = ((ax + ay) + (az + aw)) * 0.125f;
            s = (col <= t) ? s : -1e30f;
            float nm = fmaxf(M, s);
            Z = Z * __expf(M - nm) + __expf(s - nm);
            M = nm;
            if (s > lv[11]) {  // lane-local sorted top-12 insert (static indices)
                float cv = s; int cs = col;
#pragma unroll
                for (int jj = 0; jj < 12; jj++) {
                    if (cv > lv[jj]) {
                        float tv = lv[jj]; int ts = ls[jj];
                        lv[jj] = cv; ls[jj] = cs;
                        cv = tv; cs = ts;
                    }
                }
            }
        }
        __syncthreads();
    }

    const float sink = sink_s[h];
    float ms = fmaxf(M, sink);
    float Zf = Z * __expf(M - ms) + __expf(sink - ms);
    float invZ = 1.f / Zf;

    // marker gather (lane-local rows from vanilla k)
    const float* kvan = kb + (((size_t)b * 12288 + hk) << 6);
    float4 mk[16];
#pragma unroll
    for (int i = 0; i < 16; i++) mk[i] = make_float4(0.f, 0.f, 0.f, 0.f);
#pragma unroll
    for (int r = 0; r < 12; r++) {
        float w = __expf(lv[r] - ms) * invZ;   // exactly 0 for empty slots
        const float4* krow = reinterpret_cast<const float4*>(kvan + (size_t)ls[r] * 768);
#pragma unroll
        for (int i = 0; i < 16; i++) {
            float4 kv = krow[i];
            mk[i].x = fmaf(w, kv.x, mk[i].x);
            mk[i].y = fmaf(w, kv.y, mk[i].y);
            mk[i].z = fmaf(w, kv.z, mk[i].z);
            mk[i].w = fmaf(w, kv.w, mk[i].w);
        }
    }
    const float4* srow = reinterpret_cast<const float4*>(kvan + (size_t)t * 768);
    const size_t orow = ((size_t)(b * 48 + h) << 10) + t;
    float4* mout = reinterpret_cast<float4*>(mkbuf + (orow << 6));
#pragma unroll
    for (int i = 0; i < 16; i++) {
        float4 sv = srow[i];
        float4 o;
        o.x = (mk[i].x + sv.x) * (1.f / 13.f);
        o.y = (mk[i].y + sv.y) * (1.f / 13.f);
        o.z = (mk[i].z + sv.z) * (1.f / 13.f);
        o.w = (mk[i].w + sv.w) * (1.f / 13.f);
        mout[i] = o;
    }
    psbuf[orow] = __expf(sink - ms) * invZ;
}

// ---------------------------------------------------------------- activation + rmsnorm(256) + gate, in place
__global__ __launch_bounds__(256) void act_kernel(float* __restrict__ hb) {
    const int tid = threadIdx.x, wv = tid >> 6, lane = tid & 63;
    const size_t row = (size_t)blockIdx.x * 4 + wv;
    float4* p = reinterpret_cast<float4*>(hb + (row << 8)) + lane;
    float4 x = *p;
    float4 y;
    y.x = x.x * x.x + 0.75f * x.x * x.x * x.x;
    y.y = x.y * x.y + 0.75f * x.y * x.y * x.y;
    y.z = x.z * x.z + 0.75f * x.z * x.z * x.z;
    y.w = x.w * x.w + 0.75f * x.w * x.w * x.w;
    float ss = wave_sum(y.x * y.x + y.y * y.y + y.z * y.z + y.w * y.w);
    float rinv = 1.f / sqrtf(ss * (1.f / 256.f) + 1.1920928955078125e-07f);
    float4 g;
    float zx = y.x * rinv, zy = y.y * rinv, zz = y.z * rinv, zw = y.w * rinv;
    g.x = zx / (1.f + __expf(-1.8137993642342178f * zx));
    g.y = zy / (1.f + __expf(-1.8137993642342178f * zy));
    g.z = zz / (1.f + __expf(-1.8137993642342178f * zz));
    g.w = zw / (1.f + __expf(-1.8137993642342178f * zw));
    *p = g;
}

// ---------------------------------------------------------------- proj GEMM (N=64, K=256) + sink epilogue -> ctx
__global__ __launch_bounds__(256) void proj_gemm(const float* __restrict__ A, const float* __restrict__ W,
                                                 const float* __restrict__ bias, const float* __restrict__ ps,
                                                 const float* __restrict__ vn, float* __restrict__ ctx,
                                                 int rowbase) {
    __shared__ float As[16][68];
    __shared__ float Ws[16][68];
    const int bm = blockIdx.y * 64;
    const int tid = threadIdx.x;
    const int tx = tid & 15, ty = tid >> 4;
    float acc[4][4] = {};
    const int mm = tid >> 2;
    const int kk4 = (tid & 3) * 4;
    for (int k0 = 0; k0 < 256; k0 += 16) {
        float4 av = *reinterpret_cast<const float4*>(&A[(size_t)(bm + mm) * 256 + k0 + kk4]);
        As[kk4 + 0][mm] = av.x; As[kk4 + 1][mm] = av.y; As[kk4 + 2][mm] = av.z; As[kk4 + 3][mm] = av.w;
        float4 wv = *reinterpret_cast<const float4*>(&W[(size_t)mm * 256 + k0 + kk4]);
        Ws[kk4 + 0][mm] = wv.x; Ws[kk4 + 1][mm] = wv.y; Ws[kk4 + 2][mm] = wv.z; Ws[kk4 + 3][mm] = wv.w;
        __syncthreads();
#pragma unroll
        for (int kk = 0; kk < 16; kk++) {
            float a0 = As[kk][ty * 4 + 0], a1 = As[kk][ty * 4 + 1], a2 = As[kk][ty * 4 + 2], a3 = As[kk][ty * 4 + 3];
            float b0 = Ws[kk][tx * 4 + 0], b1 = Ws[kk][tx * 4 + 1], b2 = Ws[kk][tx * 4 + 2], b3 = Ws[kk][tx * 4 + 3];
            acc[0][0] += a0 * b0; acc[0][1] += a0 * b1; acc[0][2] += a0 * b2; acc[0][3] += a0 * b3;
            acc[1][0] += a1 * b0; acc[1][1] += a1 * b1; acc[1][2] += a1 * b2; acc[1][3] += a1 * b3;
            acc[2][0] += a2 * b0; acc[2][1] += a2 * b1; acc[2][2] += a2 * b2; acc[2][3] += a2 * b3;
            acc[3][0] += a3 * b0; acc[3][1] += a3 * b1; acc[3][2] += a3 * b2; acc[3][3] += a3 * b3;
        }
        __syncthreads();
    }
#pragma unroll
    for (int i = 0; i < 4; i++) {
        int rm = rowbase + bm + ty * 4 + i;
        int g = rm >> 10, t = rm & 1023;
        int hh = g % 48, bb = g / 48;
        float p = ps[rm];
        const float* v = vn + hh * 64 + tx * 4;
        float4 o;
        o.x = acc[i][0] + bias[tx * 4 + 0] + p * v[0];
        o.y = acc[i][1] + bias[tx * 4 + 1] + p * v[1];
        o.z = acc[i][2] + bias[tx * 4 + 2] + p * v[2];
        o.w = acc[i][3] + bias[tx * 4 + 3] + p * v[3];
        *reinterpret_cast<float4*>(&ctx[((((size_t)(bb << 10) + t) * 48 + hh) << 6) + tx * 4]) = o;
    }
}

// ---------------------------------------------------------------- launch
extern "C" void kernel_launch(void* const* d_in, const int* in_sizes, int n_in,
                              void* d_out, int out_size, void* d_ws, size_t ws_size,
                              hipStream_t stream) {
    (void)in_sizes; (void)n_in; (void)out_size; (void)ws_size;
    const float* A       = (const float*)d_in[0];
    const float* X       = (const float*)d_in[1];
    const float* Wq_w    = (const float*)d_in[2];
    const float* Wq_b    = (const float*)d_in[3];
    const float* Wk_w    = (const float*)d_in[4];
    const float* Wk_b    = (const float*)d_in[5];
    const float* wedge_A = (const float*)d_in[6];
    const float* wedge_b = (const float*)d_in[7];
    const float* sink    = (const float*)d_in[8];
    const float* v_nulls = (const float*)d_in[9];
    const float* fc_w    = (const float*)d_in[10];
    const float* fc_b    = (const float*)d_in[11];
    const float* proj_w  = (const float*)d_in[12];
    const float* proj_b  = (const float*)d_in[13];
    const float* WO      = (const float*)d_in[14];
    const float* WO_b    = (const float*)d_in[15];
    float* out = (float*)d_out;
    float* ws  = (float*)d_ws;

    // layout (floats). ctx overlays qbuf (dead after attn); hbuf overlays kb/kf (dead after attn).
    float* qbuf  = ws;                      // 6291456  (B,T,48,64) ; later reused as ctx
    float* ctx   = ws;
    float* kbbuf = ws + 6291456;            // 1572864  (B,T,12,64)
    float* hbuf  = ws + 6291456;            // 6291456  (24576 x 256) per segment, overlays kb/kf
    float* kfbuf = ws + 7864320;            // 6291456  (B,48,T,64)
    float* mkbuf = ws + 14155776;           // 6291456  (B*48*1024, 64)
    float* psbuf = ws + 20447232;           // 98304
    float* Sbuf  = ws + 20545536;           // 196608
    float* rcbuf = ws + 20742144;           // 32768
    float* rsbuf = ws + 20774912;           // 32768
    float* wob   = ws + 20807680;           // 768

    prep_kernel<<<(48 * 64 * 64 + 1024 * 32 + 768 + 255) / 256, 256, 0, stream>>>(
        wedge_A, wedge_b, WO_b, Sbuf, rcbuf, rsbuf, wob);
    gemm_wt<<<dim3(48, 32), 256, 0, stream>>>(A, Wq_w, Wq_b, qbuf, 2048, 3072, 768);
    gemm_wt<<<dim3(12, 32), 256, 0, stream>>>(X, Wk_w, Wk_b, kbbuf, 2048, 768, 768);
    q_transform<<<24576, 256, 0, stream>>>(qbuf, Sbuf, rcbuf, rsbuf);
    k_transform<<<24576, 256, 0, stream>>>(kbbuf, kfbuf, Sbuf, rcbuf, rsbuf);
    attn_kernel<<<1536, 64, 0, stream>>>(qbuf, kfbuf, kbbuf, sink, mkbuf, psbuf);
    for (int seg = 0; seg < 4; seg++) {
        const int rowbase = seg * 24576;
        gemm_wt<<<dim3(4, 384), 256, 0, stream>>>(mkbuf + (size_t)rowbase * 64, fc_w, fc_b,
                                                  hbuf, 24576, 256, 64);
        act_kernel<<<6144, 256, 0, stream>>>(hbuf);
        proj_gemm<<<dim3(1, 384), 256, 0, stream>>>(hbuf, proj_w, proj_b, psbuf, v_nulls,
                                                    ctx, rowbase);
    }
    gemm_kn<<<dim3(12, 32), 256, 0, stream>>>(ctx, WO, wob, out, 2048, 768, 3072, 0.25f);
}

// Round 4
// 1025.109 us; speedup vs baseline: 3.8078x; 1.6004x over previous
//
#include <hip/hip_runtime.h>
#include <math.h>

#define B_   2
#define T_   1024
#define C_   768
#define DH_  64
#define NH_  12
#define HT_  48

__device__ __forceinline__ float wave_sum(float v) {
#pragma unroll
    for (int off = 32; off; off >>= 1) v += __shfl_xor(v, off, 64);
    return v;
}

// phase-A work tables: 40 (tile,part) units per (b,h), sorted heavy-first.
__constant__ int c_tileTab[40] = {15,15,15,15, 14,14,14, 13,13,13, 12,12,12, 11,11,11,
                                  10,10, 9,9, 8,8, 7,7, 6, 5, 4, 3,
                                  14,10,6,2, 13,9,5,1, 12,8,4,0};
__constant__ int c_partTab[40] = { 0, 1, 2, 3,  0, 1, 2,  0, 1, 2,  0, 1, 2,  0, 1, 2,
                                   0, 1, 0,1, 0,1, 0,1, 0, 0, 0, 0,
                                   3, 2,1,0,  3,2,1,0,  3,2,1,0};

// ---------------------------------------------------------------- prep
__global__ void prep_kernel(const float* __restrict__ wA, const float* __restrict__ wb,
                            const float* __restrict__ WOb,
                            float* __restrict__ S, float* __restrict__ rc,
                            float* __restrict__ rs, float* __restrict__ wob) {
    int i = blockIdx.x * 256 + threadIdx.x;
    if (i < HT_ * 64 * 64) {
        int e = i & 63, d = (i >> 6) & 63, h = i >> 12;
        float v = wA[d * 64 + e] - wA[e * 64 + d];
        if (d == e) v += wb[h * 64 + d];
        S[i] = v;
    } else if (i < HT_ * 64 * 64 + T_ * 32) {
        int j = i - HT_ * 64 * 64;
        int t = j >> 5, f = j & 31;
        float invf = (float)(1.0 / pow(10000.0, (double)f / 32.0));
        float fr = (float)t * invf;
        rc[j] = cosf(fr);
        rs[j] = sinf(fr);
    } else if (i < HT_ * 64 * 64 + T_ * 32 + C_) {
        int d = i - (HT_ * 64 * 64 + T_ * 32);
        wob[d] = WOb[d] + WOb[C_ + d] + WOb[2 * C_ + d] + WOb[3 * C_ + d];
    }
}

// ---------------------------------------------------------------- GEMM, W as (N,K):  C = A @ W^T + bias
__global__ __launch_bounds__(256) void gemm_wt(const float* __restrict__ A, const float* __restrict__ W,
                                               const float* __restrict__ bias, float* __restrict__ C,
                                               int M, int N, int K) {
    __shared__ float As[16][68];
    __shared__ float Ws[16][68];
    const int bm = blockIdx.y * 64, bn = blockIdx.x * 64;
    const int tid = threadIdx.x;
    const int tx = tid & 15, ty = tid >> 4;
    float acc[4][4] = {};
    const int mm = tid >> 2;
    const int kk4 = (tid & 3) * 4;
    for (int k0 = 0; k0 < K; k0 += 16) {
        float4 av = *reinterpret_cast<const float4*>(&A[(size_t)(bm + mm) * K + k0 + kk4]);
        As[kk4 + 0][mm] = av.x; As[kk4 + 1][mm] = av.y; As[kk4 + 2][mm] = av.z; As[kk4 + 3][mm] = av.w;
        float4 wv = *reinterpret_cast<const float4*>(&W[(size_t)(bn + mm) * K + k0 + kk4]);
        Ws[kk4 + 0][mm] = wv.x; Ws[kk4 + 1][mm] = wv.y; Ws[kk4 + 2][mm] = wv.z; Ws[kk4 + 3][mm] = wv.w;
        __syncthreads();
#pragma unroll
        for (int kk = 0; kk < 16; kk++) {
            float a0 = As[kk][ty * 4 + 0], a1 = As[kk][ty * 4 + 1], a2 = As[kk][ty * 4 + 2], a3 = As[kk][ty * 4 + 3];
            float b0 = Ws[kk][tx * 4 + 0], b1 = Ws[kk][tx * 4 + 1], b2 = Ws[kk][tx * 4 + 2], b3 = Ws[kk][tx * 4 + 3];
            acc[0][0] += a0 * b0; acc[0][1] += a0 * b1; acc[0][2] += a0 * b2; acc[0][3] += a0 * b3;
            acc[1][0] += a1 * b0; acc[1][1] += a1 * b1; acc[1][2] += a1 * b2; acc[1][3] += a1 * b3;
            acc[2][0] += a2 * b0; acc[2][1] += a2 * b1; acc[2][2] += a2 * b2; acc[2][3] += a2 * b3;
            acc[3][0] += a3 * b0; acc[3][1] += a3 * b1; acc[3][2] += a3 * b2; acc[3][3] += a3 * b3;
        }
        __syncthreads();
    }
#pragma unroll
    for (int i = 0; i < 4; i++) {
        float4 o;
        o.x = acc[i][0] + bias[bn + tx * 4 + 0];
        o.y = acc[i][1] + bias[bn + tx * 4 + 1];
        o.z = acc[i][2] + bias[bn + tx * 4 + 2];
        o.w = acc[i][3] + bias[bn + tx * 4 + 3];
        *reinterpret_cast<float4*>(&C[(size_t)(bm + ty * 4 + i) * N + bn + tx * 4]) = o;
    }
}

// ---------------------------------------------------------------- GEMM, W as (K,N):  C = (A @ W + bias) * scl
__global__ __launch_bounds__(256) void gemm_kn(const float* __restrict__ A, const float* __restrict__ W,
                                               const float* __restrict__ bias, float* __restrict__ C,
                                               int M, int N, int K, float scl) {
    __shared__ float As[16][68];
    __shared__ float Ws[16][68];
    const int bm = blockIdx.y * 64, bn = blockIdx.x * 64;
    const int tid = threadIdx.x;
    const int tx = tid & 15, ty = tid >> 4;
    float acc[4][4] = {};
    const int mm = tid >> 2;
    const int kk4 = (tid & 3) * 4;
    const int wkk = tid >> 4;
    const int wnn = (tid & 15) * 4;
    for (int k0 = 0; k0 < K; k0 += 16) {
        float4 av = *reinterpret_cast<const float4*>(&A[(size_t)(bm + mm) * K + k0 + kk4]);
        As[kk4 + 0][mm] = av.x; As[kk4 + 1][mm] = av.y; As[kk4 + 2][mm] = av.z; As[kk4 + 3][mm] = av.w;
        float4 wv = *reinterpret_cast<const float4*>(&W[(size_t)(k0 + wkk) * N + bn + wnn]);
        Ws[wkk][wnn + 0] = wv.x; Ws[wkk][wnn + 1] = wv.y; Ws[wkk][wnn + 2] = wv.z; Ws[wkk][wnn + 3] = wv.w;
        __syncthreads();
#pragma unroll
        for (int kk = 0; kk < 16; kk++) {
            float a0 = As[kk][ty * 4 + 0], a1 = As[kk][ty * 4 + 1], a2 = As[kk][ty * 4 + 2], a3 = As[kk][ty * 4 + 3];
            float b0 = Ws[kk][tx * 4 + 0], b1 = Ws[kk][tx * 4 + 1], b2 = Ws[kk][tx * 4 + 2], b3 = Ws[kk][tx * 4 + 3];
            acc[0][0] += a0 * b0; acc[0][1] += a0 * b1; acc[0][2] += a0 * b2; acc[0][3] += a0 * b3;
            acc[1][0] += a1 * b0; acc[1][1] += a1 * b1; acc[1][2] += a1 * b2; acc[1][3] += a1 * b3;
            acc[2][0] += a2 * b0; acc[2][1] += a2 * b1; acc[2][2] += a2 * b2; acc[2][3] += a2 * b3;
            acc[3][0] += a3 * b0; acc[3][1] += a3 * b1; acc[3][2] += a3 * b2; acc[3][3] += a3 * b3;
        }
        __syncthreads();
    }
#pragma unroll
    for (int i = 0; i < 4; i++) {
        float4 o;
        o.x = (acc[i][0] + bias[bn + tx * 4 + 0]) * scl;
        o.y = (acc[i][1] + bias[bn + tx * 4 + 1]) * scl;
        o.z = (acc[i][2] + bias[bn + tx * 4 + 2]) * scl;
        o.w = (acc[i][3] + bias[bn + tx * 4 + 3]) * scl;
        *reinterpret_cast<float4*>(&C[(size_t)(bm + ty * 4 + i) * N + bn + tx * 4]) = o;
    }
}

// ---------------------------------------------------------------- q transform (in place): rmsnorm -> wedge -> rope
__global__ __launch_bounds__(256) void q_transform(float* __restrict__ q, const float* __restrict__ S,
                                                   const float* __restrict__ rc, const float* __restrict__ rs) {
    const int tid = threadIdx.x, wv = tid >> 6, lane = tid & 63;
    const int row = blockIdx.x * 4 + wv;
    const int h = row % 48;
    const int t = (row / 48) & (T_ - 1);
    float* rowp = q + ((size_t)row << 6);
    __shared__ float sh[4][64];
    float v = rowp[lane];
    float ss = wave_sum(v * v);
    v *= 1.f / sqrtf(ss * (1.f / 64.f) + 1.1920928955078125e-07f);
    sh[wv][lane] = v;
    __syncthreads();
    const float* Sh = S + h * 4096;
    float acc = v;
#pragma unroll 8
    for (int d = 0; d < 64; d++) acc += sh[wv][d] * Sh[d * 64 + lane];
    __syncthreads();
    sh[wv][lane] = acc;
    __syncthreads();
    int j = lane & 31;
    float x1 = sh[wv][2 * j], x2 = sh[wv][2 * j + 1];
    float cth = rc[t * 32 + j], sth = rs[t * 32 + j];
    rowp[lane] = (lane < 32) ? (x1 * cth - x2 * sth) : (x1 * sth + x2 * cth);
}

// ---------------------------------------------------------------- k transform
__global__ __launch_bounds__(256) void k_transform(const float* __restrict__ kb, float* __restrict__ kf,
                                                   const float* __restrict__ S,
                                                   const float* __restrict__ rc, const float* __restrict__ rs) {
    const int tid = threadIdx.x, wv = tid >> 6, lane = tid & 63;
    const int row = blockIdx.x * 4 + wv;
    const int t = row & (T_ - 1);
    const int bh = row >> 10;
    const int h = bh % 48;
    const int b = bh / 48;
    const int hk = h % 12;
    __shared__ float sh[4][64];
    float v = kb[(((size_t)(b * T_ + t) * 12 + hk) << 6) + lane];
    sh[wv][lane] = v;
    __syncthreads();
    const float* Sh = S + h * 4096;
    float acc = v;
#pragma unroll 8
    for (int d = 0; d < 64; d++) acc += sh[wv][d] * Sh[d * 64 + lane];
    __syncthreads();
    sh[wv][lane] = acc;
    __syncthreads();
    int j = lane & 31;
    float x1 = sh[wv][2 * j], x2 = sh[wv][2 * j + 1];
    float cth = rc[t * 32 + j], sth = rs[t * 32 + j];
    kf[((size_t)row << 6) + lane] = (lane < 32) ? (x1 * cth - x2 * sth) : (x1 * sth + x2 * cth);
}

// ---------------------------------------------------------------- phase A: partial scores
// one wave per (b,h,tile,part); lane = row in tile; part = up to 256 columns
// staged as 8 x 32-column LDS chunks. Z without max-stabilization (|s| <~ 10).
// top-12 kept as packed u32 keys: (monotone-float-key & ~1023) | (1023-col).
__global__ __launch_bounds__(64) void attn_scores(
    const float* __restrict__ q,      // (B,T,48,64) transformed (pre-scaled here)
    const float* __restrict__ kf,     // (B,48,T,64) transformed
    float* __restrict__ pZ,           // (B*48*1024, 4)
    unsigned int* __restrict__ pP)    // (B*48*1024, 4, 12)
{
    const int lane = threadIdx.x;
    const int bid = blockIdx.x;
    const int u = bid / 96;           // heavy units first
    const int bh = bid % 96;
    const int tile = c_tileTab[u];
    const int part = c_partTab[u];
    const int h = bh % 48;
    const int b = bh / 48;
    const int t = (tile << 6) + lane;
    const int hc0 = part << 3;
    const int hc1 = min(hc0 + 8, (tile + 1) << 1);

    __shared__ float ksh[32 * 64];
    float4* kshv = reinterpret_cast<float4*>(ksh);

    const float4* qrow = reinterpret_cast<const float4*>(q + (((size_t)((b << 10) + t) * 48 + h) << 6));
    float4 qv[16];
#pragma unroll
    for (int i = 0; i < 16; i++) {
        float4 v = qrow[i];
        qv[i] = make_float4(v.x * 0.125f, v.y * 0.125f, v.z * 0.125f, v.w * 0.125f);
    }
    const float4* kfb = reinterpret_cast<const float4*>(kf) + (((size_t)(b * 48 + h)) << 14);

    unsigned int pl[12];
#pragma unroll
    for (int i = 0; i < 12; i++) pl[i] = 0u;
    float Z = 0.f;

    for (int hc = hc0; hc < hc1; ++hc) {
        const float4* src = kfb + (hc << 9);
#pragma unroll
        for (int i = 0; i < 8; i++) kshv[(i << 6) + lane] = src[(i << 6) + lane];
#pragma unroll 4
        for (int j = 0; j < 32; j++) {
            const float4* kj = reinterpret_cast<const float4*>(ksh + (j << 6));
            float ax = 0.f, ay = 0.f, az = 0.f, aw = 0.f;
#pragma unroll
            for (int i = 0; i < 16; i++) {
                float4 kv = kj[i];
                ax = fmaf(qv[i].x, kv.x, ax);
                ay = fmaf(qv[i].y, kv.y, ay);
                az = fmaf(qv[i].z, kv.z, az);
                aw = fmaf(qv[i].w, kv.w, aw);
            }
            float s = (ax + ay) + (az + aw);
            int col = (hc << 5) + j;
            bool msk = col > t;
            Z += __expf(msk ? -1e30f : s);
            unsigned int su = __float_as_uint(s);
            unsigned int key = su ^ ((unsigned int)(((int)su) >> 31) | 0x80000000u);
            unsigned int pk = (key & 0xFFFFFC00u) | (unsigned int)(1023 - col);
            pk = msk ? 0u : pk;
#pragma unroll
            for (int jj = 0; jj < 12; jj++) {   // branchless sorted-desc insert
                unsigned int mx = pl[jj] > pk ? pl[jj] : pk;
                pk = pl[jj] > pk ? pk : pl[jj];
                pl[jj] = mx;
            }
        }
    }
    const size_t r = (((size_t)bh) << 10) + t;
    pZ[r * 4 + part] = Z;
    unsigned int* pp = pP + r * 48 + (size_t)part * 12;
    *reinterpret_cast<uint4*>(pp + 0) = make_uint4(pl[0], pl[1], pl[2], pl[3]);
    *reinterpret_cast<uint4*>(pp + 4) = make_uint4(pl[4], pl[5], pl[6], pl[7]);
    *reinterpret_cast<uint4*>(pp + 8) = make_uint4(pl[8], pl[9], pl[10], pl[11]);
}

// ---------------------------------------------------------------- phase B: merge partials + marker gather
#define LDLIST(dst, o, valid)                                                     \
    {                                                                             \
        uint4 x0, x1, x2;                                                         \
        if (valid) { x0 = pp[o]; x1 = pp[o + 1]; x2 = pp[o + 2]; }                \
        else { x0 = make_uint4(0,0,0,0); x1 = x0; x2 = x0; }                      \
        dst[0]=x0.x; dst[1]=x0.y; dst[2]=x0.z; dst[3]=x0.w;                       \
        dst[4]=x1.x; dst[5]=x1.y; dst[6]=x1.z; dst[7]=x1.w;                       \
        dst[8]=x2.x; dst[9]=x2.y; dst[10]=x2.z; dst[11]=x2.w;                     \
    }

#define POPQ(qq)                                                                  \
    {                                                                             \
        bool tk = (qq[0] == hm);                                                  \
        qq[0]=tk?qq[1]:qq[0]; qq[1]=tk?qq[2]:qq[1]; qq[2]=tk?qq[3]:qq[2];         \
        qq[3]=tk?qq[4]:qq[3]; qq[4]=tk?qq[5]:qq[4]; qq[5]=tk?qq[6]:qq[5];         \
        qq[6]=tk?qq[7]:qq[6]; qq[7]=tk?qq[8]:qq[7]; qq[8]=tk?qq[9]:qq[8];         \
        qq[9]=tk?qq[10]:qq[9]; qq[10]=tk?qq[11]:qq[10]; qq[11]=tk?0u:qq[11];      \
    }

__global__ __launch_bounds__(256) void attn_merge(
    const unsigned int* __restrict__ pP, const float* __restrict__ pZ,
    const float* __restrict__ kb,      // (B,T,12,64) vanilla
    const float* __restrict__ sink_s,  // (48)
    float* __restrict__ mkbuf,         // (B*48*1024, 64)
    float* __restrict__ psbuf)         // (B*48*1024)
{
    const int tid = threadIdx.x, wv = tid >> 6, lane = tid & 63;
    const int wid = blockIdx.x * 4 + wv;
    const int tile = wid & 15, bh = wid >> 4;
    const int h = bh % 48, b = bh / 48, hk = h % 12;
    const int t = (tile << 6) + lane;
    const size_t r = (((size_t)bh) << 10) + t;
    const int npart = (tile >> 2) + 1;   // wave-uniform

    unsigned int q0[12], q1[12], q2[12], q3[12];
    const uint4* pp = reinterpret_cast<const uint4*>(pP + r * 48);
    LDLIST(q0, 0, true);
    LDLIST(q1, 3, npart > 1);
    LDLIST(q2, 6, npart > 2);
    LDLIST(q3, 9, npart > 3);

    float Z = pZ[r * 4 + 0];
    if (npart > 1) Z += pZ[r * 4 + 1];
    if (npart > 2) Z += pZ[r * 4 + 2];
    if (npart > 3) Z += pZ[r * 4 + 3];
    const float es = __expf(sink_s[h]);
    const float invZ = 1.f / (Z + es);

    const float* kvan = kb + (((size_t)b * 12288 + hk) << 6);
    float4 mk[16];
#pragma unroll
    for (int i = 0; i < 16; i++) mk[i] = make_float4(0.f, 0.f, 0.f, 0.f);

#pragma unroll
    for (int rd = 0; rd < 12; rd++) {
        unsigned int ha = q0[0] > q1[0] ? q0[0] : q1[0];
        unsigned int hb2 = q2[0] > q3[0] ? q2[0] : q3[0];
        unsigned int hm = ha > hb2 ? ha : hb2;
        POPQ(q0); POPQ(q1); POPQ(q2); POPQ(q3);
        unsigned int key = hm & 0xFFFFFC00u;
        unsigned int uu = (key & 0x80000000u) ? (key ^ 0x80000000u) : ~key;
        float v = __uint_as_float(uu);
        int idx = 1023 - (int)(hm & 1023u);
        float w = (hm == 0u) ? 0.f : __expf(v) * invZ;
        const float4* kr = reinterpret_cast<const float4*>(kvan + (size_t)idx * 768);
#pragma unroll
        for (int i = 0; i < 16; i++) {
            float4 kv = kr[i];
            mk[i].x = fmaf(w, kv.x, mk[i].x);
            mk[i].y = fmaf(w, kv.y, mk[i].y);
            mk[i].z = fmaf(w, kv.z, mk[i].z);
            mk[i].w = fmaf(w, kv.w, mk[i].w);
        }
    }
    const float4* sr = reinterpret_cast<const float4*>(kvan + (size_t)t * 768);
    float4* mo = reinterpret_cast<float4*>(mkbuf + (r << 6));
#pragma unroll
    for (int i = 0; i < 16; i++) {
        float4 sv = sr[i];
        float4 o;
        o.x = (mk[i].x + sv.x) * (1.f / 13.f);
        o.y = (mk[i].y + sv.y) * (1.f / 13.f);
        o.z = (mk[i].z + sv.z) * (1.f / 13.f);
        o.w = (mk[i].w + sv.w) * (1.f / 13.f);
        mo[i] = o;
    }
    psbuf[r] = es * invZ;
}

// ---------------------------------------------------------------- activation + rmsnorm(256) + gate, in place
__global__ __launch_bounds__(256) void act_kernel(float* __restrict__ hb) {
    const int tid = threadIdx.x, wv = tid >> 6, lane = tid & 63;
    const size_t row = (size_t)blockIdx.x * 4 + wv;
    float4* p = reinterpret_cast<float4*>(hb + (row << 8)) + lane;
    float4 x = *p;
    float4 y;
    y.x = x.x * x.x + 0.75f * x.x * x.x * x.x;
    y.y = x.y * x.y + 0.75f * x.y * x.y * x.y;
    y.z = x.z * x.z + 0.75f * x.z * x.z * x.z;
    y.w = x.w * x.w + 0.75f * x.w * x.w * x.w;
    float ss = wave_sum(y.x * y.x + y.y * y.y + y.z * y.z + y.w * y.w);
    float rinv = 1.f / sqrtf(ss * (1.f / 256.f) + 1.1920928955078125e-07f);
    float4 g;
    float zx = y.x * rinv, zy = y.y * rinv, zz = y.z * rinv, zw = y.w * rinv;
    g.x = zx / (1.f + __expf(-1.8137993642342178f * zx));
    g.y = zy / (1.f + __expf(-1.8137993642342178f * zy));
    g.z = zz / (1.f + __expf(-1.8137993642342178f * zz));
    g.w = zw / (1.f + __expf(-1.8137993642342178f * zw));
    *p = g;
}

// ---------------------------------------------------------------- proj GEMM (N=64, K=256) + sink epilogue -> ctx
__global__ __launch_bounds__(256) void proj_gemm(const float* __restrict__ A, const float* __restrict__ W,
                                                 const float* __restrict__ bias, const float* __restrict__ ps,
                                                 const float* __restrict__ vn, float* __restrict__ ctx,
                                                 int rowbase) {
    __shared__ float As[16][68];
    __shared__ float Ws[16][68];
    const int bm = blockIdx.y * 64;
    const int tid = threadIdx.x;
    const int tx = tid & 15, ty = tid >> 4;
    float acc[4][4] = {};
    const int mm = tid >> 2;
    const int kk4 = (tid & 3) * 4;
    for (int k0 = 0; k0 < 256; k0 += 16) {
        float4 av = *reinterpret_cast<const float4*>(&A[(size_t)(bm + mm) * 256 + k0 + kk4]);
        As[kk4 + 0][mm] = av.x; As[kk4 + 1][mm] = av.y; As[kk4 + 2][mm] = av.z; As[kk4 + 3][mm] = av.w;
        float4 wv = *reinterpret_cast<const float4*>(&W[(size_t)mm * 256 + k0 + kk4]);
        Ws[kk4 + 0][mm] = wv.x; Ws[kk4 + 1][mm] = wv.y; Ws[kk4 + 2][mm] = wv.z; Ws[kk4 + 3][mm] = wv.w;
        __syncthreads();
#pragma unroll
        for (int kk = 0; kk < 16; kk++) {
            float a0 = As[kk][ty * 4 + 0], a1 = As[kk][ty * 4 + 1], a2 = As[kk][ty * 4 + 2], a3 = As[kk][ty * 4 + 3];
            float b0 = Ws[kk][tx * 4 + 0], b1 = Ws[kk][tx * 4 + 1], b2 = Ws[kk][tx * 4 + 2], b3 = Ws[kk][tx * 4 + 3];
            acc[0][0] += a0 * b0; acc[0][1] += a0 * b1; acc[0][2] += a0 * b2; acc[0][3] += a0 * b3;
            acc[1][0] += a1 * b0; acc[1][1] += a1 * b1; acc[1][2] += a1 * b2; acc[1][3] += a1 * b3;
            acc[2][0] += a2 * b0; acc[2][1] += a2 * b1; acc[2][2] += a2 * b2; acc[2][3] += a2 * b3;
            acc[3][0] += a3 * b0; acc[3][1] += a3 * b1; acc[3][2] += a3 * b2; acc[3][3] += a3 * b3;
        }
        __syncthreads();
    }
#pragma unroll
    for (int i = 0; i < 4; i++) {
        int rm = rowbase + bm + ty * 4 + i;
        int g = rm >> 10, t = rm & 1023;
        int hh = g % 48, bb = g / 48;
        float p = ps[rm];
        const float* v = vn + hh * 64 + tx * 4;
        float4 o;
        o.x = acc[i][0] + bias[tx * 4 + 0] + p * v[0];
        o.y = acc[i][1] + bias[tx * 4 + 1] + p * v[1];
        o.z = acc[i][2] + bias[tx * 4 + 2] + p * v[2];
        o.w = acc[i][3] + bias[tx * 4 + 3] + p * v[3];
        *reinterpret_cast<float4*>(&ctx[((((size_t)(bb << 10) + t) * 48 + hh) << 6) + tx * 4]) = o;
    }
}

// ---------------------------------------------------------------- launch
extern "C" void kernel_launch(void* const* d_in, const int* in_sizes, int n_in,
                              void* d_out, int out_size, void* d_ws, size_t ws_size,
                              hipStream_t stream) {
    (void)in_sizes; (void)n_in; (void)out_size; (void)ws_size;
    const float* A       = (const float*)d_in[0];
    const float* X       = (const float*)d_in[1];
    const float* Wq_w    = (const float*)d_in[2];
    const float* Wq_b    = (const float*)d_in[3];
    const float* Wk_w    = (const float*)d_in[4];
    const float* Wk_b    = (const float*)d_in[5];
    const float* wedge_A = (const float*)d_in[6];
    const float* wedge_b = (const float*)d_in[7];
    const float* sink    = (const float*)d_in[8];
    const float* v_nulls = (const float*)d_in[9];
    const float* fc_w    = (const float*)d_in[10];
    const float* fc_b    = (const float*)d_in[11];
    const float* proj_w  = (const float*)d_in[12];
    const float* proj_b  = (const float*)d_in[13];
    const float* WO      = (const float*)d_in[14];
    const float* WO_b    = (const float*)d_in[15];
    float* out = (float*)d_out;
    float* ws  = (float*)d_ws;

    // layout (floats). ctx overlays qbuf (dead after attn); hbuf overlays kb/kf (dead after attn).
    float* qbuf  = ws;                      // 6291456  (B,T,48,64) ; later reused as ctx
    float* ctx   = ws;
    float* kbbuf = ws + 6291456;            // 1572864  (B,T,12,64)
    float* hbuf  = ws + 6291456;            // 6291456  (24576 x 256) per segment, overlays kb/kf
    float* kfbuf = ws + 7864320;            // 6291456  (B,48,T,64)
    float* mkbuf = ws + 14155776;           // 6291456  (B*48*1024, 64)
    float* psbuf = ws + 20447232;           // 98304
    float* Sbuf  = ws + 20545536;           // 196608
    float* rcbuf = ws + 20742144;           // 32768
    float* rsbuf = ws + 20774912;           // 32768
    float* wob   = ws + 20807680;           // 768
    float* pZ    = ws + 20808448;           // 393216  (98304 x 4)
    unsigned int* pP = (unsigned int*)(ws + 21201664);  // 4718592 (98304 x 48)
    // total: 25,920,256 floats = 103.7 MB

    prep_kernel<<<(48 * 64 * 64 + 1024 * 32 + 768 + 255) / 256, 256, 0, stream>>>(
        wedge_A, wedge_b, WO_b, Sbuf, rcbuf, rsbuf, wob);
    gemm_wt<<<dim3(48, 32), 256, 0, stream>>>(A, Wq_w, Wq_b, qbuf, 2048, 3072, 768);
    gemm_wt<<<dim3(12, 32), 256, 0, stream>>>(X, Wk_w, Wk_b, kbbuf, 2048, 768, 768);
    q_transform<<<24576, 256, 0, stream>>>(qbuf, Sbuf, rcbuf, rsbuf);
    k_transform<<<24576, 256, 0, stream>>>(kbbuf, kfbuf, Sbuf, rcbuf, rsbuf);
    attn_scores<<<3840, 64, 0, stream>>>(qbuf, kfbuf, pZ, pP);
    attn_merge<<<384, 256, 0, stream>>>(pP, pZ, kbbuf, sink, mkbuf, psbuf);
    for (int seg = 0; seg < 4; seg++) {
        const int rowbase = seg * 24576;
        gemm_wt<<<dim3(4, 384), 256, 0, stream>>>(mkbuf + (size_t)rowbase * 64, fc_w, fc_b,
                                                  hbuf, 24576, 256, 64);
        act_kernel<<<6144, 256, 0, stream>>>(hbuf);
        proj_gemm<<<dim3(1, 384), 256, 0, stream>>>(hbuf, proj_w, proj_b, psbuf, v_nulls,
                                                    ctx, rowbase);
    }
    gemm_kn<<<dim3(12, 32), 256, 0, stream>>>(ctx, WO, wob, out, 2048, 768, 3072, 0.25f);
}

// Round 5
// 719.966 us; speedup vs baseline: 5.4217x; 1.4238x over previous
//
#include <hip/hip_runtime.h>
#include <math.h>

#define B_   2
#define T_   1024
#define C_   768
#define DH_  64
#define NH_  12
#define HT_  48

typedef short bf16x8 __attribute__((ext_vector_type(8)));
typedef float f32x4 __attribute__((ext_vector_type(4)));

__device__ __forceinline__ float wave_sum(float v) {
#pragma unroll
    for (int off = 32; off; off >>= 1) v += __shfl_xor(v, off, 64);
    return v;
}
__device__ __forceinline__ unsigned short rne_bf16(float f) {
    unsigned u = __float_as_uint(f);
    return (unsigned short)((u + 0x7FFFu + ((u >> 16) & 1u)) >> 16);
}

// phase-A work tables: 40 (tile,part) units per (b,h), sorted heavy-first.
__constant__ int c_tileTab[40] = {15,15,15,15, 14,14,14, 13,13,13, 12,12,12, 11,11,11,
                                  10,10, 9,9, 8,8, 7,7, 6, 5, 4, 3,
                                  14,10,6,2, 13,9,5,1, 12,8,4,0};
__constant__ int c_partTab[40] = { 0, 1, 2, 3,  0, 1, 2,  0, 1, 2,  0, 1, 2,  0, 1, 2,
                                   0, 1, 0,1, 0,1, 0,1, 0, 0, 0, 0,
                                   3, 2,1,0,  3,2,1,0,  3,2,1,0};

// ---------------------------------------------------------------- prep
__global__ void prep_kernel(const float* __restrict__ wA, const float* __restrict__ wb,
                            const float* __restrict__ WOb,
                            float* __restrict__ S, float* __restrict__ rc,
                            float* __restrict__ rs, float* __restrict__ wob) {
    int i = blockIdx.x * 256 + threadIdx.x;
    if (i < HT_ * 64 * 64) {
        int e = i & 63, d = (i >> 6) & 63, h = i >> 12;
        float v = wA[d * 64 + e] - wA[e * 64 + d];
        if (d == e) v += wb[h * 64 + d];
        S[i] = v;
    } else if (i < HT_ * 64 * 64 + T_ * 32) {
        int j = i - HT_ * 64 * 64;
        int t = j >> 5, f = j & 31;
        float invf = (float)(1.0 / pow(10000.0, (double)f / 32.0));
        float fr = (float)t * invf;
        rc[j] = cosf(fr);
        rs[j] = sinf(fr);
    } else if (i < HT_ * 64 * 64 + T_ * 32 + C_) {
        int d = i - (HT_ * 64 * 64 + T_ * 32);
        wob[d] = WOb[d] + WOb[C_ + d] + WOb[2 * C_ + d] + WOb[3 * C_ + d];
    }
}

// ---------------------------------------------------------------- f32 -> bf16 convert
__global__ void cvt_bf16(const float* __restrict__ src, unsigned short* __restrict__ dst, int n) {
    int i = (blockIdx.x * 256 + threadIdx.x) * 4;
    if (i < n) {
        float4 v = *reinterpret_cast<const float4*>(src + i);
        ushort4 o;
        o.x = rne_bf16(v.x); o.y = rne_bf16(v.y); o.z = rne_bf16(v.z); o.w = rne_bf16(v.w);
        *reinterpret_cast<ushort4*>(dst + i) = o;
    }
}

// ---------------------------------------------------------------- WO (4,768,768) -> WOt[d][n*768+c] bf16
__global__ __launch_bounds__(256) void wo_transpose(const float* __restrict__ WO,
                                                    unsigned short* __restrict__ WOt) {
    __shared__ float tl[32][33];
    const int n = blockIdx.z;
    const int c0 = blockIdx.x * 32, d0 = blockIdx.y * 32;
    const int tx = threadIdx.x & 31, ty = threadIdx.x >> 5;
#pragma unroll
    for (int p = 0; p < 4; p++)
        tl[ty + p * 8][tx] = WO[(size_t)n * 589824 + (size_t)(c0 + ty + p * 8) * 768 + d0 + tx];
    __syncthreads();
#pragma unroll
    for (int p = 0; p < 4; p++)
        WOt[(size_t)(d0 + ty + p * 8) * 3072 + n * 768 + c0 + tx] = rne_bf16(tl[tx][ty + p * 8]);
}

// ---------------------------------------------------------------- bf16 MFMA GEMM: C = (A @ W^T + bias) * scl
// A (M,K) bf16 row-major, W (N,K) bf16 row-major, C (M,N) f32. M%128==0, N%128==0, K%32==0.
__global__ __launch_bounds__(256) void gemm_bf16(const unsigned short* __restrict__ A,
                                                 const unsigned short* __restrict__ W,
                                                 const float* __restrict__ bias,
                                                 float* __restrict__ C,
                                                 int M, int N, int K, float scl) {
    __shared__ unsigned short Asd[128][40];   // +8 pad: 2-way banks (free)
    __shared__ unsigned short Bsd[128][40];
    const int tid = threadIdx.x;
    const int wv = tid >> 6, lane = tid & 63;
    const int m0 = blockIdx.y * 128, n0 = blockIdx.x * 128;
    const int wr = (wv >> 1) * 64, wc = (wv & 1) * 64;
    const int l15 = lane & 15, l4 = lane >> 4;
    const int srow = tid >> 2, soff = (tid & 3) * 8;
    f32x4 acc[4][4] = {};
    for (int k0 = 0; k0 < K; k0 += 32) {
        uint4 a0 = *reinterpret_cast<const uint4*>(A + (size_t)(m0 + srow) * K + k0 + soff);
        uint4 a1 = *reinterpret_cast<const uint4*>(A + (size_t)(m0 + srow + 64) * K + k0 + soff);
        uint4 b0 = *reinterpret_cast<const uint4*>(W + (size_t)(n0 + srow) * K + k0 + soff);
        uint4 b1 = *reinterpret_cast<const uint4*>(W + (size_t)(n0 + srow + 64) * K + k0 + soff);
        *reinterpret_cast<uint4*>(&Asd[srow][soff])      = a0;
        *reinterpret_cast<uint4*>(&Asd[srow + 64][soff]) = a1;
        *reinterpret_cast<uint4*>(&Bsd[srow][soff])      = b0;
        *reinterpret_cast<uint4*>(&Bsd[srow + 64][soff]) = b1;
        __syncthreads();
        bf16x8 af[4], bfr[4];
#pragma unroll
        for (int i = 0; i < 4; i++)
            af[i] = *reinterpret_cast<const bf16x8*>(&Asd[wr + i * 16 + l15][l4 * 8]);
#pragma unroll
        for (int j = 0; j < 4; j++)
            bfr[j] = *reinterpret_cast<const bf16x8*>(&Bsd[wc + j * 16 + l15][l4 * 8]);
#pragma unroll
        for (int i = 0; i < 4; i++)
#pragma unroll
            for (int j = 0; j < 4; j++)
                acc[i][j] = __builtin_amdgcn_mfma_f32_16x16x32_bf16(af[i], bfr[j], acc[i][j], 0, 0, 0);
        __syncthreads();
    }
#pragma unroll
    for (int i = 0; i < 4; i++)
#pragma unroll
        for (int j = 0; j < 4; j++) {
            int col = n0 + wc + j * 16 + l15;
            float bv = bias[col];
#pragma unroll
            for (int r = 0; r < 4; r++) {
                int row = m0 + wr + i * 16 + l4 * 4 + r;
                C[(size_t)row * N + col] = (acc[i][j][r] + bv) * scl;
            }
        }
}

// ---------------------------------------------------------------- q transform (in place): rmsnorm -> wedge -> rope
__global__ __launch_bounds__(256) void q_transform(float* __restrict__ q, const float* __restrict__ S,
                                                   const float* __restrict__ rc, const float* __restrict__ rs) {
    const int tid = threadIdx.x, wv = tid >> 6, lane = tid & 63;
    const int row = blockIdx.x * 4 + wv;
    const int h = row % 48;
    const int t = (row / 48) & (T_ - 1);
    float* rowp = q + ((size_t)row << 6);
    __shared__ float sh[4][64];
    float v = rowp[lane];
    float ss = wave_sum(v * v);
    v *= 1.f / sqrtf(ss * (1.f / 64.f) + 1.1920928955078125e-07f);
    sh[wv][lane] = v;
    __syncthreads();
    const float* Sh = S + h * 4096;
    float acc = v;
#pragma unroll 8
    for (int d = 0; d < 64; d++) acc += sh[wv][d] * Sh[d * 64 + lane];
    __syncthreads();
    sh[wv][lane] = acc;
    __syncthreads();
    int j = lane & 31;
    float x1 = sh[wv][2 * j], x2 = sh[wv][2 * j + 1];
    float cth = rc[t * 32 + j], sth = rs[t * 32 + j];
    rowp[lane] = (lane < 32) ? (x1 * cth - x2 * sth) : (x1 * sth + x2 * cth);
}

// ---------------------------------------------------------------- k transform
__global__ __launch_bounds__(256) void k_transform(const float* __restrict__ kb, float* __restrict__ kf,
                                                   const float* __restrict__ S,
                                                   const float* __restrict__ rc, const float* __restrict__ rs) {
    const int tid = threadIdx.x, wv = tid >> 6, lane = tid & 63;
    const int row = blockIdx.x * 4 + wv;
    const int t = row & (T_ - 1);
    const int bh = row >> 10;
    const int h = bh % 48;
    const int b = bh / 48;
    const int hk = h % 12;
    __shared__ float sh[4][64];
    float v = kb[(((size_t)(b * T_ + t) * 12 + hk) << 6) + lane];
    sh[wv][lane] = v;
    __syncthreads();
    const float* Sh = S + h * 4096;
    float acc = v;
#pragma unroll 8
    for (int d = 0; d < 64; d++) acc += sh[wv][d] * Sh[d * 64 + lane];
    __syncthreads();
    sh[wv][lane] = acc;
    __syncthreads();
    int j = lane & 31;
    float x1 = sh[wv][2 * j], x2 = sh[wv][2 * j + 1];
    float cth = rc[t * 32 + j], sth = rs[t * 32 + j];
    kf[((size_t)row << 6) + lane] = (lane < 32) ? (x1 * cth - x2 * sth) : (x1 * sth + x2 * cth);
}

// ---------------------------------------------------------------- phase A: partial scores (f32)
__global__ __launch_bounds__(64) void attn_scores(
    const float* __restrict__ q, const float* __restrict__ kf,
    float* __restrict__ pZ, unsigned int* __restrict__ pP)
{
    const int lane = threadIdx.x;
    const int bid = blockIdx.x;
    const int u = bid / 96;
    const int bh = bid % 96;
    const int tile = c_tileTab[u];
    const int part = c_partTab[u];
    const int h = bh % 48;
    const int b = bh / 48;
    const int t = (tile << 6) + lane;
    const int hc0 = part << 3;
    const int hc1 = min(hc0 + 8, (tile + 1) << 1);

    __shared__ float ksh[32 * 64];
    float4* kshv = reinterpret_cast<float4*>(ksh);

    const float4* qrow = reinterpret_cast<const float4*>(q + (((size_t)((b << 10) + t) * 48 + h) << 6));
    float4 qv[16];
#pragma unroll
    for (int i = 0; i < 16; i++) {
        float4 v = qrow[i];
        qv[i] = make_float4(v.x * 0.125f, v.y * 0.125f, v.z * 0.125f, v.w * 0.125f);
    }
    const float4* kfb = reinterpret_cast<const float4*>(kf) + (((size_t)(b * 48 + h)) << 14);

    unsigned int pl[12];
#pragma unroll
    for (int i = 0; i < 12; i++) pl[i] = 0u;
    float Z = 0.f;

    for (int hc = hc0; hc < hc1; ++hc) {
        const float4* src = kfb + (hc << 9);
#pragma unroll
        for (int i = 0; i < 8; i++) kshv[(i << 6) + lane] = src[(i << 6) + lane];
#pragma unroll 4
        for (int j = 0; j < 32; j++) {
            const float4* kj = reinterpret_cast<const float4*>(ksh + (j << 6));
            float ax = 0.f, ay = 0.f, az = 0.f, aw = 0.f;
#pragma unroll
            for (int i = 0; i < 16; i++) {
                float4 kv = kj[i];
                ax = fmaf(qv[i].x, kv.x, ax);
                ay = fmaf(qv[i].y, kv.y, ay);
                az = fmaf(qv[i].z, kv.z, az);
                aw = fmaf(qv[i].w, kv.w, aw);
            }
            float s = (ax + ay) + (az + aw);
            int col = (hc << 5) + j;
            bool msk = col > t;
            Z += __expf(msk ? -1e30f : s);
            unsigned int su = __float_as_uint(s);
            unsigned int key = su ^ ((unsigned int)(((int)su) >> 31) | 0x80000000u);
            unsigned int pk = (key & 0xFFFFFC00u) | (unsigned int)(1023 - col);
            pk = msk ? 0u : pk;
#pragma unroll
            for (int jj = 0; jj < 12; jj++) {
                unsigned int mx = pl[jj] > pk ? pl[jj] : pk;
                pk = pl[jj] > pk ? pk : pl[jj];
                pl[jj] = mx;
            }
        }
    }
    const size_t r = (((size_t)bh) << 10) + t;
    pZ[r * 4 + part] = Z;
    unsigned int* pp = pP + r * 48 + (size_t)part * 12;
    *reinterpret_cast<uint4*>(pp + 0) = make_uint4(pl[0], pl[1], pl[2], pl[3]);
    *reinterpret_cast<uint4*>(pp + 4) = make_uint4(pl[4], pl[5], pl[6], pl[7]);
    *reinterpret_cast<uint4*>(pp + 8) = make_uint4(pl[8], pl[9], pl[10], pl[11]);
}

// ---------------------------------------------------------------- phase B: merge partials + marker gather -> bf16
#define LDLIST(dst, o, valid)                                                     \
    {                                                                             \
        uint4 x0, x1, x2;                                                         \
        if (valid) { x0 = pp[o]; x1 = pp[o + 1]; x2 = pp[o + 2]; }                \
        else { x0 = make_uint4(0,0,0,0); x1 = x0; x2 = x0; }                      \
        dst[0]=x0.x; dst[1]=x0.y; dst[2]=x0.z; dst[3]=x0.w;                       \
        dst[4]=x1.x; dst[5]=x1.y; dst[6]=x1.z; dst[7]=x1.w;                       \
        dst[8]=x2.x; dst[9]=x2.y; dst[10]=x2.z; dst[11]=x2.w;                     \
    }

#define POPQ(qq)                                                                  \
    {                                                                             \
        bool tk = (qq[0] == hm);                                                  \
        qq[0]=tk?qq[1]:qq[0]; qq[1]=tk?qq[2]:qq[1]; qq[2]=tk?qq[3]:qq[2];         \
        qq[3]=tk?qq[4]:qq[3]; qq[4]=tk?qq[5]:qq[4]; qq[5]=tk?qq[6]:qq[5];         \
        qq[6]=tk?qq[7]:qq[6]; qq[7]=tk?qq[8]:qq[7]; qq[8]=tk?qq[9]:qq[8];         \
        qq[9]=tk?qq[10]:qq[9]; qq[10]=tk?qq[11]:qq[10]; qq[11]=tk?0u:qq[11];      \
    }

__global__ __launch_bounds__(256) void attn_merge(
    const unsigned int* __restrict__ pP, const float* __restrict__ pZ,
    const float* __restrict__ kb, const float* __restrict__ sink_s,
    unsigned short* __restrict__ mkbuf,   // (B*48*1024, 64) bf16 marker/13
    float* __restrict__ psbuf)
{
    const int tid = threadIdx.x, wv = tid >> 6, lane = tid & 63;
    const int wid = blockIdx.x * 4 + wv;
    const int tile = wid & 15, bh = wid >> 4;
    const int h = bh % 48, b = bh / 48, hk = h % 12;
    const int t = (tile << 6) + lane;
    const size_t r = (((size_t)bh) << 10) + t;
    const int npart = (tile >> 2) + 1;

    unsigned int q0[12], q1[12], q2[12], q3[12];
    const uint4* pp = reinterpret_cast<const uint4*>(pP + r * 48);
    LDLIST(q0, 0, true);
    LDLIST(q1, 3, npart > 1);
    LDLIST(q2, 6, npart > 2);
    LDLIST(q3, 9, npart > 3);

    float Z = pZ[r * 4 + 0];
    if (npart > 1) Z += pZ[r * 4 + 1];
    if (npart > 2) Z += pZ[r * 4 + 2];
    if (npart > 3) Z += pZ[r * 4 + 3];
    const float es = __expf(sink_s[h]);
    const float invZ = 1.f / (Z + es);

    const float* kvan = kb + (((size_t)b * 12288 + hk) << 6);
    float4 mk[16];
#pragma unroll
    for (int i = 0; i < 16; i++) mk[i] = make_float4(0.f, 0.f, 0.f, 0.f);

#pragma unroll
    for (int rd = 0; rd < 12; rd++) {
        unsigned int ha = q0[0] > q1[0] ? q0[0] : q1[0];
        unsigned int hb2 = q2[0] > q3[0] ? q2[0] : q3[0];
        unsigned int hm = ha > hb2 ? ha : hb2;
        POPQ(q0); POPQ(q1); POPQ(q2); POPQ(q3);
        unsigned int key = hm & 0xFFFFFC00u;
        unsigned int uu = (key & 0x80000000u) ? (key ^ 0x80000000u) : ~key;
        float v = __uint_as_float(uu);
        int idx = 1023 - (int)(hm & 1023u);
        float w = (hm == 0u) ? 0.f : __expf(v) * invZ;
        const float4* kr = reinterpret_cast<const float4*>(kvan + (size_t)idx * 768);
#pragma unroll
        for (int i = 0; i < 16; i++) {
            float4 kv = kr[i];
            mk[i].x = fmaf(w, kv.x, mk[i].x);
            mk[i].y = fmaf(w, kv.y, mk[i].y);
            mk[i].z = fmaf(w, kv.z, mk[i].z);
            mk[i].w = fmaf(w, kv.w, mk[i].w);
        }
    }
    const float4* sr = reinterpret_cast<const float4*>(kvan + (size_t)t * 768);
    unsigned short* mo = mkbuf + (r << 6);
#pragma unroll
    for (int i = 0; i < 16; i++) {
        float4 sv = sr[i];
        ushort4 o;
        o.x = rne_bf16((mk[i].x + sv.x) * (1.f / 13.f));
        o.y = rne_bf16((mk[i].y + sv.y) * (1.f / 13.f));
        o.z = rne_bf16((mk[i].z + sv.z) * (1.f / 13.f));
        o.w = rne_bf16((mk[i].w + sv.w) * (1.f / 13.f));
        *reinterpret_cast<ushort4*>(mo + i * 4) = o;
    }
    psbuf[r] = es * invZ;
}

// ---------------------------------------------------------------- activation + rmsnorm(256) + gate, in place
__global__ __launch_bounds__(256) void act_kernel(float* __restrict__ hb) {
    const int tid = threadIdx.x, wv = tid >> 6, lane = tid & 63;
    const size_t row = (size_t)blockIdx.x * 4 + wv;
    float4* p = reinterpret_cast<float4*>(hb + (row << 8)) + lane;
    float4 x = *p;
    float4 y;
    y.x = x.x * x.x + 0.75f * x.x * x.x * x.x;
    y.y = x.y * x.y + 0.75f * x.y * x.y * x.y;
    y.z = x.z * x.z + 0.75f * x.z * x.z * x.z;
    y.w = x.w * x.w + 0.75f * x.w * x.w * x.w;
    float ss = wave_sum(y.x * y.x + y.y * y.y + y.z * y.z + y.w * y.w);
    float rinv = 1.f / sqrtf(ss * (1.f / 256.f) + 1.1920928955078125e-07f);
    float4 g;
    float zx = y.x * rinv, zy = y.y * rinv, zz = y.z * rinv, zw = y.w * rinv;
    g.x = zx / (1.f + __expf(-1.8137993642342178f * zx));
    g.y = zy / (1.f + __expf(-1.8137993642342178f * zy));
    g.z = zz / (1.f + __expf(-1.8137993642342178f * zz));
    g.w = zw / (1.f + __expf(-1.8137993642342178f * zw));
    *p = g;
}

// ---------------------------------------------------------------- proj GEMM (N=64, K=256) + sink epilogue -> ctx bf16
__global__ __launch_bounds__(256) void proj_gemm(const float* __restrict__ A, const float* __restrict__ W,
                                                 const float* __restrict__ bias, const float* __restrict__ ps,
                                                 const float* __restrict__ vn, unsigned short* __restrict__ ctx,
                                                 int rowbase) {
    __shared__ float As[16][68];
    __shared__ float Ws[16][68];
    const int bm = blockIdx.y * 64;
    const int tid = threadIdx.x;
    const int tx = tid & 15, ty = tid >> 4;
    float acc[4][4] = {};
    const int mm = tid >> 2;
    const int kk4 = (tid & 3) * 4;
    for (int k0 = 0; k0 < 256; k0 += 16) {
        float4 av = *reinterpret_cast<const float4*>(&A[(size_t)(bm + mm) * 256 + k0 + kk4]);
        As[kk4 + 0][mm] = av.x; As[kk4 + 1][mm] = av.y; As[kk4 + 2][mm] = av.z; As[kk4 + 3][mm] = av.w;
        float4 wv = *reinterpret_cast<const float4*>(&W[(size_t)mm * 256 + k0 + kk4]);
        Ws[kk4 + 0][mm] = wv.x; Ws[kk4 + 1][mm] = wv.y; Ws[kk4 + 2][mm] = wv.z; Ws[kk4 + 3][mm] = wv.w;
        __syncthreads();
#pragma unroll
        for (int kk = 0; kk < 16; kk++) {
            float a0 = As[kk][ty * 4 + 0], a1 = As[kk][ty * 4 + 1], a2 = As[kk][ty * 4 + 2], a3 = As[kk][ty * 4 + 3];
            float b0 = Ws[kk][tx * 4 + 0], b1 = Ws[kk][tx * 4 + 1], b2 = Ws[kk][tx * 4 + 2], b3 = Ws[kk][tx * 4 + 3];
            acc[0][0] += a0 * b0; acc[0][1] += a0 * b1; acc[0][2] += a0 * b2; acc[0][3] += a0 * b3;
            acc[1][0] += a1 * b0; acc[1][1] += a1 * b1; acc[1][2] += a1 * b2; acc[1][3] += a1 * b3;
            acc[2][0] += a2 * b0; acc[2][1] += a2 * b1; acc[2][2] += a2 * b2; acc[2][3] += a2 * b3;
            acc[3][0] += a3 * b0; acc[3][1] += a3 * b1; acc[3][2] += a3 * b2; acc[3][3] += a3 * b3;
        }
        __syncthreads();
    }
#pragma unroll
    for (int i = 0; i < 4; i++) {
        int rm = rowbase + bm + ty * 4 + i;
        int g = rm >> 10, t = rm & 1023;
        int hh = g % 48, bb = g / 48;
        float p = ps[rm];
        const float* v = vn + hh * 64 + tx * 4;
        ushort4 o;
        o.x = rne_bf16(acc[i][0] + bias[tx * 4 + 0] + p * v[0]);
        o.y = rne_bf16(acc[i][1] + bias[tx * 4 + 1] + p * v[1]);
        o.z = rne_bf16(acc[i][2] + bias[tx * 4 + 2] + p * v[2]);
        o.w = rne_bf16(acc[i][3] + bias[tx * 4 + 3] + p * v[3]);
        *reinterpret_cast<ushort4*>(&ctx[((((size_t)(bb << 10) + t) * 48 + hh) << 6) + tx * 4]) = o;
    }
}

// ---------------------------------------------------------------- launch
extern "C" void kernel_launch(void* const* d_in, const int* in_sizes, int n_in,
                              void* d_out, int out_size, void* d_ws, size_t ws_size,
                              hipStream_t stream) {
    (void)in_sizes; (void)n_in; (void)out_size; (void)ws_size;
    const float* A       = (const float*)d_in[0];
    const float* X       = (const float*)d_in[1];
    const float* Wq_w    = (const float*)d_in[2];
    const float* Wq_b    = (const float*)d_in[3];
    const float* Wk_w    = (const float*)d_in[4];
    const float* Wk_b    = (const float*)d_in[5];
    const float* wedge_A = (const float*)d_in[6];
    const float* wedge_b = (const float*)d_in[7];
    const float* sink    = (const float*)d_in[8];
    const float* v_nulls = (const float*)d_in[9];
    const float* fc_w    = (const float*)d_in[10];
    const float* fc_b    = (const float*)d_in[11];
    const float* proj_w  = (const float*)d_in[12];
    const float* proj_b  = (const float*)d_in[13];
    const float* WO      = (const float*)d_in[14];
    const float* WO_b    = (const float*)d_in[15];
    float* out = (float*)d_out;
    float* ws  = (float*)d_ws;

    // ---- workspace layout (float offsets, all multiples of 64) ----
    float*          qbuf   = ws;                                   // 6291456 f32 (B,T,48,64); region reused after attn_scores:
    unsigned short* ctx_bf = (unsigned short*)ws;                  //   first half: 2048x3072 bf16
    unsigned short* mk_bf  = (unsigned short*)(ws + 3145728);      //   second half: 98304x64 bf16
    float*          kbbuf  = ws + 6291456;                         // 1572864
    float*          kfbuf  = ws + 7864320;                         // 6291456; reused as hbuf after attn_scores
    float*          hbuf   = ws + 7864320;                         //   24576x256 f32 per segment
    float*          psbuf  = ws + 14155776;                        // 98304
    float*          pZ     = ws + 14254080;                        // 393216
    unsigned int*   pP     = (unsigned int*)(ws + 14647296);       // 4718592 u32
    float*          Sbuf   = ws + 19365888;                        // 196608
    float*          rcbuf  = ws + 19562496;                        // 32768
    float*          rsbuf  = ws + 19595264;                        // 32768
    float*          wob    = ws + 19628032;                        // 768 (+pad)
    unsigned short* A_bf   = (unsigned short*)(ws + 19629056);     // 1572864 u16
    unsigned short* X_bf   = (unsigned short*)(ws + 20415488);     // 1572864 u16
    unsigned short* Wq_bf  = (unsigned short*)(ws + 21201920);     // 2359296 u16
    unsigned short* Wk_bf  = (unsigned short*)(ws + 22381568);     // 589824 u16
    unsigned short* WOt_bf = (unsigned short*)(ws + 22676480);     // 2359296 u16
    unsigned short* fcw_bf = (unsigned short*)(ws + 23856128);     // 16384 u16
    // end: 23864320 floats = 95.5 MB

    prep_kernel<<<(48 * 64 * 64 + 1024 * 32 + 768 + 255) / 256, 256, 0, stream>>>(
        wedge_A, wedge_b, WO_b, Sbuf, rcbuf, rsbuf, wob);
    cvt_bf16<<<1536, 256, 0, stream>>>(A, A_bf, 1572864);
    cvt_bf16<<<1536, 256, 0, stream>>>(X, X_bf, 1572864);
    cvt_bf16<<<2304, 256, 0, stream>>>(Wq_w, Wq_bf, 2359296);
    cvt_bf16<<<576, 256, 0, stream>>>(Wk_w, Wk_bf, 589824);
    cvt_bf16<<<16, 256, 0, stream>>>(fc_w, fcw_bf, 16384);
    wo_transpose<<<dim3(24, 24, 4), 256, 0, stream>>>(WO, WOt_bf);

    gemm_bf16<<<dim3(24, 16), 256, 0, stream>>>(A_bf, Wq_bf, Wq_b, qbuf, 2048, 3072, 768, 1.f);
    gemm_bf16<<<dim3(6, 16), 256, 0, stream>>>(X_bf, Wk_bf, Wk_b, kbbuf, 2048, 768, 768, 1.f);
    q_transform<<<24576, 256, 0, stream>>>(qbuf, Sbuf, rcbuf, rsbuf);
    k_transform<<<24576, 256, 0, stream>>>(kbbuf, kfbuf, Sbuf, rcbuf, rsbuf);
    attn_scores<<<3840, 64, 0, stream>>>(qbuf, kfbuf, pZ, pP);
    attn_merge<<<384, 256, 0, stream>>>(pP, pZ, kbbuf, sink, mk_bf, psbuf);
    for (int seg = 0; seg < 4; seg++) {
        const int rowbase = seg * 24576;
        gemm_bf16<<<dim3(2, 192), 256, 0, stream>>>(mk_bf + (size_t)rowbase * 64, fcw_bf, fc_b,
                                                    hbuf, 24576, 256, 64, 1.f);
        act_kernel<<<6144, 256, 0, stream>>>(hbuf);
        proj_gemm<<<dim3(1, 384), 256, 0, stream>>>(hbuf, proj_w, proj_b, psbuf, v_nulls,
                                                    ctx_bf, rowbase);
    }
    gemm_bf16<<<dim3(6, 16), 256, 0, stream>>>(ctx_bf, WOt_bf, wob, out, 2048, 768, 3072, 0.25f);
}

// Round 6
// 475.940 us; speedup vs baseline: 8.2016x; 1.5127x over previous
//
#include <hip/hip_runtime.h>
#include <math.h>

#define B_   2
#define T_   1024
#define C_   768
#define DH_  64
#define NH_  12
#define HT_  48

typedef short bf16x8 __attribute__((ext_vector_type(8)));
typedef float f32x4 __attribute__((ext_vector_type(4)));

__device__ __forceinline__ float wave_sum(float v) {
#pragma unroll
    for (int off = 32; off; off >>= 1) v += __shfl_xor(v, off, 64);
    return v;
}
__device__ __forceinline__ unsigned short rne_bf16(float f) {
    unsigned u = __float_as_uint(f);
    return (unsigned short)((u + 0x7FFFu + ((u >> 16) & 1u)) >> 16);
}
__device__ __forceinline__ float bf2f(unsigned short u) {
    return __uint_as_float((unsigned)u << 16);
}

// work tables: 40 (tile,part) units per (b,h), heavy-first. chunk = 64 cols, part = 4 chunks.
__constant__ int c_tileTab[40] = {15,15,15,15, 14,14,14, 13,13,13, 12,12,12, 11,11,11,
                                  10,10, 9,9, 8,8, 7,7, 6, 5, 4, 3,
                                  14,10,6,2, 13,9,5,1, 12,8,4,0};
__constant__ int c_partTab[40] = { 0, 1, 2, 3,  0, 1, 2,  0, 1, 2,  0, 1, 2,  0, 1, 2,
                                   0, 1, 0,1, 0,1, 0,1, 0, 0, 0, 0,
                                   3, 2,1,0,  3,2,1,0,  3,2,1,0};

// ---------------------------------------------------------------- prep
__global__ void prep_kernel(const float* __restrict__ wA, const float* __restrict__ wb,
                            const float* __restrict__ WOb,
                            float* __restrict__ S, float* __restrict__ rc,
                            float* __restrict__ rs, float* __restrict__ wob) {
    int i = blockIdx.x * 256 + threadIdx.x;
    if (i < HT_ * 64 * 64) {
        int e = i & 63, d = (i >> 6) & 63, h = i >> 12;
        float v = wA[d * 64 + e] - wA[e * 64 + d];
        if (d == e) v += wb[h * 64 + d];
        S[i] = v;
    } else if (i < HT_ * 64 * 64 + T_ * 32) {
        int j = i - HT_ * 64 * 64;
        int t = j >> 5, f = j & 31;
        float invf = (float)(1.0 / pow(10000.0, (double)f / 32.0));
        float fr = (float)t * invf;
        rc[j] = cosf(fr);
        rs[j] = sinf(fr);
    } else if (i < HT_ * 64 * 64 + T_ * 32 + C_) {
        int d = i - (HT_ * 64 * 64 + T_ * 32);
        wob[d] = WOb[d] + WOb[C_ + d] + WOb[2 * C_ + d] + WOb[3 * C_ + d];
    }
}

// ---------------------------------------------------------------- fused f32->bf16 conversions (A,X,Wq,Wk,fc_w)
__global__ void cvt_all(const float* __restrict__ A, const float* __restrict__ X,
                        const float* __restrict__ Wq, const float* __restrict__ Wk,
                        const float* __restrict__ fcw,
                        unsigned short* __restrict__ Ab, unsigned short* __restrict__ Xb,
                        unsigned short* __restrict__ Wqb, unsigned short* __restrict__ Wkb,
                        unsigned short* __restrict__ fcb) {
    int i = blockIdx.x * 256 + threadIdx.x;   // float4 index
    const float* s; unsigned short* d; int o;
    if (i < 393216)       { s = A;   d = Ab;  o = i; }
    else if (i < 786432)  { s = X;   d = Xb;  o = i - 393216; }
    else if (i < 1376256) { s = Wq;  d = Wqb; o = i - 786432; }
    else if (i < 1523712) { s = Wk;  d = Wkb; o = i - 1376256; }
    else if (i < 1527808) { s = fcw; d = fcb; o = i - 1523712; }
    else return;
    float4 v = reinterpret_cast<const float4*>(s)[o];
    ushort4 u;
    u.x = rne_bf16(v.x); u.y = rne_bf16(v.y); u.z = rne_bf16(v.z); u.w = rne_bf16(v.w);
    reinterpret_cast<ushort4*>(d)[o] = u;
}

// ---------------------------------------------------------------- WO (4,768,768) -> WOt[d][n*768+c] bf16
__global__ __launch_bounds__(256) void wo_transpose(const float* __restrict__ WO,
                                                    unsigned short* __restrict__ WOt) {
    __shared__ float tl[32][33];
    const int n = blockIdx.z;
    const int c0 = blockIdx.x * 32, d0 = blockIdx.y * 32;
    const int tx = threadIdx.x & 31, ty = threadIdx.x >> 5;
#pragma unroll
    for (int p = 0; p < 4; p++)
        tl[ty + p * 8][tx] = WO[(size_t)n * 589824 + (size_t)(c0 + ty + p * 8) * 768 + d0 + tx];
    __syncthreads();
#pragma unroll
    for (int p = 0; p < 4; p++)
        WOt[(size_t)(d0 + ty + p * 8) * 3072 + n * 768 + c0 + tx] = rne_bf16(tl[tx][ty + p * 8]);
}

// ---------------------------------------------------------------- bf16 MFMA GEMM: C = (A @ W^T + bias) * scl
// A (M,K) bf16, W (N,K) bf16, C f32 (OBF=0) or bf16 (OBF=1).
template<int OBF>
__global__ __launch_bounds__(256) void gemm_bf16k(const unsigned short* __restrict__ A,
                                                  const unsigned short* __restrict__ W,
                                                  const float* __restrict__ bias,
                                                  void* __restrict__ Cv,
                                                  int M, int N, int K, float scl) {
    __shared__ unsigned short Asd[128][40];
    __shared__ unsigned short Bsd[128][40];
    const int tid = threadIdx.x;
    const int wv = tid >> 6, lane = tid & 63;
    const int m0 = blockIdx.y * 128, n0 = blockIdx.x * 128;
    const int wr = (wv >> 1) * 64, wc = (wv & 1) * 64;
    const int l15 = lane & 15, l4 = lane >> 4;
    const int srow = tid >> 2, soff = (tid & 3) * 8;
    f32x4 acc[4][4] = {};
    for (int k0 = 0; k0 < K; k0 += 32) {
        uint4 a0 = *reinterpret_cast<const uint4*>(A + (size_t)(m0 + srow) * K + k0 + soff);
        uint4 a1 = *reinterpret_cast<const uint4*>(A + (size_t)(m0 + srow + 64) * K + k0 + soff);
        uint4 b0 = *reinterpret_cast<const uint4*>(W + (size_t)(n0 + srow) * K + k0 + soff);
        uint4 b1 = *reinterpret_cast<const uint4*>(W + (size_t)(n0 + srow + 64) * K + k0 + soff);
        *reinterpret_cast<uint4*>(&Asd[srow][soff])      = a0;
        *reinterpret_cast<uint4*>(&Asd[srow + 64][soff]) = a1;
        *reinterpret_cast<uint4*>(&Bsd[srow][soff])      = b0;
        *reinterpret_cast<uint4*>(&Bsd[srow + 64][soff]) = b1;
        __syncthreads();
        bf16x8 af[4], bfr[4];
#pragma unroll
        for (int i = 0; i < 4; i++)
            af[i] = *reinterpret_cast<const bf16x8*>(&Asd[wr + i * 16 + l15][l4 * 8]);
#pragma unroll
        for (int j = 0; j < 4; j++)
            bfr[j] = *reinterpret_cast<const bf16x8*>(&Bsd[wc + j * 16 + l15][l4 * 8]);
#pragma unroll
        for (int i = 0; i < 4; i++)
#pragma unroll
            for (int j = 0; j < 4; j++)
                acc[i][j] = __builtin_amdgcn_mfma_f32_16x16x32_bf16(af[i], bfr[j], acc[i][j], 0, 0, 0);
        __syncthreads();
    }
#pragma unroll
    for (int i = 0; i < 4; i++)
#pragma unroll
        for (int j = 0; j < 4; j++) {
            int col = n0 + wc + j * 16 + l15;
            float bv = bias[col];
#pragma unroll
            for (int r = 0; r < 4; r++) {
                int row = m0 + wr + i * 16 + l4 * 4 + r;
                float o = (acc[i][j][r] + bv) * scl;
                if (OBF) ((unsigned short*)Cv)[(size_t)row * N + col] = rne_bf16(o);
                else     ((float*)Cv)[(size_t)row * N + col] = o;
            }
        }
}

// ---------------------------------------------------------------- q transform: rmsnorm -> wedge(S in LDS) -> rope -> 0.125 -> bf16 hi/lo, (b,h,t,d)
__global__ __launch_bounds__(256) void q_transform2(
    const float* __restrict__ qb, const float* __restrict__ S,
    const float* __restrict__ rc, const float* __restrict__ rs,
    unsigned short* __restrict__ qhi, unsigned short* __restrict__ qlo) {
    const int tid = threadIdx.x, wv = tid >> 6, lane = tid & 63;
    const int h = blockIdx.x >> 5, blk = blockIdx.x & 31;
    __shared__ float Sl[4096];
    __shared__ float sh[4][64];
    const float4* Sg = reinterpret_cast<const float4*>(S + h * 4096);
#pragma unroll
    for (int i = 0; i < 4; i++)
        reinterpret_cast<float4*>(Sl)[tid + 256 * i] = Sg[tid + 256 * i];
    __syncthreads();
    for (int it = 0; it < 16; ++it) {
        int r = (blk << 6) + (wv << 4) + it;        // 0..2047
        int b = r >> 10, t = r & 1023;
        const float* rowp = qb + ((((size_t)(b << 10) + t) * 48 + h) << 6);
        float v = rowp[lane];
        float ss = wave_sum(v * v);
        v *= 1.f / sqrtf(ss * (1.f / 64.f) + 1.1920928955078125e-07f);
        sh[wv][lane] = v;
        float acc = v;
#pragma unroll 8
        for (int d = 0; d < 64; d++) acc = fmaf(sh[wv][d], Sl[(d << 6) + lane], acc);
        sh[wv][lane] = acc;
        int j = lane & 31;
        float x1 = sh[wv][2 * j], x2 = sh[wv][2 * j + 1];
        float ct = rc[t * 32 + j], st = rs[t * 32 + j];
        float o = (lane < 32) ? (x1 * ct - x2 * st) : (x1 * st + x2 * ct);
        o *= 0.125f;
        unsigned short oh = rne_bf16(o);
        unsigned short ol = rne_bf16(o - bf2f(oh));
        size_t oidx = ((((size_t)(b * 48 + h)) << 10) + t) * 64 + lane;
        qhi[oidx] = oh;
        qlo[oidx] = ol;
    }
}

// ---------------------------------------------------------------- k transform: wedge -> rope -> bf16 hi/lo, (b,h,t,d)
__global__ __launch_bounds__(256) void k_transform2(
    const float* __restrict__ kb, const float* __restrict__ S,
    const float* __restrict__ rc, const float* __restrict__ rs,
    unsigned short* __restrict__ khi, unsigned short* __restrict__ klo) {
    const int tid = threadIdx.x, wv = tid >> 6, lane = tid & 63;
    const int h = blockIdx.x >> 5, blk = blockIdx.x & 31;
    const int hk = h % 12;
    __shared__ float Sl[4096];
    __shared__ float sh[4][64];
    const float4* Sg = reinterpret_cast<const float4*>(S + h * 4096);
#pragma unroll
    for (int i = 0; i < 4; i++)
        reinterpret_cast<float4*>(Sl)[tid + 256 * i] = Sg[tid + 256 * i];
    __syncthreads();
    for (int it = 0; it < 16; ++it) {
        int r = (blk << 6) + (wv << 4) + it;
        int b = r >> 10, t = r & 1023;
        const float* rowp = kb + ((((size_t)(b << 10) + t) * 12 + hk) << 6);
        float v = rowp[lane];
        sh[wv][lane] = v;
        float acc = v;
#pragma unroll 8
        for (int d = 0; d < 64; d++) acc = fmaf(sh[wv][d], Sl[(d << 6) + lane], acc);
        sh[wv][lane] = acc;
        int j = lane & 31;
        float x1 = sh[wv][2 * j], x2 = sh[wv][2 * j + 1];
        float ct = rc[t * 32 + j], st = rs[t * 32 + j];
        float o = (lane < 32) ? (x1 * ct - x2 * st) : (x1 * st + x2 * ct);
        unsigned short oh = rne_bf16(o);
        unsigned short ol = rne_bf16(o - bf2f(oh));
        size_t oidx = ((((size_t)(b * 48 + h)) << 10) + t) * 64 + lane;
        khi[oidx] = oh;
        klo[oidx] = ol;
    }
}

#define POPQ(qq)                                                                  \
    {                                                                             \
        bool tk = (qq[0] == hm);                                                  \
        qq[0]=tk?qq[1]:qq[0]; qq[1]=tk?qq[2]:qq[1]; qq[2]=tk?qq[3]:qq[2];         \
        qq[3]=tk?qq[4]:qq[3]; qq[4]=tk?qq[5]:qq[4]; qq[5]=tk?qq[6]:qq[5];         \
        qq[6]=tk?qq[7]:qq[6]; qq[7]=tk?qq[8]:qq[7]; qq[8]=tk?qq[9]:qq[8];         \
        qq[9]=tk?qq[10]:qq[9]; qq[10]=tk?qq[11]:qq[10]; qq[11]=tk?0u:qq[11];      \
    }

// ---------------------------------------------------------------- phase A: MFMA scores (hi/lo bf16, 3-product)
// one wave per (b,h,tile,half,part): 32 q-rows x up-to-256 kcols.
// mfma(A=K,B=Q): per lane qrow = base+ni*16+(lane&15), kcol = base+mi*16+(lane>>4)*4+r.
__global__ __launch_bounds__(64, 3) void attn_scores(
    const unsigned short* __restrict__ qhi, const unsigned short* __restrict__ qlo,
    const unsigned short* __restrict__ khi, const unsigned short* __restrict__ klo,
    float* __restrict__ pZ, unsigned int* __restrict__ pP) {
    const int lane = threadIdx.x;
    const int bid = blockIdx.x;
    const int u = bid / 96, bh = bid % 96;
    const int tile = c_tileTab[u >> 1], part = c_partTab[u >> 1], half = u & 1;
    const int l15 = lane & 15, l4 = lane >> 4;
    const int t0 = (tile << 6) + (half << 5);
    const int c0 = part << 2;
    const int c1 = min(c0 + 4, tile + 1);
    const size_t base = ((size_t)bh) << 16;

    bf16x8 qh8[2][2], ql8[2][2];
#pragma unroll
    for (int ni = 0; ni < 2; ni++)
#pragma unroll
        for (int ks = 0; ks < 2; ks++) {
            size_t off = base + (size_t)(t0 + ni * 16 + l15) * 64 + ks * 32 + l4 * 8;
            qh8[ni][ks] = *reinterpret_cast<const bf16x8*>(qhi + off);
            ql8[ni][ks] = *reinterpret_cast<const bf16x8*>(qlo + off);
        }

    unsigned int pl[2][12];
#pragma unroll
    for (int ni = 0; ni < 2; ni++)
#pragma unroll
        for (int i = 0; i < 12; i++) pl[ni][i] = 0u;
    float Zp[2] = {0.f, 0.f};

    for (int cc = c0; cc < c1; ++cc) {
        f32x4 acc[4][2] = {};
#pragma unroll
        for (int ks = 0; ks < 2; ks++) {
            bf16x8 kh8[4], kl8[4];
#pragma unroll
            for (int mi = 0; mi < 4; mi++) {
                size_t off = base + (size_t)((cc << 6) + mi * 16 + l15) * 64 + ks * 32 + l4 * 8;
                kh8[mi] = *reinterpret_cast<const bf16x8*>(khi + off);
                kl8[mi] = *reinterpret_cast<const bf16x8*>(klo + off);
            }
#pragma unroll
            for (int mi = 0; mi < 4; mi++)
#pragma unroll
                for (int ni = 0; ni < 2; ni++) {
                    acc[mi][ni] = __builtin_amdgcn_mfma_f32_16x16x32_bf16(kh8[mi], qh8[ni][ks], acc[mi][ni], 0, 0, 0);
                    acc[mi][ni] = __builtin_amdgcn_mfma_f32_16x16x32_bf16(kh8[mi], ql8[ni][ks], acc[mi][ni], 0, 0, 0);
                    acc[mi][ni] = __builtin_amdgcn_mfma_f32_16x16x32_bf16(kl8[mi], qh8[ni][ks], acc[mi][ni], 0, 0, 0);
                }
        }
        // consume 32 values: 2 qrows x 16 kcols per lane
#pragma unroll
        for (int ni = 0; ni < 2; ni++) {
            const int tq = t0 + ni * 16 + l15;
#pragma unroll
            for (int mi = 0; mi < 4; mi++)
#pragma unroll
                for (int r = 0; r < 4; r++) {
                    int kcol = (cc << 6) + mi * 16 + l4 * 4 + r;
                    float s = acc[mi][ni][r];
                    bool ok = kcol <= tq;
                    float e = __expf(s);
                    Zp[ni] += ok ? e : 0.f;
                    unsigned su = __float_as_uint(s);
                    unsigned key = su ^ ((unsigned)(((int)su) >> 31) | 0x80000000u);
                    unsigned pk = (key & 0xFFFFFC00u) | (unsigned)(1023 - kcol);
                    pk = ok ? pk : 0u;
#pragma unroll
                    for (int jj = 0; jj < 12; jj++) {
                        unsigned mx = pl[ni][jj] > pk ? pl[ni][jj] : pk;
                        pk = pl[ni][jj] > pk ? pk : pl[ni][jj];
                        pl[ni][jj] = mx;
                    }
                }
        }
    }

    // in-wave 4-lane merge per qrow
    __shared__ unsigned int lsh[64][2][12];
    __shared__ float zsh[64][2];
#pragma unroll
    for (int ni = 0; ni < 2; ni++) {
#pragma unroll
        for (int i = 0; i < 12; i++) lsh[lane][ni][i] = pl[ni][i];
        zsh[lane][ni] = Zp[ni];
    }
    __syncthreads();
    if (lane < 32) {
        const int ni = lane >> 4, c = lane & 15;
        unsigned int m0[12], m1[12], m2[12], m3[12];
#pragma unroll
        for (int i = 0; i < 12; i++) {
            m0[i] = lsh[c][ni][i];
            m1[i] = lsh[c + 16][ni][i];
            m2[i] = lsh[c + 32][ni][i];
            m3[i] = lsh[c + 48][ni][i];
        }
        float Z = zsh[c][ni] + zsh[c + 16][ni] + zsh[c + 32][ni] + zsh[c + 48][ni];
        unsigned int out[12];
#pragma unroll
        for (int rd = 0; rd < 12; rd++) {
            unsigned int ha = m0[0] > m1[0] ? m0[0] : m1[0];
            unsigned int hb2 = m2[0] > m3[0] ? m2[0] : m3[0];
            unsigned int hm = ha > hb2 ? ha : hb2;
            POPQ(m0); POPQ(m1); POPQ(m2); POPQ(m3);
            out[rd] = hm;
        }
        const size_t r = (((size_t)bh) << 10) + t0 + lane;
        pZ[r * 4 + part] = Z;
        unsigned int* pp = pP + r * 48 + part * 12;
        *reinterpret_cast<uint4*>(pp + 0) = make_uint4(out[0], out[1], out[2], out[3]);
        *reinterpret_cast<uint4*>(pp + 4) = make_uint4(out[4], out[5], out[6], out[7]);
        *reinterpret_cast<uint4*>(pp + 8) = make_uint4(out[8], out[9], out[10], out[11]);
    }
}

// ---------------------------------------------------------------- phase B: merge partials + marker gather -> bf16
#define LDLIST(dst, o, valid)                                                     \
    {                                                                             \
        uint4 x0, x1, x2;                                                         \
        if (valid) { x0 = pp[o]; x1 = pp[o + 1]; x2 = pp[o + 2]; }                \
        else { x0 = make_uint4(0,0,0,0); x1 = x0; x2 = x0; }                      \
        dst[0]=x0.x; dst[1]=x0.y; dst[2]=x0.z; dst[3]=x0.w;                       \
        dst[4]=x1.x; dst[5]=x1.y; dst[6]=x1.z; dst[7]=x1.w;                       \
        dst[8]=x2.x; dst[9]=x2.y; dst[10]=x2.z; dst[11]=x2.w;                     \
    }

__global__ __launch_bounds__(256) void attn_merge(
    const unsigned int* __restrict__ pP, const float* __restrict__ pZ,
    const float* __restrict__ kb, const float* __restrict__ sink_s,
    unsigned short* __restrict__ mkbuf, float* __restrict__ psbuf) {
    const int tid = threadIdx.x, wv = tid >> 6, lane = tid & 63;
    const int wid = blockIdx.x * 4 + wv;
    const int tile = wid & 15, bh = wid >> 4;
    const int h = bh % 48, b = bh / 48, hk = h % 12;
    const int t = (tile << 6) + lane;
    const size_t r = (((size_t)bh) << 10) + t;
    const int npart = (tile >> 2) + 1;

    unsigned int q0[12], q1[12], q2[12], q3[12];
    const uint4* pp = reinterpret_cast<const uint4*>(pP + r * 48);
    LDLIST(q0, 0, true);
    LDLIST(q1, 3, npart > 1);
    LDLIST(q2, 6, npart > 2);
    LDLIST(q3, 9, npart > 3);

    float Z = pZ[r * 4 + 0];
    if (npart > 1) Z += pZ[r * 4 + 1];
    if (npart > 2) Z += pZ[r * 4 + 2];
    if (npart > 3) Z += pZ[r * 4 + 3];
    const float es = __expf(sink_s[h]);
    const float invZ = 1.f / (Z + es);

    const float* kvan = kb + (((size_t)b * 12288 + hk) << 6);
    float4 mk[16];
#pragma unroll
    for (int i = 0; i < 16; i++) mk[i] = make_float4(0.f, 0.f, 0.f, 0.f);

#pragma unroll
    for (int rd = 0; rd < 12; rd++) {
        unsigned int ha = q0[0] > q1[0] ? q0[0] : q1[0];
        unsigned int hb2 = q2[0] > q3[0] ? q2[0] : q3[0];
        unsigned int hm = ha > hb2 ? ha : hb2;
        POPQ(q0); POPQ(q1); POPQ(q2); POPQ(q3);
        unsigned int key = hm & 0xFFFFFC00u;
        unsigned int uu = (key & 0x80000000u) ? (key ^ 0x80000000u) : ~key;
        float v = __uint_as_float(uu);
        int idx = 1023 - (int)(hm & 1023u);
        float w = (hm == 0u) ? 0.f : __expf(v) * invZ;
        const float4* kr = reinterpret_cast<const float4*>(kvan + (size_t)idx * 768);
#pragma unroll
        for (int i = 0; i < 16; i++) {
            float4 kv = kr[i];
            mk[i].x = fmaf(w, kv.x, mk[i].x);
            mk[i].y = fmaf(w, kv.y, mk[i].y);
            mk[i].z = fmaf(w, kv.z, mk[i].z);
            mk[i].w = fmaf(w, kv.w, mk[i].w);
        }
    }
    const float4* sr = reinterpret_cast<const float4*>(kvan + (size_t)t * 768);
    unsigned short* mo = mkbuf + (r << 6);
#pragma unroll
    for (int i = 0; i < 16; i++) {
        float4 sv = sr[i];
        ushort4 o;
        o.x = rne_bf16((mk[i].x + sv.x) * (1.f / 13.f));
        o.y = rne_bf16((mk[i].y + sv.y) * (1.f / 13.f));
        o.z = rne_bf16((mk[i].z + sv.z) * (1.f / 13.f));
        o.w = rne_bf16((mk[i].w + sv.w) * (1.f / 13.f));
        *reinterpret_cast<ushort4*>(mo + i * 4) = o;
    }
    psbuf[r] = es * invZ;
}

// ---------------------------------------------------------------- activation + rmsnorm(256) + gate, in place (bf16)
__global__ __launch_bounds__(256) void act_kernel(unsigned short* __restrict__ hb) {
    const int tid = threadIdx.x, wv = tid >> 6, lane = tid & 63;
    const size_t row = (size_t)blockIdx.x * 4 + wv;
    ushort4* p = reinterpret_cast<ushort4*>(hb + (row << 8)) + lane;
    ushort4 xu = *p;
    float xs[4] = {bf2f(xu.x), bf2f(xu.y), bf2f(xu.z), bf2f(xu.w)};
    float ys[4];
    float ss = 0.f;
#pragma unroll
    for (int i = 0; i < 4; i++) {
        float x = xs[i];
        float y = x * x + 0.75f * x * x * x;
        ys[i] = y;
        ss += y * y;
    }
    ss = wave_sum(ss);
    float rinv = 1.f / sqrtf(ss * (1.f / 256.f) + 1.1920928955078125e-07f);
    ushort4 o;
    unsigned short* po = reinterpret_cast<unsigned short*>(&o);
#pragma unroll
    for (int i = 0; i < 4; i++) {
        float z = ys[i] * rinv;
        po[i] = rne_bf16(z / (1.f + __expf(-1.8137993642342178f * z)));
    }
    *p = o;
}

// ---------------------------------------------------------------- proj GEMM (bf16 A, f32 W) + sink epilogue -> ctx bf16
__global__ __launch_bounds__(256) void proj_gemm(const unsigned short* __restrict__ A,
                                                 const float* __restrict__ W,
                                                 const float* __restrict__ bias, const float* __restrict__ ps,
                                                 const float* __restrict__ vn, unsigned short* __restrict__ ctx) {
    __shared__ float As[16][68];
    __shared__ float Ws[16][68];
    const int bm = blockIdx.y * 64;
    const int tid = threadIdx.x;
    const int tx = tid & 15, ty = tid >> 4;
    float acc[4][4] = {};
    const int mm = tid >> 2;
    const int kk4 = (tid & 3) * 4;
    for (int k0 = 0; k0 < 256; k0 += 16) {
        ushort4 au = *reinterpret_cast<const ushort4*>(&A[(size_t)(bm + mm) * 256 + k0 + kk4]);
        As[kk4 + 0][mm] = bf2f(au.x); As[kk4 + 1][mm] = bf2f(au.y);
        As[kk4 + 2][mm] = bf2f(au.z); As[kk4 + 3][mm] = bf2f(au.w);
        float4 wv = *reinterpret_cast<const float4*>(&W[(size_t)mm * 256 + k0 + kk4]);
        Ws[kk4 + 0][mm] = wv.x; Ws[kk4 + 1][mm] = wv.y; Ws[kk4 + 2][mm] = wv.z; Ws[kk4 + 3][mm] = wv.w;
        __syncthreads();
#pragma unroll
        for (int kk = 0; kk < 16; kk++) {
            float a0 = As[kk][ty * 4 + 0], a1 = As[kk][ty * 4 + 1], a2 = As[kk][ty * 4 + 2], a3 = As[kk][ty * 4 + 3];
            float b0 = Ws[kk][tx * 4 + 0], b1 = Ws[kk][tx * 4 + 1], b2 = Ws[kk][tx * 4 + 2], b3 = Ws[kk][tx * 4 + 3];
            acc[0][0] += a0 * b0; acc[0][1] += a0 * b1; acc[0][2] += a0 * b2; acc[0][3] += a0 * b3;
            acc[1][0] += a1 * b0; acc[1][1] += a1 * b1; acc[1][2] += a1 * b2; acc[1][3] += a1 * b3;
            acc[2][0] += a2 * b0; acc[2][1] += a2 * b1; acc[2][2] += a2 * b2; acc[2][3] += a2 * b3;
            acc[3][0] += a3 * b0; acc[3][1] += a3 * b1; acc[3][2] += a3 * b2; acc[3][3] += a3 * b3;
        }
        __syncthreads();
    }
#pragma unroll
    for (int i = 0; i < 4; i++) {
        int rm = bm + ty * 4 + i;
        int g = rm >> 10, t = rm & 1023;
        int hh = g % 48, bb = g / 48;
        float p = ps[rm];
        const float* v = vn + hh * 64 + tx * 4;
        ushort4 o;
        o.x = rne_bf16(acc[i][0] + bias[tx * 4 + 0] + p * v[0]);
        o.y = rne_bf16(acc[i][1] + bias[tx * 4 + 1] + p * v[1]);
        o.z = rne_bf16(acc[i][2] + bias[tx * 4 + 2] + p * v[2]);
        o.w = rne_bf16(acc[i][3] + bias[tx * 4 + 3] + p * v[3]);
        *reinterpret_cast<ushort4*>(&ctx[((((size_t)(bb << 10) + t) * 48 + hh) << 6) + tx * 4]) = o;
    }
}

// ---------------------------------------------------------------- launch
extern "C" void kernel_launch(void* const* d_in, const int* in_sizes, int n_in,
                              void* d_out, int out_size, void* d_ws, size_t ws_size,
                              hipStream_t stream) {
    (void)in_sizes; (void)n_in; (void)out_size; (void)ws_size;
    const float* A       = (const float*)d_in[0];
    const float* X       = (const float*)d_in[1];
    const float* Wq_w    = (const float*)d_in[2];
    const float* Wq_b    = (const float*)d_in[3];
    const float* Wk_w    = (const float*)d_in[4];
    const float* Wk_b    = (const float*)d_in[5];
    const float* wedge_A = (const float*)d_in[6];
    const float* wedge_b = (const float*)d_in[7];
    const float* sink    = (const float*)d_in[8];
    const float* v_nulls = (const float*)d_in[9];
    const float* fc_w    = (const float*)d_in[10];
    const float* fc_b    = (const float*)d_in[11];
    const float* proj_w  = (const float*)d_in[12];
    const float* proj_b  = (const float*)d_in[13];
    const float* WO      = (const float*)d_in[14];
    const float* WO_b    = (const float*)d_in[15];
    float* out = (float*)d_out;
    float* ws  = (float*)d_ws;

    // ---- workspace layout (float offsets) ----
    float*          qbuf   = ws;                                  // [0, 6291456) f32; later ctx_bf + mk_bf
    unsigned short* ctx_bf = (unsigned short*)ws;
    unsigned short* mk_bf  = (unsigned short*)(ws + 3145728);
    float*          kbbuf  = ws + 6291456;                        // [6291456, 7864320)
    unsigned short* q_hi   = (unsigned short*)(ws + 7864320);     // [7864320, 11010048)
    unsigned short* q_lo   = (unsigned short*)(ws + 11010048);    // [11010048, 14155776)
    unsigned short* kf_hi  = (unsigned short*)(ws + 14155776);    // [14155776, 17301504)
    unsigned short* kf_lo  = (unsigned short*)(ws + 17301504);    // [17301504, 20447232)
    unsigned short* hbuf   = (unsigned short*)(ws + 7864320);     // overlays q/k bf16 (dead after scores)
    // R5 [20447232, 25559040): early = cvt scratch + S/rc/rs; late = pZ + pP
    unsigned short* A_bf   = (unsigned short*)(ws + 20447232);
    unsigned short* X_bf   = (unsigned short*)(ws + 21233664);
    unsigned short* Wq_bf  = (unsigned short*)(ws + 22020096);
    unsigned short* Wk_bf  = (unsigned short*)(ws + 23199744);
    float*          Sbuf   = ws + 23494656;
    float*          rcbuf  = ws + 23691264;
    float*          rsbuf  = ws + 23724032;
    float*          pZ     = ws + 20447232;
    unsigned int*   pP     = (unsigned int*)(ws + 20840448);
    // R6 [25559040, 26846208)
    float*          wob    = ws + 25559040;
    float*          psbuf  = ws + 25560064;
    unsigned short* fcw_bf = (unsigned short*)(ws + 25658368);
    unsigned short* WOt_bf = (unsigned short*)(ws + 25666560);
    // end: 26,846,208 floats = 107.4 MB

    prep_kernel<<<(48 * 64 * 64 + 1024 * 32 + 768 + 255) / 256, 256, 0, stream>>>(
        wedge_A, wedge_b, WO_b, Sbuf, rcbuf, rsbuf, wob);
    cvt_all<<<5968, 256, 0, stream>>>(A, X, Wq_w, Wk_w, fc_w, A_bf, X_bf, Wq_bf, Wk_bf, fcw_bf);
    wo_transpose<<<dim3(24, 24, 4), 256, 0, stream>>>(WO, WOt_bf);

    gemm_bf16k<0><<<dim3(24, 16), 256, 0, stream>>>(A_bf, Wq_bf, Wq_b, qbuf, 2048, 3072, 768, 1.f);
    gemm_bf16k<0><<<dim3(6, 16), 256, 0, stream>>>(X_bf, Wk_bf, Wk_b, kbbuf, 2048, 768, 768, 1.f);
    q_transform2<<<1536, 256, 0, stream>>>(qbuf, Sbuf, rcbuf, rsbuf, q_hi, q_lo);
    k_transform2<<<1536, 256, 0, stream>>>(kbbuf, Sbuf, rcbuf, rsbuf, kf_hi, kf_lo);
    attn_scores<<<7680, 64, 0, stream>>>(q_hi, q_lo, kf_hi, kf_lo, pZ, pP);
    attn_merge<<<384, 256, 0, stream>>>(pP, pZ, kbbuf, sink, mk_bf, psbuf);
    gemm_bf16k<1><<<dim3(2, 768), 256, 0, stream>>>(mk_bf, fcw_bf, fc_b, hbuf, 98304, 256, 64, 1.f);
    act_kernel<<<24576, 256, 0, stream>>>(hbuf);
    proj_gemm<<<dim3(1, 1536), 256, 0, stream>>>(hbuf, proj_w, proj_b, psbuf, v_nulls, ctx_bf);
    gemm_bf16k<0><<<dim3(6, 16), 256, 0, stream>>>(ctx_bf, WOt_bf, wob, out, 2048, 768, 3072, 0.25f);
}

// Round 7
// 405.541 us; speedup vs baseline: 9.6253x; 1.1736x over previous
//
#include <hip/hip_runtime.h>
#include <math.h>

#define B_   2
#define T_   1024
#define C_   768
#define DH_  64
#define NH_  12
#define HT_  48

typedef short bf16x8 __attribute__((ext_vector_type(8)));
typedef float f32x4 __attribute__((ext_vector_type(4)));

__device__ __forceinline__ float wave_sum(float v) {
#pragma unroll
    for (int off = 32; off; off >>= 1) v += __shfl_xor(v, off, 64);
    return v;
}
__device__ __forceinline__ unsigned short rne_bf16(float f) {
    unsigned u = __float_as_uint(f);
    return (unsigned short)((u + 0x7FFFu + ((u >> 16) & 1u)) >> 16);
}
__device__ __forceinline__ float bf2f(unsigned short u) {
    return __uint_as_float((unsigned)u << 16);
}

#define LOG2E 1.4426950408889634f

// work tables: 40 (tile,part) units per (b,h), heavy-first. chunk = 64 cols, part = 4 chunks.
__constant__ int c_tileTab[40] = {15,15,15,15, 14,14,14, 13,13,13, 12,12,12, 11,11,11,
                                  10,10, 9,9, 8,8, 7,7, 6, 5, 4, 3,
                                  14,10,6,2, 13,9,5,1, 12,8,4,0};
__constant__ int c_partTab[40] = { 0, 1, 2, 3,  0, 1, 2,  0, 1, 2,  0, 1, 2,  0, 1, 2,
                                   0, 1, 0,1, 0,1, 0,1, 0, 0, 0, 0,
                                   3, 2,1,0,  3,2,1,0,  3,2,1,0};

// ---------------------------------------------------------------- prep
__global__ void prep_kernel(const float* __restrict__ wA, const float* __restrict__ wb,
                            const float* __restrict__ WOb,
                            float* __restrict__ S, float* __restrict__ rc,
                            float* __restrict__ rs, float* __restrict__ wob) {
    int i = blockIdx.x * 256 + threadIdx.x;
    if (i < HT_ * 64 * 64) {
        int e = i & 63, d = (i >> 6) & 63, h = i >> 12;
        float v = wA[d * 64 + e] - wA[e * 64 + d];
        if (d == e) v += wb[h * 64 + d];
        S[i] = v;
    } else if (i < HT_ * 64 * 64 + T_ * 32) {
        int j = i - HT_ * 64 * 64;
        int t = j >> 5, f = j & 31;
        float invf = (float)(1.0 / pow(10000.0, (double)f / 32.0));
        float fr = (float)t * invf;
        rc[j] = cosf(fr);
        rs[j] = sinf(fr);
    } else if (i < HT_ * 64 * 64 + T_ * 32 + C_) {
        int d = i - (HT_ * 64 * 64 + T_ * 32);
        wob[d] = WOb[d] + WOb[C_ + d] + WOb[2 * C_ + d] + WOb[3 * C_ + d];
    }
}

// ---------------------------------------------------------------- fused f32->bf16 conversions
__global__ void cvt_all(const float* __restrict__ A, const float* __restrict__ X,
                        const float* __restrict__ Wq, const float* __restrict__ Wk,
                        const float* __restrict__ fcw, const float* __restrict__ pw,
                        unsigned short* __restrict__ Ab, unsigned short* __restrict__ Xb,
                        unsigned short* __restrict__ Wqb, unsigned short* __restrict__ Wkb,
                        unsigned short* __restrict__ fcb, unsigned short* __restrict__ pwb) {
    int i = blockIdx.x * 256 + threadIdx.x;   // float4 index
    const float* s; unsigned short* d; int o;
    if (i < 393216)       { s = A;   d = Ab;  o = i; }
    else if (i < 786432)  { s = X;   d = Xb;  o = i - 393216; }
    else if (i < 1376256) { s = Wq;  d = Wqb; o = i - 786432; }
    else if (i < 1523712) { s = Wk;  d = Wkb; o = i - 1376256; }
    else if (i < 1527808) { s = fcw; d = fcb; o = i - 1523712; }
    else if (i < 1531904) { s = pw;  d = pwb; o = i - 1527808; }
    else return;
    float4 v = reinterpret_cast<const float4*>(s)[o];
    ushort4 u;
    u.x = rne_bf16(v.x); u.y = rne_bf16(v.y); u.z = rne_bf16(v.z); u.w = rne_bf16(v.w);
    reinterpret_cast<ushort4*>(d)[o] = u;
}

// ---------------------------------------------------------------- WO (4,768,768) -> WOt[d][n*768+c] bf16
__global__ __launch_bounds__(256) void wo_transpose(const float* __restrict__ WO,
                                                    unsigned short* __restrict__ WOt) {
    __shared__ float tl[32][33];
    const int n = blockIdx.z;
    const int c0 = blockIdx.x * 32, d0 = blockIdx.y * 32;
    const int tx = threadIdx.x & 31, ty = threadIdx.x >> 5;
#pragma unroll
    for (int p = 0; p < 4; p++)
        tl[ty + p * 8][tx] = WO[(size_t)n * 589824 + (size_t)(c0 + ty + p * 8) * 768 + d0 + tx];
    __syncthreads();
#pragma unroll
    for (int p = 0; p < 4; p++)
        WOt[(size_t)(d0 + ty + p * 8) * 3072 + n * 768 + c0 + tx] = rne_bf16(tl[tx][ty + p * 8]);
}

// ---------------------------------------------------------------- bf16 MFMA GEMM 128x128: C = (A @ W^T + bias) * scl
__global__ __launch_bounds__(256) void gemm_bf16k(const unsigned short* __restrict__ A,
                                                  const unsigned short* __restrict__ W,
                                                  const float* __restrict__ bias,
                                                  float* __restrict__ C,
                                                  int M, int N, int K, float scl) {
    __shared__ unsigned short Asd[128][40];
    __shared__ unsigned short Bsd[128][40];
    const int tid = threadIdx.x;
    const int wv = tid >> 6, lane = tid & 63;
    const int m0 = blockIdx.y * 128, n0 = blockIdx.x * 128;
    const int wr = (wv >> 1) * 64, wc = (wv & 1) * 64;
    const int l15 = lane & 15, l4 = lane >> 4;
    const int srow = tid >> 2, soff = (tid & 3) * 8;
    f32x4 acc[4][4] = {};
    for (int k0 = 0; k0 < K; k0 += 32) {
        uint4 a0 = *reinterpret_cast<const uint4*>(A + (size_t)(m0 + srow) * K + k0 + soff);
        uint4 a1 = *reinterpret_cast<const uint4*>(A + (size_t)(m0 + srow + 64) * K + k0 + soff);
        uint4 b0 = *reinterpret_cast<const uint4*>(W + (size_t)(n0 + srow) * K + k0 + soff);
        uint4 b1 = *reinterpret_cast<const uint4*>(W + (size_t)(n0 + srow + 64) * K + k0 + soff);
        *reinterpret_cast<uint4*>(&Asd[srow][soff])      = a0;
        *reinterpret_cast<uint4*>(&Asd[srow + 64][soff]) = a1;
        *reinterpret_cast<uint4*>(&Bsd[srow][soff])      = b0;
        *reinterpret_cast<uint4*>(&Bsd[srow + 64][soff]) = b1;
        __syncthreads();
        bf16x8 af[4], bfr[4];
#pragma unroll
        for (int i = 0; i < 4; i++)
            af[i] = *reinterpret_cast<const bf16x8*>(&Asd[wr + i * 16 + l15][l4 * 8]);
#pragma unroll
        for (int j = 0; j < 4; j++)
            bfr[j] = *reinterpret_cast<const bf16x8*>(&Bsd[wc + j * 16 + l15][l4 * 8]);
#pragma unroll
        for (int i = 0; i < 4; i++)
#pragma unroll
            for (int j = 0; j < 4; j++)
                acc[i][j] = __builtin_amdgcn_mfma_f32_16x16x32_bf16(af[i], bfr[j], acc[i][j], 0, 0, 0);
        __syncthreads();
    }
#pragma unroll
    for (int i = 0; i < 4; i++)
#pragma unroll
        for (int j = 0; j < 4; j++) {
            int col = n0 + wc + j * 16 + l15;
            float bv = bias[col];
#pragma unroll
            for (int r = 0; r < 4; r++) {
                int row = m0 + wr + i * 16 + l4 * 4 + r;
                C[(size_t)row * N + col] = (acc[i][j][r] + bv) * scl;
            }
        }
}

// ---------------------------------------------------------------- bf16 MFMA GEMM 64x64 tile (4 waves, 16 rows each)
__global__ __launch_bounds__(256) void gemm_bf16_64(const unsigned short* __restrict__ A,
                                                    const unsigned short* __restrict__ W,
                                                    const float* __restrict__ bias,
                                                    float* __restrict__ C,
                                                    int M, int N, int K, float scl) {
    __shared__ unsigned short Asd[64][40];
    __shared__ unsigned short Bsd[64][40];
    const int tid = threadIdx.x;
    const int wv = tid >> 6, lane = tid & 63;
    const int m0 = blockIdx.y * 64, n0 = blockIdx.x * 64;
    const int l15 = lane & 15, l4 = lane >> 4;
    const int srow = tid >> 2, soff = (tid & 3) * 8;
    f32x4 acc[4] = {};
    for (int k0 = 0; k0 < K; k0 += 32) {
        uint4 a0 = *reinterpret_cast<const uint4*>(A + (size_t)(m0 + srow) * K + k0 + soff);
        uint4 b0 = *reinterpret_cast<const uint4*>(W + (size_t)(n0 + srow) * K + k0 + soff);
        *reinterpret_cast<uint4*>(&Asd[srow][soff]) = a0;
        *reinterpret_cast<uint4*>(&Bsd[srow][soff]) = b0;
        __syncthreads();
        bf16x8 af = *reinterpret_cast<const bf16x8*>(&Asd[wv * 16 + l15][l4 * 8]);
#pragma unroll
        for (int j = 0; j < 4; j++) {
            bf16x8 bfr = *reinterpret_cast<const bf16x8*>(&Bsd[j * 16 + l15][l4 * 8]);
            acc[j] = __builtin_amdgcn_mfma_f32_16x16x32_bf16(af, bfr, acc[j], 0, 0, 0);
        }
        __syncthreads();
    }
#pragma unroll
    for (int j = 0; j < 4; j++) {
        int col = n0 + j * 16 + l15;
        float bv = bias[col];
#pragma unroll
        for (int r = 0; r < 4; r++) {
            int row = m0 + wv * 16 + l4 * 4 + r;
            C[(size_t)row * N + col] = (acc[j][r] + bv) * scl;
        }
    }
}

// ---------------------------------------------------------------- q transform: rmsnorm -> wedge -> rope -> *0.125*log2e -> bf16 hi/lo
__global__ __launch_bounds__(256) void q_transform2(
    const float* __restrict__ qb, const float* __restrict__ S,
    const float* __restrict__ rc, const float* __restrict__ rs,
    unsigned short* __restrict__ qhi, unsigned short* __restrict__ qlo) {
    const int tid = threadIdx.x, wv = tid >> 6, lane = tid & 63;
    const int h = blockIdx.x >> 5, blk = blockIdx.x & 31;
    __shared__ float Sl[4096];
    __shared__ float sh[4][64];
    const float4* Sg = reinterpret_cast<const float4*>(S + h * 4096);
#pragma unroll
    for (int i = 0; i < 4; i++)
        reinterpret_cast<float4*>(Sl)[tid + 256 * i] = Sg[tid + 256 * i];
    __syncthreads();
    for (int it = 0; it < 16; ++it) {
        int r = (blk << 6) + (wv << 4) + it;        // 0..2047
        int b = r >> 10, t = r & 1023;
        const float* rowp = qb + ((((size_t)(b << 10) + t) * 48 + h) << 6);
        float v = rowp[lane];
        float ss = wave_sum(v * v);
        v *= 1.f / sqrtf(ss * (1.f / 64.f) + 1.1920928955078125e-07f);
        sh[wv][lane] = v;
        float acc = v;
#pragma unroll 8
        for (int d = 0; d < 64; d++) acc = fmaf(sh[wv][d], Sl[(d << 6) + lane], acc);
        sh[wv][lane] = acc;
        int j = lane & 31;
        float x1 = sh[wv][2 * j], x2 = sh[wv][2 * j + 1];
        float ct = rc[t * 32 + j], st = rs[t * 32 + j];
        float o = (lane < 32) ? (x1 * ct - x2 * st) : (x1 * st + x2 * ct);
        o *= 0.125f * LOG2E;                         // exp2 domain
        unsigned short oh = rne_bf16(o);
        unsigned short ol = rne_bf16(o - bf2f(oh));
        size_t oidx = ((((size_t)(b * 48 + h)) << 10) + t) * 64 + lane;
        qhi[oidx] = oh;
        qlo[oidx] = ol;
    }
}

// ---------------------------------------------------------------- k transform: wedge -> rope -> bf16 hi/lo
__global__ __launch_bounds__(256) void k_transform2(
    const float* __restrict__ kb, const float* __restrict__ S,
    const float* __restrict__ rc, const float* __restrict__ rs,
    unsigned short* __restrict__ khi, unsigned short* __restrict__ klo) {
    const int tid = threadIdx.x, wv = tid >> 6, lane = tid & 63;
    const int h = blockIdx.x >> 5, blk = blockIdx.x & 31;
    const int hk = h % 12;
    __shared__ float Sl[4096];
    __shared__ float sh[4][64];
    const float4* Sg = reinterpret_cast<const float4*>(S + h * 4096);
#pragma unroll
    for (int i = 0; i < 4; i++)
        reinterpret_cast<float4*>(Sl)[tid + 256 * i] = Sg[tid + 256 * i];
    __syncthreads();
    for (int it = 0; it < 16; ++it) {
        int r = (blk << 6) + (wv << 4) + it;
        int b = r >> 10, t = r & 1023;
        const float* rowp = kb + ((((size_t)(b << 10) + t) * 12 + hk) << 6);
        float v = rowp[lane];
        sh[wv][lane] = v;
        float acc = v;
#pragma unroll 8
        for (int d = 0; d < 64; d++) acc = fmaf(sh[wv][d], Sl[(d << 6) + lane], acc);
        sh[wv][lane] = acc;
        int j = lane & 31;
        float x1 = sh[wv][2 * j], x2 = sh[wv][2 * j + 1];
        float ct = rc[t * 32 + j], st = rs[t * 32 + j];
        float o = (lane < 32) ? (x1 * ct - x2 * st) : (x1 * st + x2 * ct);
        unsigned short oh = rne_bf16(o);
        unsigned short ol = rne_bf16(o - bf2f(oh));
        size_t oidx = ((((size_t)(b * 48 + h)) << 10) + t) * 64 + lane;
        khi[oidx] = oh;
        klo[oidx] = ol;
    }
}

#define POPQ(qq)                                                                  \
    {                                                                             \
        bool tk = (qq[0] == hm);                                                  \
        qq[0]=tk?qq[1]:qq[0]; qq[1]=tk?qq[2]:qq[1]; qq[2]=tk?qq[3]:qq[2];         \
        qq[3]=tk?qq[4]:qq[3]; qq[4]=tk?qq[5]:qq[4]; qq[5]=tk?qq[6]:qq[5];         \
        qq[6]=tk?qq[7]:qq[6]; qq[7]=tk?qq[8]:qq[7]; qq[8]=tk?qq[9]:qq[8];         \
        qq[9]=tk?qq[10]:qq[9]; qq[10]=tk?qq[11]:qq[10]; qq[11]=tk?0u:qq[11];      \
    }

#define TOP12INS(pln, pk)                                                         \
    {                                                                             \
        unsigned _p = (pk);                                                       \
        _Pragma("unroll")                                                         \
        for (int jj = 0; jj < 12; jj++) {                                         \
            unsigned mx = pln[jj] > _p ? pln[jj] : _p;                            \
            _p = pln[jj] > _p ? _p : pln[jj];                                     \
            pln[jj] = mx;                                                         \
        }                                                                         \
    }

// ---------------------------------------------------------------- phase A: MFMA scores, exp2 domain, 4-wave blocks
__global__ __launch_bounds__(256) void attn_scores(
    const unsigned short* __restrict__ qhi, const unsigned short* __restrict__ qlo,
    const unsigned short* __restrict__ khi, const unsigned short* __restrict__ klo,
    float* __restrict__ pZ, unsigned int* __restrict__ pP) {
    const int tid = threadIdx.x, wv = tid >> 6, lane = tid & 63;
    const int unit = blockIdx.x * 4 + wv;
    const int u = unit / 96, bh = unit % 96;
    const int tile = c_tileTab[u >> 1], part = c_partTab[u >> 1], half = u & 1;
    const int l15 = lane & 15, l4 = lane >> 4;
    const int t0 = (tile << 6) + (half << 5);
    const int c0 = part << 2;
    const int c1 = min(c0 + 4, tile + 1);
    const size_t base = ((size_t)bh) << 16;

    bf16x8 qh8[2][2], ql8[2][2];
#pragma unroll
    for (int ni = 0; ni < 2; ni++)
#pragma unroll
        for (int ks = 0; ks < 2; ks++) {
            size_t off = base + (size_t)(t0 + ni * 16 + l15) * 64 + ks * 32 + l4 * 8;
            qh8[ni][ks] = *reinterpret_cast<const bf16x8*>(qhi + off);
            ql8[ni][ks] = *reinterpret_cast<const bf16x8*>(qlo + off);
        }

    unsigned int pl[2][12];
#pragma unroll
    for (int ni = 0; ni < 2; ni++)
#pragma unroll
        for (int i = 0; i < 12; i++) pl[ni][i] = 0u;
    float Zp[2] = {0.f, 0.f};

    for (int cc = c0; cc < c1; ++cc) {
        f32x4 acc[4][2] = {};
#pragma unroll
        for (int ks = 0; ks < 2; ks++) {
            bf16x8 kh8[4], kl8[4];
#pragma unroll
            for (int mi = 0; mi < 4; mi++) {
                size_t off = base + (size_t)((cc << 6) + mi * 16 + l15) * 64 + ks * 32 + l4 * 8;
                kh8[mi] = *reinterpret_cast<const bf16x8*>(khi + off);
                kl8[mi] = *reinterpret_cast<const bf16x8*>(klo + off);
            }
#pragma unroll
            for (int mi = 0; mi < 4; mi++)
#pragma unroll
                for (int ni = 0; ni < 2; ni++) {
                    acc[mi][ni] = __builtin_amdgcn_mfma_f32_16x16x32_bf16(kh8[mi], qh8[ni][ks], acc[mi][ni], 0, 0, 0);
                    acc[mi][ni] = __builtin_amdgcn_mfma_f32_16x16x32_bf16(kh8[mi], ql8[ni][ks], acc[mi][ni], 0, 0, 0);
                    acc[mi][ni] = __builtin_amdgcn_mfma_f32_16x16x32_bf16(kl8[mi], qh8[ni][ks], acc[mi][ni], 0, 0, 0);
                }
        }
        if (cc == tile) {   // diagonal chunk: causal mask
#pragma unroll
            for (int ni = 0; ni < 2; ni++) {
                const int tq = t0 + ni * 16 + l15;
#pragma unroll
                for (int mi = 0; mi < 4; mi++)
#pragma unroll
                    for (int r = 0; r < 4; r++) {
                        int kcol = (cc << 6) + mi * 16 + l4 * 4 + r;
                        float s = acc[mi][ni][r];
                        bool ok = kcol <= tq;
                        float e = exp2f(s);
                        Zp[ni] += ok ? e : 0.f;
                        unsigned su = __float_as_uint(s);
                        unsigned key = su ^ ((unsigned)(((int)su) >> 31) | 0x80000000u);
                        unsigned pk = (key & 0xFFFFFC00u) | (unsigned)(1023 - kcol);
                        pk = ok ? pk : 0u;
                        TOP12INS(pl[ni], pk);
                    }
            }
        } else {            // interior chunk: all valid
#pragma unroll
            for (int ni = 0; ni < 2; ni++) {
#pragma unroll
                for (int mi = 0; mi < 4; mi++)
#pragma unroll
                    for (int r = 0; r < 4; r++) {
                        int kcol = (cc << 6) + mi * 16 + l4 * 4 + r;
                        float s = acc[mi][ni][r];
                        Zp[ni] += exp2f(s);
                        unsigned su = __float_as_uint(s);
                        unsigned key = su ^ ((unsigned)(((int)su) >> 31) | 0x80000000u);
                        unsigned pk = (key & 0xFFFFFC00u) | (unsigned)(1023 - kcol);
                        TOP12INS(pl[ni], pk);
                    }
            }
        }
    }

    // in-wave 4-lane merge per qrow
    __shared__ unsigned int lsh[4][64][2][12];
    __shared__ float zsh[4][64][2];
#pragma unroll
    for (int ni = 0; ni < 2; ni++) {
#pragma unroll
        for (int i = 0; i < 12; i++) lsh[wv][lane][ni][i] = pl[ni][i];
        zsh[wv][lane][ni] = Zp[ni];
    }
    __syncthreads();
    if (lane < 32) {
        const int ni = lane >> 4, c = lane & 15;
        unsigned int m0[12], m1[12], m2[12], m3[12];
#pragma unroll
        for (int i = 0; i < 12; i++) {
            m0[i] = lsh[wv][c][ni][i];
            m1[i] = lsh[wv][c + 16][ni][i];
            m2[i] = lsh[wv][c + 32][ni][i];
            m3[i] = lsh[wv][c + 48][ni][i];
        }
        float Z = zsh[wv][c][ni] + zsh[wv][c + 16][ni] + zsh[wv][c + 32][ni] + zsh[wv][c + 48][ni];
        unsigned int out[12];
#pragma unroll
        for (int rd = 0; rd < 12; rd++) {
            unsigned int ha = m0[0] > m1[0] ? m0[0] : m1[0];
            unsigned int hb2 = m2[0] > m3[0] ? m2[0] : m3[0];
            unsigned int hm = ha > hb2 ? ha : hb2;
            POPQ(m0); POPQ(m1); POPQ(m2); POPQ(m3);
            out[rd] = hm;
        }
        const size_t r = (((size_t)bh) << 10) + t0 + lane;
        pZ[r * 4 + part] = Z;
        unsigned int* pp = pP + r * 48 + part * 12;
        *reinterpret_cast<uint4*>(pp + 0) = make_uint4(out[0], out[1], out[2], out[3]);
        *reinterpret_cast<uint4*>(pp + 4) = make_uint4(out[4], out[5], out[6], out[7]);
        *reinterpret_cast<uint4*>(pp + 8) = make_uint4(out[8], out[9], out[10], out[11]);
    }
}

// ---------------------------------------------------------------- phase B: merge partials -> (idx, w) lists + psink
#define LDLIST(dst, o, valid)                                                     \
    {                                                                             \
        uint4 x0, x1, x2;                                                         \
        if (valid) { x0 = pp[o]; x1 = pp[o + 1]; x2 = pp[o + 2]; }                \
        else { x0 = make_uint4(0,0,0,0); x1 = x0; x2 = x0; }                      \
        dst[0]=x0.x; dst[1]=x0.y; dst[2]=x0.z; dst[3]=x0.w;                       \
        dst[4]=x1.x; dst[5]=x1.y; dst[6]=x1.z; dst[7]=x1.w;                       \
        dst[8]=x2.x; dst[9]=x2.y; dst[10]=x2.z; dst[11]=x2.w;                     \
    }

__global__ __launch_bounds__(256) void attn_merge(
    const unsigned int* __restrict__ pP, const float* __restrict__ pZ,
    const float* __restrict__ sink_s,
    unsigned int* __restrict__ idxb, float* __restrict__ wbuf,
    float* __restrict__ psbuf) {
    const int tid = threadIdx.x, wv = tid >> 6, lane = tid & 63;
    const int wid = blockIdx.x * 4 + wv;
    const int tile = wid & 15, bh = wid >> 4;
    const int h = bh % 48;
    const int t = (tile << 6) + lane;
    const size_t r = (((size_t)bh) << 10) + t;
    const int npart = (tile >> 2) + 1;

    unsigned int q0[12], q1[12], q2[12], q3[12];
    const uint4* pp = reinterpret_cast<const uint4*>(pP + r * 48);
    LDLIST(q0, 0, true);
    LDLIST(q1, 3, npart > 1);
    LDLIST(q2, 6, npart > 2);
    LDLIST(q3, 9, npart > 3);

    float Z = pZ[r * 4 + 0];
    if (npart > 1) Z += pZ[r * 4 + 1];
    if (npart > 2) Z += pZ[r * 4 + 2];
    if (npart > 3) Z += pZ[r * 4 + 3];
    const float es = exp2f(sink_s[h] * LOG2E);
    const float invZ = 1.f / (Z + es);

    unsigned int oi[12]; float ow[12];
#pragma unroll
    for (int rd = 0; rd < 12; rd++) {
        unsigned int ha = q0[0] > q1[0] ? q0[0] : q1[0];
        unsigned int hb2 = q2[0] > q3[0] ? q2[0] : q3[0];
        unsigned int hm = ha > hb2 ? ha : hb2;
        POPQ(q0); POPQ(q1); POPQ(q2); POPQ(q3);
        unsigned int key = hm & 0xFFFFFC00u;
        unsigned int uu = (key & 0x80000000u) ? (key ^ 0x80000000u) : ~key;
        float v = __uint_as_float(uu);
        oi[rd] = 1023u - (hm & 1023u);
        ow[rd] = (hm == 0u) ? 0.f : exp2f(v) * invZ;
    }
    unsigned int* ip = idxb + r * 12;
    *reinterpret_cast<uint4*>(ip + 0) = make_uint4(oi[0], oi[1], oi[2], oi[3]);
    *reinterpret_cast<uint4*>(ip + 4) = make_uint4(oi[4], oi[5], oi[6], oi[7]);
    *reinterpret_cast<uint4*>(ip + 8) = make_uint4(oi[8], oi[9], oi[10], oi[11]);
    float* wp = wbuf + r * 12;
    *reinterpret_cast<float4*>(wp + 0) = make_float4(ow[0], ow[1], ow[2], ow[3]);
    *reinterpret_cast<float4*>(wp + 4) = make_float4(ow[4], ow[5], ow[6], ow[7]);
    *reinterpret_cast<float4*>(wp + 8) = make_float4(ow[8], ow[9], ow[10], ow[11]);
    psbuf[r] = es * invZ;
}

// ---------------------------------------------------------------- fused marker-gather + fc + act/rmsnorm/gate + proj + sink -> ctx bf16
// one wave per 16 rows (same bh); lane: l15 = row, l4 = k-chunk.
__global__ __launch_bounds__(256, 2) void mlp_fused(
    const unsigned int* __restrict__ idxb, const float* __restrict__ wbuf,
    const float* __restrict__ kb, const float* __restrict__ ps,
    const unsigned short* __restrict__ fcw, const float* __restrict__ fcb,
    const unsigned short* __restrict__ pw, const float* __restrict__ pb,
    const float* __restrict__ vn, unsigned short* __restrict__ ctx) {
    const int tid = threadIdx.x, wv = tid >> 6, lane = tid & 63;
    const int l15 = lane & 15, l4 = lane >> 4;
    const int wid = blockIdx.x * 4 + wv;          // 0..6143
    const int r0 = wid << 4;                      // global row base
    const int bh = wid >> 6;
    const int h = bh % 48, b = bh / 48, hk = h % 12;
    const int tbase = r0 & 1023;
    __shared__ unsigned short hsd[4][16][272];

    // idx/w lists for row l15
    const int row = r0 + l15;
    unsigned int idx12[12]; float w12[12];
    {
        const uint4* ip = reinterpret_cast<const uint4*>(idxb + (size_t)row * 12);
        uint4 a = ip[0], bb = ip[1], c = ip[2];
        idx12[0]=a.x; idx12[1]=a.y; idx12[2]=a.z; idx12[3]=a.w;
        idx12[4]=bb.x; idx12[5]=bb.y; idx12[6]=bb.z; idx12[7]=bb.w;
        idx12[8]=c.x; idx12[9]=c.y; idx12[10]=c.z; idx12[11]=c.w;
        const float4* wp = reinterpret_cast<const float4*>(wbuf + (size_t)row * 12);
        float4 d = wp[0], e = wp[1], f = wp[2];
        w12[0]=d.x; w12[1]=d.y; w12[2]=d.z; w12[3]=d.w;
        w12[4]=e.x; w12[5]=e.y; w12[6]=e.z; w12[7]=e.w;
        w12[8]=f.x; w12[9]=f.y; w12[10]=f.z; w12[11]=f.w;
    }

    // gather marker: lane holds dims [l4*8..+7] and [32+l4*8..+7]
    const float* kvan = kb + (((size_t)b * 12288 + hk) << 6);
    float mk[16];
#pragma unroll
    for (int i = 0; i < 16; i++) mk[i] = 0.f;
#pragma unroll
    for (int rr = 0; rr < 12; rr++) {
        const float* kr = kvan + (size_t)idx12[rr] * 768 + l4 * 8;
        float4 a0 = *reinterpret_cast<const float4*>(kr);
        float4 a1 = *reinterpret_cast<const float4*>(kr + 4);
        float4 b0 = *reinterpret_cast<const float4*>(kr + 32);
        float4 b1 = *reinterpret_cast<const float4*>(kr + 36);
        float w = w12[rr];
        mk[0] = fmaf(w, a0.x, mk[0]);  mk[1] = fmaf(w, a0.y, mk[1]);
        mk[2] = fmaf(w, a0.z, mk[2]);  mk[3] = fmaf(w, a0.w, mk[3]);
        mk[4] = fmaf(w, a1.x, mk[4]);  mk[5] = fmaf(w, a1.y, mk[5]);
        mk[6] = fmaf(w, a1.z, mk[6]);  mk[7] = fmaf(w, a1.w, mk[7]);
        mk[8] = fmaf(w, b0.x, mk[8]);  mk[9] = fmaf(w, b0.y, mk[9]);
        mk[10] = fmaf(w, b0.z, mk[10]); mk[11] = fmaf(w, b0.w, mk[11]);
        mk[12] = fmaf(w, b1.x, mk[12]); mk[13] = fmaf(w, b1.y, mk[13]);
        mk[14] = fmaf(w, b1.z, mk[14]); mk[15] = fmaf(w, b1.w, mk[15]);
    }
    {
        const float* kr = kvan + (size_t)(tbase + l15) * 768 + l4 * 8;
        float4 a0 = *reinterpret_cast<const float4*>(kr);
        float4 a1 = *reinterpret_cast<const float4*>(kr + 4);
        float4 b0 = *reinterpret_cast<const float4*>(kr + 32);
        float4 b1 = *reinterpret_cast<const float4*>(kr + 36);
        mk[0] += a0.x; mk[1] += a0.y; mk[2] += a0.z; mk[3] += a0.w;
        mk[4] += a1.x; mk[5] += a1.y; mk[6] += a1.z; mk[7] += a1.w;
        mk[8] += b0.x; mk[9] += b0.y; mk[10] += b0.z; mk[11] += b0.w;
        mk[12] += b1.x; mk[13] += b1.y; mk[14] += b1.z; mk[15] += b1.w;
    }
    bf16x8 amk[2];
#pragma unroll
    for (int ks = 0; ks < 2; ks++)
#pragma unroll
        for (int e = 0; e < 8; e++)
            amk[ks][e] = (short)rne_bf16(mk[ks * 8 + e] * (1.f / 13.f));

    // fc: 16 rows x 256 cols, K=64
    f32x4 hacc[16] = {};
#pragma unroll
    for (int ks = 0; ks < 2; ks++)
#pragma unroll
        for (int j = 0; j < 16; j++) {
            bf16x8 bw = *reinterpret_cast<const bf16x8*>(fcw + (j * 16 + l15) * 64 + ks * 32 + l4 * 8);
            hacc[j] = __builtin_amdgcn_mfma_f32_16x16x32_bf16(amk[ks], bw, hacc[j], 0, 0, 0);
        }

    // bias + activation + rmsnorm(256) + gate  (row = l4*4+r, col = j*16+l15)
    float ss[4] = {0.f, 0.f, 0.f, 0.f};
#pragma unroll
    for (int j = 0; j < 16; j++) {
        float bv = fcb[j * 16 + l15];
#pragma unroll
        for (int r = 0; r < 4; r++) {
            float x = hacc[j][r] + bv;
            float y = x * x + 0.75f * x * x * x;
            hacc[j][r] = y;
            ss[r] = fmaf(y, y, ss[r]);
        }
    }
#pragma unroll
    for (int m = 1; m < 16; m <<= 1)
#pragma unroll
        for (int r = 0; r < 4; r++) ss[r] += __shfl_xor(ss[r], m, 64);
    float rinv[4];
#pragma unroll
    for (int r = 0; r < 4; r++)
        rinv[r] = 1.f / sqrtf(ss[r] * (1.f / 256.f) + 1.1920928955078125e-07f);
#pragma unroll
    for (int j = 0; j < 16; j++)
#pragma unroll
        for (int r = 0; r < 4; r++) {
            float z = hacc[j][r] * rinv[r];
            float g = z / (1.f + __expf(-1.8137993642342178f * z));
            hsd[wv][l4 * 4 + r][j * 16 + l15] = rne_bf16(g);
        }
    __syncthreads();

    // proj: 16 rows x 64 cols, K=256
    f32x4 oacc[4] = {};
#pragma unroll
    for (int ks = 0; ks < 8; ks++) {
        bf16x8 ah = *reinterpret_cast<const bf16x8*>(&hsd[wv][l15][ks * 32 + l4 * 8]);
#pragma unroll
        for (int j = 0; j < 4; j++) {
            bf16x8 bw = *reinterpret_cast<const bf16x8*>(pw + (j * 16 + l15) * 256 + ks * 32 + l4 * 8);
            oacc[j] = __builtin_amdgcn_mfma_f32_16x16x32_bf16(ah, bw, oacc[j], 0, 0, 0);
        }
    }
#pragma unroll
    for (int j = 0; j < 4; j++) {
        int d = j * 16 + l15;
        float pbv = pb[d];
        float vnv = vn[h * 64 + d];
#pragma unroll
        for (int r = 0; r < 4; r++) {
            int rloc = l4 * 4 + r;
            int t = tbase + rloc;
            float p = ps[r0 + rloc];
            float o = oacc[j][r] + pbv + p * vnv;
            ctx[((((size_t)(b << 10) + t) * 48 + h) << 6) + d] = rne_bf16(o);
        }
    }
}

// ---------------------------------------------------------------- launch
extern "C" void kernel_launch(void* const* d_in, const int* in_sizes, int n_in,
                              void* d_out, int out_size, void* d_ws, size_t ws_size,
                              hipStream_t stream) {
    (void)in_sizes; (void)n_in; (void)out_size; (void)ws_size;
    const float* A       = (const float*)d_in[0];
    const float* X       = (const float*)d_in[1];
    const float* Wq_w    = (const float*)d_in[2];
    const float* Wq_b    = (const float*)d_in[3];
    const float* Wk_w    = (const float*)d_in[4];
    const float* Wk_b    = (const float*)d_in[5];
    const float* wedge_A = (const float*)d_in[6];
    const float* wedge_b = (const float*)d_in[7];
    const float* sink    = (const float*)d_in[8];
    const float* v_nulls = (const float*)d_in[9];
    const float* fc_w    = (const float*)d_in[10];
    const float* fc_b    = (const float*)d_in[11];
    const float* proj_w  = (const float*)d_in[12];
    const float* proj_b  = (const float*)d_in[13];
    const float* WO      = (const float*)d_in[14];
    const float* WO_b    = (const float*)d_in[15];
    float* out = (float*)d_out;
    float* ws  = (float*)d_ws;

    // ---- workspace layout (float offsets) ----
    float*          qbuf   = ws;                                  // [0, 6291456) f32; later ctx_bf
    unsigned short* ctx_bf = (unsigned short*)ws;                 //   2048x3072 bf16 (3145728 f)
    float*          kbbuf  = ws + 6291456;                        // [6291456, 7864320)
    unsigned short* q_hi   = (unsigned short*)(ws + 7864320);     // [7864320, 11010048)
    unsigned int*   idxb   = (unsigned int*)(ws + 7864320);       //   overlays q_hi after scores
    float*          wbuf   = ws + 9043968;                        //   overlays q_hi after scores
    unsigned short* q_lo   = (unsigned short*)(ws + 11010048);    // [11010048, 14155776)
    unsigned short* kf_hi  = (unsigned short*)(ws + 14155776);    // [14155776, 17301504)
    unsigned short* kf_lo  = (unsigned short*)(ws + 17301504);    // [17301504, 20447232)
    // region [20447232, 25559040): early = cvt scratch + S/rc/rs; late = pZ + pP
    unsigned short* A_bf   = (unsigned short*)(ws + 20447232);
    unsigned short* X_bf   = (unsigned short*)(ws + 21233664);
    unsigned short* Wq_bf  = (unsigned short*)(ws + 22020096);
    unsigned short* Wk_bf  = (unsigned short*)(ws + 23199744);
    float*          Sbuf   = ws + 23494656;
    float*          rcbuf  = ws + 23691264;
    float*          rsbuf  = ws + 23724032;
    float*          pZ     = ws + 20447232;
    unsigned int*   pP     = (unsigned int*)(ws + 20840448);
    // tail
    float*          wob    = ws + 25559040;
    float*          psbuf  = ws + 25560064;
    unsigned short* fcw_bf = (unsigned short*)(ws + 25658368);
    unsigned short* pw_bf  = (unsigned short*)(ws + 25666560);
    unsigned short* WOt_bf = (unsigned short*)(ws + 25674752);
    // end: 26,854,400 floats = 107.4 MB

    prep_kernel<<<(48 * 64 * 64 + 1024 * 32 + 768 + 255) / 256, 256, 0, stream>>>(
        wedge_A, wedge_b, WO_b, Sbuf, rcbuf, rsbuf, wob);
    cvt_all<<<5984, 256, 0, stream>>>(A, X, Wq_w, Wk_w, fc_w, proj_w,
                                      A_bf, X_bf, Wq_bf, Wk_bf, fcw_bf, pw_bf);
    wo_transpose<<<dim3(24, 24, 4), 256, 0, stream>>>(WO, WOt_bf);

    gemm_bf16k<<<dim3(24, 16), 256, 0, stream>>>(A_bf, Wq_bf, Wq_b, qbuf, 2048, 3072, 768, 1.f);
    gemm_bf16_64<<<dim3(12, 32), 256, 0, stream>>>(X_bf, Wk_bf, Wk_b, kbbuf, 2048, 768, 768, 1.f);
    q_transform2<<<1536, 256, 0, stream>>>(qbuf, Sbuf, rcbuf, rsbuf, q_hi, q_lo);
    k_transform2<<<1536, 256, 0, stream>>>(kbbuf, Sbuf, rcbuf, rsbuf, kf_hi, kf_lo);
    attn_scores<<<1920, 256, 0, stream>>>(q_hi, q_lo, kf_hi, kf_lo, pZ, pP);
    attn_merge<<<384, 256, 0, stream>>>(pP, pZ, sink, idxb, wbuf, psbuf);
    mlp_fused<<<1536, 256, 0, stream>>>(idxb, wbuf, kbbuf, psbuf,
                                        fcw_bf, fc_b, pw_bf, proj_b, v_nulls, ctx_bf);
    gemm_bf16_64<<<dim3(12, 32), 256, 0, stream>>>(ctx_bf, WOt_bf, wob, out, 2048, 768, 3072, 0.25f);
}

// Round 8
// 400.862 us; speedup vs baseline: 9.7376x; 1.0117x over previous
//
#include <hip/hip_runtime.h>
#include <math.h>

#define B_   2
#define T_   1024
#define C_   768
#define DH_  64
#define NH_  12
#define HT_  48

typedef short bf16x8 __attribute__((ext_vector_type(8)));
typedef float f32x4 __attribute__((ext_vector_type(4)));

__device__ __forceinline__ float wave_sum(float v) {
#pragma unroll
    for (int off = 32; off; off >>= 1) v += __shfl_xor(v, off, 64);
    return v;
}
__device__ __forceinline__ unsigned short rne_bf16(float f) {
    unsigned u = __float_as_uint(f);
    return (unsigned short)((u + 0x7FFFu + ((u >> 16) & 1u)) >> 16);
}
__device__ __forceinline__ float bf2f(unsigned short u) {
    return __uint_as_float((unsigned)u << 16);
}

#define LOG2E 1.4426950408889634f
#define KBIAS 32.0f

// work tables: 40 (tile,part) units per (b,h), heavy-first. chunk = 64 cols, part = 4 chunks.
__constant__ int c_tileTab[40] = {15,15,15,15, 14,14,14, 13,13,13, 12,12,12, 11,11,11,
                                  10,10, 9,9, 8,8, 7,7, 6, 5, 4, 3,
                                  14,10,6,2, 13,9,5,1, 12,8,4,0};
__constant__ int c_partTab[40] = { 0, 1, 2, 3,  0, 1, 2,  0, 1, 2,  0, 1, 2,  0, 1, 2,
                                   0, 1, 0,1, 0,1, 0,1, 0, 0, 0, 0,
                                   3, 2,1,0,  3,2,1,0,  3,2,1,0};

// ---------------------------------------------------------------- fused prep: wo_transpose + cvt + S/rope/wob
__global__ __launch_bounds__(256) void prep_all(
    const float* __restrict__ wA, const float* __restrict__ wb, const float* __restrict__ WOb,
    const float* __restrict__ A, const float* __restrict__ X,
    const float* __restrict__ Wq, const float* __restrict__ Wk,
    const float* __restrict__ fcw, const float* __restrict__ pw, const float* __restrict__ WO,
    float* __restrict__ S, float* __restrict__ rc, float* __restrict__ rs, float* __restrict__ wob,
    unsigned short* __restrict__ Ab, unsigned short* __restrict__ Xb,
    unsigned short* __restrict__ Wqb, unsigned short* __restrict__ Wkb,
    unsigned short* __restrict__ fcb, unsigned short* __restrict__ pwb,
    unsigned short* __restrict__ WOt) {
    __shared__ float tl[32][33];
    const int bid = blockIdx.x;
    if (bid < 2304) {               // WO transpose (4,768,768) -> WOt[d][n*768+c] bf16
        const int n = bid / 576, rem = bid % 576;
        const int d0 = (rem / 24) * 32, c0 = (rem % 24) * 32;
        const int tx = threadIdx.x & 31, ty = threadIdx.x >> 5;
#pragma unroll
        for (int p = 0; p < 4; p++)
            tl[ty + p * 8][tx] = WO[(size_t)n * 589824 + (size_t)(c0 + ty + p * 8) * 768 + d0 + tx];
        __syncthreads();
#pragma unroll
        for (int p = 0; p < 4; p++)
            WOt[(size_t)(d0 + ty + p * 8) * 3072 + n * 768 + c0 + tx] = rne_bf16(tl[tx][ty + p * 8]);
    } else if (bid < 8288) {        // f32 -> bf16 conversions, float4 granularity
        int i = (bid - 2304) * 256 + threadIdx.x;
        const float* s; unsigned short* d; int o;
        if (i < 393216)       { s = A;   d = Ab;  o = i; }
        else if (i < 786432)  { s = X;   d = Xb;  o = i - 393216; }
        else if (i < 1376256) { s = Wq;  d = Wqb; o = i - 786432; }
        else if (i < 1523712) { s = Wk;  d = Wkb; o = i - 1376256; }
        else if (i < 1527808) { s = fcw; d = fcb; o = i - 1523712; }
        else if (i < 1531904) { s = pw;  d = pwb; o = i - 1527808; }
        else return;
        float4 v = reinterpret_cast<const float4*>(s)[o];
        ushort4 u;
        u.x = rne_bf16(v.x); u.y = rne_bf16(v.y); u.z = rne_bf16(v.z); u.w = rne_bf16(v.w);
        reinterpret_cast<ushort4*>(d)[o] = u;
    } else {                        // S, rope tables, wob
        int i = (bid - 8288) * 256 + threadIdx.x;
        if (i < HT_ * 64 * 64) {
            int e = i & 63, d = (i >> 6) & 63, h = i >> 12;
            float v = wA[d * 64 + e] - wA[e * 64 + d];
            if (d == e) v += wb[h * 64 + d];
            S[i] = v;
        } else if (i < HT_ * 64 * 64 + T_ * 32) {
            int j = i - HT_ * 64 * 64;
            int t = j >> 5, f = j & 31;
            float invf = (float)(1.0 / pow(10000.0, (double)f / 32.0));
            float fr = (float)t * invf;
            rc[j] = cosf(fr);
            rs[j] = sinf(fr);
        } else if (i < HT_ * 64 * 64 + T_ * 32 + C_) {
            int d = i - (HT_ * 64 * 64 + T_ * 32);
            wob[d] = WOb[d] + WOb[C_ + d] + WOb[2 * C_ + d] + WOb[3 * C_ + d];
        }
    }
}

// ---------------------------------------------------------------- q-proj + k-proj in one grid (128x128 MFMA, K=768)
__global__ __launch_bounds__(256) void gemm_qk(
    const unsigned short* __restrict__ Aq, const unsigned short* __restrict__ Wqw,
    const float* __restrict__ bq, float* __restrict__ Cq,
    const unsigned short* __restrict__ Ak, const unsigned short* __restrict__ Wkw,
    const float* __restrict__ bk, float* __restrict__ Ck) {
    __shared__ unsigned short Asd[128][40];
    __shared__ unsigned short Bsd[128][40];
    int bx = blockIdx.x;
    const unsigned short *A, *W; const float* bias; float* C; int N;
    if (bx < 24) { A = Aq; W = Wqw; bias = bq; C = Cq; N = 3072; }
    else { bx -= 24; A = Ak; W = Wkw; bias = bk; C = Ck; N = 768; }
    const int K = 768;
    const int tid = threadIdx.x;
    const int wv = tid >> 6, lane = tid & 63;
    const int m0 = blockIdx.y * 128, n0 = bx * 128;
    const int wr = (wv >> 1) * 64, wc = (wv & 1) * 64;
    const int l15 = lane & 15, l4 = lane >> 4;
    const int srow = tid >> 2, soff = (tid & 3) * 8;
    f32x4 acc[4][4] = {};
    for (int k0 = 0; k0 < K; k0 += 32) {
        uint4 a0 = *reinterpret_cast<const uint4*>(A + (size_t)(m0 + srow) * K + k0 + soff);
        uint4 a1 = *reinterpret_cast<const uint4*>(A + (size_t)(m0 + srow + 64) * K + k0 + soff);
        uint4 b0 = *reinterpret_cast<const uint4*>(W + (size_t)(n0 + srow) * K + k0 + soff);
        uint4 b1 = *reinterpret_cast<const uint4*>(W + (size_t)(n0 + srow + 64) * K + k0 + soff);
        *reinterpret_cast<uint4*>(&Asd[srow][soff])      = a0;
        *reinterpret_cast<uint4*>(&Asd[srow + 64][soff]) = a1;
        *reinterpret_cast<uint4*>(&Bsd[srow][soff])      = b0;
        *reinterpret_cast<uint4*>(&Bsd[srow + 64][soff]) = b1;
        __syncthreads();
        bf16x8 af[4], bfr[4];
#pragma unroll
        for (int i = 0; i < 4; i++)
            af[i] = *reinterpret_cast<const bf16x8*>(&Asd[wr + i * 16 + l15][l4 * 8]);
#pragma unroll
        for (int j = 0; j < 4; j++)
            bfr[j] = *reinterpret_cast<const bf16x8*>(&Bsd[wc + j * 16 + l15][l4 * 8]);
#pragma unroll
        for (int i = 0; i < 4; i++)
#pragma unroll
            for (int j = 0; j < 4; j++)
                acc[i][j] = __builtin_amdgcn_mfma_f32_16x16x32_bf16(af[i], bfr[j], acc[i][j], 0, 0, 0);
        __syncthreads();
    }
#pragma unroll
    for (int i = 0; i < 4; i++)
#pragma unroll
        for (int j = 0; j < 4; j++) {
            int col = n0 + wc + j * 16 + l15;
            float bv = bias[col];
#pragma unroll
            for (int r = 0; r < 4; r++) {
                int row = m0 + wr + i * 16 + l4 * 4 + r;
                C[(size_t)row * N + col] = acc[i][j][r] + bv;
            }
        }
}

// ---------------------------------------------------------------- bf16 MFMA GEMM 64x64 tile (for WO, K=3072)
__global__ __launch_bounds__(256) void gemm_bf16_64(const unsigned short* __restrict__ A,
                                                    const unsigned short* __restrict__ W,
                                                    const float* __restrict__ bias,
                                                    float* __restrict__ C,
                                                    int M, int N, int K, float scl) {
    __shared__ unsigned short Asd[64][40];
    __shared__ unsigned short Bsd[64][40];
    const int tid = threadIdx.x;
    const int wv = tid >> 6, lane = tid & 63;
    const int m0 = blockIdx.y * 64, n0 = blockIdx.x * 64;
    const int l15 = lane & 15, l4 = lane >> 4;
    const int srow = tid >> 2, soff = (tid & 3) * 8;
    f32x4 acc[4] = {};
    for (int k0 = 0; k0 < K; k0 += 32) {
        uint4 a0 = *reinterpret_cast<const uint4*>(A + (size_t)(m0 + srow) * K + k0 + soff);
        uint4 b0 = *reinterpret_cast<const uint4*>(W + (size_t)(n0 + srow) * K + k0 + soff);
        *reinterpret_cast<uint4*>(&Asd[srow][soff]) = a0;
        *reinterpret_cast<uint4*>(&Bsd[srow][soff]) = b0;
        __syncthreads();
        bf16x8 af = *reinterpret_cast<const bf16x8*>(&Asd[wv * 16 + l15][l4 * 8]);
#pragma unroll
        for (int j = 0; j < 4; j++) {
            bf16x8 bfr = *reinterpret_cast<const bf16x8*>(&Bsd[j * 16 + l15][l4 * 8]);
            acc[j] = __builtin_amdgcn_mfma_f32_16x16x32_bf16(af, bfr, acc[j], 0, 0, 0);
        }
        __syncthreads();
    }
#pragma unroll
    for (int j = 0; j < 4; j++) {
        int col = n0 + j * 16 + l15;
        float bv = bias[col];
#pragma unroll
        for (int r = 0; r < 4; r++) {
            int row = m0 + wv * 16 + l4 * 4 + r;
            C[(size_t)row * N + col] = (acc[j][r] + bv) * scl;
        }
    }
}

// ---------------------------------------------------------------- q + k transforms in one grid
__global__ __launch_bounds__(256) void transform_qk(
    const float* __restrict__ qb, const float* __restrict__ kbv, const float* __restrict__ S,
    const float* __restrict__ rc, const float* __restrict__ rs,
    unsigned short* __restrict__ qhi, unsigned short* __restrict__ qlo,
    unsigned short* __restrict__ khi, unsigned short* __restrict__ klo) {
    const int tid = threadIdx.x, wv = tid >> 6, lane = tid & 63;
    const bool isQ = blockIdx.x < 1536;
    const int bidx = isQ ? blockIdx.x : blockIdx.x - 1536;
    const int h = bidx >> 5, blk = bidx & 31;
    const int hk = h % 12;
    __shared__ float Sl[4096];
    __shared__ float sh[4][64];
    const float4* Sg = reinterpret_cast<const float4*>(S + h * 4096);
#pragma unroll
    for (int i = 0; i < 4; i++)
        reinterpret_cast<float4*>(Sl)[tid + 256 * i] = Sg[tid + 256 * i];
    __syncthreads();
    unsigned short* ohi = isQ ? qhi : khi;
    unsigned short* olo = isQ ? qlo : klo;
    for (int it = 0; it < 16; ++it) {
        int r = (blk << 6) + (wv << 4) + it;   // 0..2047
        int b = r >> 10, t = r & 1023;
        float v;
        if (isQ) {
            v = qb[((((size_t)(b << 10) + t) * 48 + h) << 6) + lane];
            float ss = wave_sum(v * v);
            v *= 1.f / sqrtf(ss * (1.f / 64.f) + 1.1920928955078125e-07f);
        } else {
            v = kbv[((((size_t)(b << 10) + t) * 12 + hk) << 6) + lane];
        }
        sh[wv][lane] = v;
        float acc = v;
#pragma unroll 8
        for (int d = 0; d < 64; d++) acc = fmaf(sh[wv][d], Sl[(d << 6) + lane], acc);
        sh[wv][lane] = acc;
        int j = lane & 31;
        float x1 = sh[wv][2 * j], x2 = sh[wv][2 * j + 1];
        float ct = rc[t * 32 + j], st = rs[t * 32 + j];
        float o = (lane < 32) ? (x1 * ct - x2 * st) : (x1 * st + x2 * ct);
        if (isQ) o *= 0.125f * LOG2E;          // exp2 domain
        unsigned short oh = rne_bf16(o);
        unsigned short ol = rne_bf16(o - bf2f(oh));
        size_t oidx = ((((size_t)(b * 48 + h)) << 10) + t) * 64 + lane;
        ohi[oidx] = oh;
        olo[oidx] = ol;
    }
}

#define POPQ(qq)                                                                  \
    {                                                                             \
        bool tk = (qq[0] == hm);                                                  \
        qq[0]=tk?qq[1]:qq[0]; qq[1]=tk?qq[2]:qq[1]; qq[2]=tk?qq[3]:qq[2];         \
        qq[3]=tk?qq[4]:qq[3]; qq[4]=tk?qq[5]:qq[4]; qq[5]=tk?qq[6]:qq[5];         \
        qq[6]=tk?qq[7]:qq[6]; qq[7]=tk?qq[8]:qq[7]; qq[8]=tk?qq[9]:qq[8];         \
        qq[9]=tk?qq[10]:qq[9]; qq[10]=tk?qq[11]:qq[10]; qq[11]=tk?0u:qq[11];      \
    }

#define TOP12INS(pln, pk)                                                         \
    {                                                                             \
        unsigned _p = (pk);                                                       \
        _Pragma("unroll")                                                         \
        for (int jj = 0; jj < 12; jj++) {                                         \
            unsigned mx = pln[jj] > _p ? pln[jj] : _p;                            \
            _p = pln[jj] > _p ? _p : pln[jj];                                     \
            pln[jj] = mx;                                                         \
        }                                                                         \
    }

// ---------------------------------------------------------------- phase A: MFMA scores, exp2 domain, +KBIAS in acc
// 2 units per 128-thread block, one per wave, no cross-wave sync.
// Positive biased scores => float bits are monotone keys directly.
__global__ __launch_bounds__(128, 5) void attn_scores(
    const unsigned short* __restrict__ qhi, const unsigned short* __restrict__ qlo,
    const unsigned short* __restrict__ khi, const unsigned short* __restrict__ klo,
    float* __restrict__ pZ, unsigned int* __restrict__ pP) {
    const int tid = threadIdx.x, wv = tid >> 6, lane = tid & 63;
    const int unit = blockIdx.x * 2 + wv;
    const int u = unit / 96, bh = unit % 96;
    const int tile = c_tileTab[u >> 1], part = c_partTab[u >> 1], half = u & 1;
    const int l15 = lane & 15, l4 = lane >> 4;
    const int t0 = (tile << 6) + (half << 5);
    const int c0 = part << 2;
    const int c1 = min(c0 + 4, tile + 1);
    const size_t base = ((size_t)bh) << 16;

    bf16x8 qh8[2][2], ql8[2][2];
#pragma unroll
    for (int ni = 0; ni < 2; ni++)
#pragma unroll
        for (int ks = 0; ks < 2; ks++) {
            size_t off = base + (size_t)(t0 + ni * 16 + l15) * 64 + ks * 32 + l4 * 8;
            qh8[ni][ks] = *reinterpret_cast<const bf16x8*>(qhi + off);
            ql8[ni][ks] = *reinterpret_cast<const bf16x8*>(qlo + off);
        }

    unsigned int pl[2][12];
#pragma unroll
    for (int ni = 0; ni < 2; ni++)
#pragma unroll
        for (int i = 0; i < 12; i++) pl[ni][i] = 0u;
    float Zp[2] = {0.f, 0.f};

    for (int cc = c0; cc < c1; ++cc) {
        f32x4 acc[4][2];
#pragma unroll
        for (int mi = 0; mi < 4; mi++)
#pragma unroll
            for (int ni = 0; ni < 2; ni++)
                acc[mi][ni] = (f32x4){KBIAS, KBIAS, KBIAS, KBIAS};
#pragma unroll
        for (int ks = 0; ks < 2; ks++) {
            bf16x8 kh8[4], kl8[4];
#pragma unroll
            for (int mi = 0; mi < 4; mi++) {
                size_t off = base + (size_t)((cc << 6) + mi * 16 + l15) * 64 + ks * 32 + l4 * 8;
                kh8[mi] = *reinterpret_cast<const bf16x8*>(khi + off);
                kl8[mi] = *reinterpret_cast<const bf16x8*>(klo + off);
            }
#pragma unroll
            for (int mi = 0; mi < 4; mi++)
#pragma unroll
                for (int ni = 0; ni < 2; ni++) {
                    acc[mi][ni] = __builtin_amdgcn_mfma_f32_16x16x32_bf16(kh8[mi], qh8[ni][ks], acc[mi][ni], 0, 0, 0);
                    acc[mi][ni] = __builtin_amdgcn_mfma_f32_16x16x32_bf16(kh8[mi], ql8[ni][ks], acc[mi][ni], 0, 0, 0);
                    acc[mi][ni] = __builtin_amdgcn_mfma_f32_16x16x32_bf16(kl8[mi], qh8[ni][ks], acc[mi][ni], 0, 0, 0);
                }
        }
        if (cc == tile) {   // diagonal chunk: causal mask
#pragma unroll
            for (int ni = 0; ni < 2; ni++) {
                const int tq = t0 + ni * 16 + l15;
#pragma unroll
                for (int mi = 0; mi < 4; mi++)
#pragma unroll
                    for (int r = 0; r < 4; r++) {
                        int kcol = (cc << 6) + mi * 16 + l4 * 4 + r;
                        float s = acc[mi][ni][r];
                        bool ok = kcol <= tq;
                        float e = exp2f(s);
                        Zp[ni] += ok ? e : 0.f;
                        unsigned pk = (__float_as_uint(s) & 0xFFFFFC00u) | (unsigned)(1023 - kcol);
                        pk = ok ? pk : 0u;
                        TOP12INS(pl[ni], pk);
                    }
            }
        } else {            // interior chunk: all valid
#pragma unroll
            for (int ni = 0; ni < 2; ni++) {
#pragma unroll
                for (int mi = 0; mi < 4; mi++)
#pragma unroll
                    for (int r = 0; r < 4; r++) {
                        int kcol = (cc << 6) + mi * 16 + l4 * 4 + r;
                        float s = acc[mi][ni][r];
                        Zp[ni] += exp2f(s);
                        unsigned pk = (__float_as_uint(s) & 0xFFFFFC00u) | (unsigned)(1023 - kcol);
                        TOP12INS(pl[ni], pk);
                    }
            }
        }
    }

    // per-wave 4-lane merge per qrow (LDS region private to this wave; no barrier)
    __shared__ unsigned int lsh[2][64][2][12];
    __shared__ float zsh[2][64][2];
#pragma unroll
    for (int ni = 0; ni < 2; ni++) {
#pragma unroll
        for (int i = 0; i < 12; i++) lsh[wv][lane][ni][i] = pl[ni][i];
        zsh[wv][lane][ni] = Zp[ni];
    }
    __threadfence_block();   // order this wave's LDS writes before its reads
    if (lane < 32) {
        const int ni = lane >> 4, c = lane & 15;
        unsigned int m0[12], m1[12], m2[12], m3[12];
#pragma unroll
        for (int i = 0; i < 12; i++) {
            m0[i] = lsh[wv][c][ni][i];
            m1[i] = lsh[wv][c + 16][ni][i];
            m2[i] = lsh[wv][c + 32][ni][i];
            m3[i] = lsh[wv][c + 48][ni][i];
        }
        float Z = zsh[wv][c][ni] + zsh[wv][c + 16][ni] + zsh[wv][c + 32][ni] + zsh[wv][c + 48][ni];
        unsigned int out[12];
#pragma unroll
        for (int rd = 0; rd < 12; rd++) {
            unsigned int ha = m0[0] > m1[0] ? m0[0] : m1[0];
            unsigned int hb2 = m2[0] > m3[0] ? m2[0] : m3[0];
            unsigned int hm = ha > hb2 ? ha : hb2;
            POPQ(m0); POPQ(m1); POPQ(m2); POPQ(m3);
            out[rd] = hm;
        }
        const size_t r = (((size_t)bh) << 10) + t0 + lane;
        pZ[r * 4 + part] = Z;
        unsigned int* pp = pP + r * 48 + part * 12;
        *reinterpret_cast<uint4*>(pp + 0) = make_uint4(out[0], out[1], out[2], out[3]);
        *reinterpret_cast<uint4*>(pp + 4) = make_uint4(out[4], out[5], out[6], out[7]);
        *reinterpret_cast<uint4*>(pp + 8) = make_uint4(out[8], out[9], out[10], out[11]);
    }
}

// ---------------------------------------------------------------- fused merge + marker-gather + fc + act + proj + sink
// one wave per 16 rows; lane: l15 = row, l4 = part-queue (merge) / k-chunk (gather).
__global__ __launch_bounds__(256, 2) void mlp_fused(
    const unsigned int* __restrict__ pP, const float* __restrict__ pZ,
    const float* __restrict__ sink_s, const float* __restrict__ kb,
    const unsigned short* __restrict__ fcw, const float* __restrict__ fcb,
    const unsigned short* __restrict__ pw, const float* __restrict__ pb,
    const float* __restrict__ vn, unsigned short* __restrict__ ctx) {
    const int tid = threadIdx.x, wv = tid >> 6, lane = tid & 63;
    const int l15 = lane & 15, l4 = lane >> 4;
    const int wid = blockIdx.x * 4 + wv;          // 0..6143
    const int r0 = wid << 4;
    const int bh = wid >> 6;
    const int h = bh % 48, b = bh / 48, hk = h % 12;
    const int tbase = r0 & 1023;
    const int tile = tbase >> 6;
    const int npart = (tile >> 2) + 1;            // wave-uniform
    __shared__ unsigned short hsd[4][16][272];

    // ---- inline part-merge: lane l4 owns queue (part) l4 of row l15 ----
    const int row = r0 + l15;
    unsigned int qq[12];
    {
        const bool val = l4 < npart;
        uint4 x0 = make_uint4(0,0,0,0), x1 = x0, x2 = x0;
        if (val) {
            const uint4* ip = reinterpret_cast<const uint4*>(pP + (size_t)row * 48 + l4 * 12);
            x0 = ip[0]; x1 = ip[1]; x2 = ip[2];
        }
        qq[0]=x0.x; qq[1]=x0.y; qq[2]=x0.z; qq[3]=x0.w;
        qq[4]=x1.x; qq[5]=x1.y; qq[6]=x1.z; qq[7]=x1.w;
        qq[8]=x2.x; qq[9]=x2.y; qq[10]=x2.z; qq[11]=x2.w;
    }
    float Zl = (l4 < npart) ? pZ[(size_t)row * 4 + l4] : 0.f;
    float Z = Zl;
    Z += __shfl_xor(Z, 16, 64);
    Z += __shfl_xor(Z, 32, 64);
    const float es = exp2f(sink_s[h] * LOG2E + KBIAS);
    const float invZ = 1.f / (Z + es);
    const float psink = es * invZ;                // for row l15

    unsigned int idx12[12]; float w12[12];
#pragma unroll
    for (int rd = 0; rd < 12; rd++) {
        unsigned int m = qq[0];
        unsigned int o1 = __shfl_xor(m, 16, 64); m = m > o1 ? m : o1;
        unsigned int o2 = __shfl_xor(m, 32, 64); m = m > o2 ? m : o2;
        const unsigned int hm = m;                // uniform in 4-lane group
        POPQ(qq);
        idx12[rd] = 1023u - (hm & 1023u);
        w12[rd] = (hm == 0u) ? 0.f : exp2f(__uint_as_float(hm & 0xFFFFFC00u)) * invZ;
    }

    // ---- gather marker: lane holds dims [l4*8..+7] and [32+l4*8..+7] of row l15 ----
    const float* kvan = kb + (((size_t)b * 12288 + hk) << 6);
    float mk[16];
#pragma unroll
    for (int i = 0; i < 16; i++) mk[i] = 0.f;
#pragma unroll
    for (int rr = 0; rr < 12; rr++) {
        const float* kr = kvan + (size_t)idx12[rr] * 768 + l4 * 8;
        float4 a0 = *reinterpret_cast<const float4*>(kr);
        float4 a1 = *reinterpret_cast<const float4*>(kr + 4);
        float4 b0 = *reinterpret_cast<const float4*>(kr + 32);
        float4 b1 = *reinterpret_cast<const float4*>(kr + 36);
        float w = w12[rr];
        mk[0] = fmaf(w, a0.x, mk[0]);  mk[1] = fmaf(w, a0.y, mk[1]);
        mk[2] = fmaf(w, a0.z, mk[2]);  mk[3] = fmaf(w, a0.w, mk[3]);
        mk[4] = fmaf(w, a1.x, mk[4]);  mk[5] = fmaf(w, a1.y, mk[5]);
        mk[6] = fmaf(w, a1.z, mk[6]);  mk[7] = fmaf(w, a1.w, mk[7]);
        mk[8] = fmaf(w, b0.x, mk[8]);  mk[9] = fmaf(w, b0.y, mk[9]);
        mk[10] = fmaf(w, b0.z, mk[10]); mk[11] = fmaf(w, b0.w, mk[11]);
        mk[12] = fmaf(w, b1.x, mk[12]); mk[13] = fmaf(w, b1.y, mk[13]);
        mk[14] = fmaf(w, b1.z, mk[14]); mk[15] = fmaf(w, b1.w, mk[15]);
    }
    {
        const float* kr = kvan + (size_t)(tbase + l15) * 768 + l4 * 8;
        float4 a0 = *reinterpret_cast<const float4*>(kr);
        float4 a1 = *reinterpret_cast<const float4*>(kr + 4);
        float4 b0 = *reinterpret_cast<const float4*>(kr + 32);
        float4 b1 = *reinterpret_cast<const float4*>(kr + 36);
        mk[0] += a0.x; mk[1] += a0.y; mk[2] += a0.z; mk[3] += a0.w;
        mk[4] += a1.x; mk[5] += a1.y; mk[6] += a1.z; mk[7] += a1.w;
        mk[8] += b0.x; mk[9] += b0.y; mk[10] += b0.z; mk[11] += b0.w;
        mk[12] += b1.x; mk[13] += b1.y; mk[14] += b1.z; mk[15] += b1.w;
    }
    bf16x8 amk[2];
#pragma unroll
    for (int ks = 0; ks < 2; ks++)
#pragma unroll
        for (int e = 0; e < 8; e++)
            amk[ks][e] = (short)rne_bf16(mk[ks * 8 + e] * (1.f / 13.f));

    // ---- fc: 16 rows x 256 cols, K=64 ----
    f32x4 hacc[16] = {};
#pragma unroll
    for (int ks = 0; ks < 2; ks++)
#pragma unroll
        for (int j = 0; j < 16; j++) {
            bf16x8 bw = *reinterpret_cast<const bf16x8*>(fcw + (j * 16 + l15) * 64 + ks * 32 + l4 * 8);
            hacc[j] = __builtin_amdgcn_mfma_f32_16x16x32_bf16(amk[ks], bw, hacc[j], 0, 0, 0);
        }

    // bias + activation + rmsnorm(256) + gate  (row = l4*4+r, col = j*16+l15)
    float ss[4] = {0.f, 0.f, 0.f, 0.f};
#pragma unroll
    for (int j = 0; j < 16; j++) {
        float bv = fcb[j * 16 + l15];
#pragma unroll
        for (int r = 0; r < 4; r++) {
            float x = hacc[j][r] + bv;
            float y = x * x + 0.75f * x * x * x;
            hacc[j][r] = y;
            ss[r] = fmaf(y, y, ss[r]);
        }
    }
#pragma unroll
    for (int m = 1; m < 16; m <<= 1)
#pragma unroll
        for (int r = 0; r < 4; r++) ss[r] += __shfl_xor(ss[r], m, 64);
    float rinv[4];
#pragma unroll
    for (int r = 0; r < 4; r++)
        rinv[r] = 1.f / sqrtf(ss[r] * (1.f / 256.f) + 1.1920928955078125e-07f);
#pragma unroll
    for (int j = 0; j < 16; j++)
#pragma unroll
        for (int r = 0; r < 4; r++) {
            float z = hacc[j][r] * rinv[r];
            float g = z / (1.f + __expf(-1.8137993642342178f * z));
            hsd[wv][l4 * 4 + r][j * 16 + l15] = rne_bf16(g);
        }
    __syncthreads();

    // ---- proj: 16 rows x 64 cols, K=256 ----
    f32x4 oacc[4] = {};
#pragma unroll
    for (int ks = 0; ks < 8; ks++) {
        bf16x8 ah = *reinterpret_cast<const bf16x8*>(&hsd[wv][l15][ks * 32 + l4 * 8]);
#pragma unroll
        for (int j = 0; j < 4; j++) {
            bf16x8 bw = *reinterpret_cast<const bf16x8*>(pw + (j * 16 + l15) * 256 + ks * 32 + l4 * 8);
            oacc[j] = __builtin_amdgcn_mfma_f32_16x16x32_bf16(ah, bw, oacc[j], 0, 0, 0);
        }
    }
#pragma unroll
    for (int j = 0; j < 4; j++) {
        int d = j * 16 + l15;
        float pbv = pb[d];
        float vnv = vn[h * 64 + d];
#pragma unroll
        for (int r = 0; r < 4; r++) {
            int rloc = l4 * 4 + r;
            int t = tbase + rloc;
            float p = __shfl(psink, rloc, 64);    // psink of output row rloc
            float o = oacc[j][r] + pbv + p * vnv;
            ctx[((((size_t)(b << 10) + t) * 48 + h) << 6) + d] = rne_bf16(o);
        }
    }
}

// ---------------------------------------------------------------- launch
extern "C" void kernel_launch(void* const* d_in, const int* in_sizes, int n_in,
                              void* d_out, int out_size, void* d_ws, size_t ws_size,
                              hipStream_t stream) {
    (void)in_sizes; (void)n_in; (void)out_size; (void)ws_size;
    const float* A       = (const float*)d_in[0];
    const float* X       = (const float*)d_in[1];
    const float* Wq_w    = (const float*)d_in[2];
    const float* Wq_b    = (const float*)d_in[3];
    const float* Wk_w    = (const float*)d_in[4];
    const float* Wk_b    = (const float*)d_in[5];
    const float* wedge_A = (const float*)d_in[6];
    const float* wedge_b = (const float*)d_in[7];
    const float* sink    = (const float*)d_in[8];
    const float* v_nulls = (const float*)d_in[9];
    const float* fc_w    = (const float*)d_in[10];
    const float* fc_b    = (const float*)d_in[11];
    const float* proj_w  = (const float*)d_in[12];
    const float* proj_b  = (const float*)d_in[13];
    const float* WO      = (const float*)d_in[14];
    const float* WO_b    = (const float*)d_in[15];
    float* out = (float*)d_out;
    float* ws  = (float*)d_ws;

    // ---- workspace layout (float offsets) ----
    float*          qbuf   = ws;                                  // [0, 6291456) f32; later ctx_bf
    unsigned short* ctx_bf = (unsigned short*)ws;                 //   2048x3072 bf16
    float*          kbbuf  = ws + 6291456;                        // [6291456, 7864320) f32, live to end of mlp
    unsigned short* q_hi   = (unsigned short*)(ws + 7864320);     // [7864320, 11010048)
    unsigned short* q_lo   = (unsigned short*)(ws + 11010048);    // [11010048, 14155776)
    unsigned short* kf_hi  = (unsigned short*)(ws + 14155776);    // [14155776, 17301504)
    unsigned short* kf_lo  = (unsigned short*)(ws + 17301504);    // [17301504, 20447232)
    // region [20447232, 25559040): early = cvt scratch; late = pZ + pP
    unsigned short* A_bf   = (unsigned short*)(ws + 20447232);
    unsigned short* X_bf   = (unsigned short*)(ws + 21233664);
    unsigned short* Wq_bf  = (unsigned short*)(ws + 22020096);
    unsigned short* Wk_bf  = (unsigned short*)(ws + 23199744);
    float*          Sbuf   = ws + 23494656;
    float*          rcbuf  = ws + 23691264;
    float*          rsbuf  = ws + 23724032;
    float*          pZ     = ws + 20447232;                       // 393216 f32
    unsigned int*   pP     = (unsigned int*)(ws + 20840448);      // 4718592 u32, ends 25559040
    // tail
    float*          wob    = ws + 25559040;
    unsigned short* fcw_bf = (unsigned short*)(ws + 25560064);
    unsigned short* pw_bf  = (unsigned short*)(ws + 25568256);
    unsigned short* WOt_bf = (unsigned short*)(ws + 25576448);
    // end: 26,756,096 floats = 107.0 MB

    prep_all<<<9187, 256, 0, stream>>>(wedge_A, wedge_b, WO_b,
                                       A, X, Wq_w, Wk_w, fc_w, proj_w, WO,
                                       Sbuf, rcbuf, rsbuf, wob,
                                       A_bf, X_bf, Wq_bf, Wk_bf, fcw_bf, pw_bf, WOt_bf);
    gemm_qk<<<dim3(30, 16), 256, 0, stream>>>(A_bf, Wq_bf, Wq_b, qbuf,
                                              X_bf, Wk_bf, Wk_b, kbbuf);
    transform_qk<<<3072, 256, 0, stream>>>(qbuf, kbbuf, Sbuf, rcbuf, rsbuf,
                                           q_hi, q_lo, kf_hi, kf_lo);
    attn_scores<<<3840, 128, 0, stream>>>(q_hi, q_lo, kf_hi, kf_lo, pZ, pP);
    mlp_fused<<<1536, 256, 0, stream>>>(pP, pZ, sink, kbbuf,
                                        fcw_bf, fc_b, pw_bf, proj_b, v_nulls, ctx_bf);
    gemm_bf16_64<<<dim3(12, 32), 256, 0, stream>>>(ctx_bf, WOt_bf, wob, out, 2048, 768, 3072, 0.25f);
}